// Round 13
// baseline (323.423 us; speedup 1.0000x reference)
//
#include <hip/hip_runtime.h>
#include <hip/hip_bf16.h>

#define D 112
#define HEADS 28
#define HDIM 4
#define SEQ 512
#define BATCH 16
#define NTOK (BATCH*SEQ)
#define NBASES 8
#define NKNOT 12
#define KTOT (D*9)          // 1008 real K; padded to 1024 for MFMA
#define KPAD 1024
#define NKT (KPAD/32)       // 32 K-steps
#define TM 16               // tokens per block in kan GEMM

typedef __attribute__((ext_vector_type(8))) __bf16 bf16x8;
typedef __attribute__((ext_vector_type(4))) float f32x4;

__device__ __forceinline__ float dot4(float4 a, float4 b) {
    return a.x*b.x + a.y*b.y + a.z*b.z + a.w*b.w;
}

__device__ __forceinline__ unsigned short f2bf(float f) {
    unsigned u = __float_as_uint(f);
    unsigned r = u + 0x7FFFu + ((u >> 16) & 1u);   // RNE
    return (unsigned short)(r >> 16);
}

// ---------------- QKV projection (8 tokens/block) ----------------
// q is scaled by 0.5*log2(e) so attention scores are in log2 units.
__global__ __launch_bounds__(256) void qkv_kernel(
    const float* __restrict__ hin,
    const float* __restrict__ qw, const float* __restrict__ qb,
    const float* __restrict__ kw, const float* __restrict__ kb,
    const float* __restrict__ vw, const float* __restrict__ vb,
    int l, float* __restrict__ q, float* __restrict__ k, float* __restrict__ v)
{
    __shared__ float4 xs[8][28];
    int tid = threadIdx.x;
    int t0 = blockIdx.x * 8;
    const float4* src = (const float4*)(hin + (size_t)t0 * D);
    for (int e = tid; e < 8*28; e += 256) xs[e/28][e%28] = src[e];
    __syncthreads();
    for (int o = tid; o < 3*D; o += 256) {
        int m = o / D, j = o % D;
        const float* wbase = (m==0) ? qw : (m==1) ? kw : vw;
        const float* bbase = (m==0) ? qb : (m==1) ? kb : vb;
        const float4* wrow = (const float4*)(wbase + (size_t)(l*D + j) * D);
        float acc[8];
        #pragma unroll
        for (int t=0;t<8;++t) acc[t]=0.f;
        for (int c = 0; c < 28; ++c) {
            float4 wc = wrow[c];
            #pragma unroll
            for (int t = 0; t < 8; ++t) acc[t] += dot4(wc, xs[t][c]);
        }
        float bias = bbase[l*D + j];
        float scl = (m==0) ? 0.5f * 1.44269504088896f : 1.0f;  // q/sqrt(4) * log2(e)
        float* dst = (m==0) ? q : (m==1) ? k : v;
        int h = j >> 2, hd = j & 3;
        #pragma unroll
        for (int t = 0; t < 8; ++t) {
            int n = t0 + t; int b = n >> 9; int s = n & 511;
            dst[((size_t)(b*HEADS + h) * SEQ + s) * HDIM + hd] = (acc[t] + bias) * scl;
        }
    }
}

// ---------------- attention: fixed-bias softmax, uniform scalar K/V loads ----------------
// One block per (b,h): 256 threads x 2 queries. K/V/mask read with wave-uniform
// indices straight from global (scalar-load / L1-broadcast path) - no LDS, no syncs.
__global__ __launch_bounds__(256) void attn_kernel(
    const float* __restrict__ q, const float* __restrict__ k, const float* __restrict__ v,
    const int* __restrict__ mask, float* __restrict__ ctx)
{
    int tid = threadIdx.x;
    int bh = blockIdx.x;
    int b = bh / HEADS, h = bh % HEADS;
    const float4* __restrict__ kk = (const float4*)k + (size_t)bh*SEQ;
    const float4* __restrict__ vv = (const float4*)v + (size_t)bh*SEQ;
    const int*    __restrict__ mr = mask + b*SEQ;
    int s0 = tid;             // query 0
    int s1 = tid + 256;       // query 1
    const float4* qp = (const float4*)q + (size_t)bh*SEQ;
    float4 qv0 = qp[s0], qv1 = qp[s1];
    float sum0 = 0.f, sum1 = 0.f;
    float a00=0.f, a01=0.f, a02=0.f, a03=0.f;
    float a10=0.f, a11=0.f, a12=0.f, a13=0.f;
    #pragma unroll 8
    for (int kp = 0; kp < SEQ; ++kp) {
        float4 k4 = kk[kp];
        float4 v4 = vv[kp];
        float mf = mr[kp] ? -23.0831169f : -1e9f;   // -16*log2(e) | masked
        float sc0 = fmaf(qv0.x, k4.x, fmaf(qv0.y, k4.y,
                    fmaf(qv0.z, k4.z, fmaf(qv0.w, k4.w, mf))));
        float sc1 = fmaf(qv1.x, k4.x, fmaf(qv1.y, k4.y,
                    fmaf(qv1.z, k4.z, fmaf(qv1.w, k4.w, mf))));
        float p0 = __builtin_exp2f(sc0);
        float p1 = __builtin_exp2f(sc1);
        sum0 += p0; sum1 += p1;
        a00 = fmaf(p0, v4.x, a00); a01 = fmaf(p0, v4.y, a01);
        a02 = fmaf(p0, v4.z, a02); a03 = fmaf(p0, v4.w, a03);
        a10 = fmaf(p1, v4.x, a10); a11 = fmaf(p1, v4.y, a11);
        a12 = fmaf(p1, v4.z, a12); a13 = fmaf(p1, v4.w, a13);
    }
    float inv0 = 1.f / sum0, inv1 = 1.f / sum1;
    float4 o0 = {a00*inv0, a01*inv0, a02*inv0, a03*inv0};
    float4 o1 = {a10*inv1, a11*inv1, a12*inv1, a13*inv1};
    ((float4*)ctx)[(size_t)(b*SEQ + s0)*HEADS + h] = o0;   // ctx in (B,S,D) layout
    ((float4*)ctx)[(size_t)(b*SEQ + s1)*HEADS + h] = o1;
}

// ---------------- O-projection + residual + LN1 (4 tokens/block) ----------------
__global__ __launch_bounds__(256) void oproj_ln_kernel(
    const float* __restrict__ ctx, const float* __restrict__ hin,
    const float* __restrict__ ow, const float* __restrict__ ob,
    const float* __restrict__ g, const float* __restrict__ bta,
    int l, float* __restrict__ hout)
{
    __shared__ float4 sc[4][28];
    __shared__ float so[4][112];
    int tid = threadIdx.x;
    int t0 = blockIdx.x * 4;
    const float4* src = (const float4*)(ctx + (size_t)t0*D);
    if (tid < 112) sc[tid/28][tid%28] = src[tid];
    __syncthreads();
    if (tid < 224) {
        int j = tid % D, tg = tid / D;
        const float4* wrow = (const float4*)(ow + (size_t)(l*D + j)*D);
        float a0=0.f, a1=0.f;
        for (int c = 0; c < 28; ++c) {
            float4 wc = wrow[c];
            a0 += dot4(wc, sc[2*tg][c]);
            a1 += dot4(wc, sc[2*tg+1][c]);
        }
        float bias = ob[l*D + j];
        so[2*tg][j]   = a0 + bias + hin[(size_t)(t0+2*tg)*D + j];
        so[2*tg+1][j] = a1 + bias + hin[(size_t)(t0+2*tg+1)*D + j];
    }
    __syncthreads();
    int w = tid >> 6, lane = tid & 63;
    float x0 = so[w][lane];
    float x1 = (lane + 64 < D) ? so[w][lane+64] : 0.f;
    float s1 = x0 + x1, s2 = x0*x0 + x1*x1;
    #pragma unroll
    for (int off = 32; off; off >>= 1) { s1 += __shfl_xor(s1, off, 64); s2 += __shfl_xor(s2, off, 64); }
    float mu = s1 * (1.f/112.f);
    float var = s2 * (1.f/112.f) - mu*mu;
    float rs = rsqrtf(var + 1e-5f);
    for (int i = lane; i < D; i += 64)
        hout[(size_t)(t0+w)*D + i] = (so[w][i] - mu) * rs * g[l*D+i] + bta[l*D+i];
}

// ---------------- Wb prep: fold (spline_w*scaler, base_w) into bf16 B-fragment layout ----
__global__ void wb_prep_kernel(
    const float* __restrict__ base_w, const float* __restrict__ spline_w,
    const float* __restrict__ scaler, unsigned short* __restrict__ wb)
{
    int idx = blockIdx.x * 256 + threadIdx.x;
    if (idx >= 2 * NKT * D * 32) return;
    int kk = idx & 31;
    int j  = (idx >> 5) % D;
    int kt = ((idx >> 5) / D) % NKT;
    int l  = idx / (32 * D * NKT);
    int k = kt * 32 + kk;
    float val = 0.f;
    if (k < KTOT) {
        int i = k / 9, b = k % 9;
        size_t ji = ((size_t)l * D + j) * D + i;
        val = (b == 8) ? base_w[ji] : spline_w[ji * NBASES + b] * scaler[ji];
    }
    wb[idx] = f2bf(val);
}

// ---------------- KAN via bf16 MFMA + residual + LN2 (16 tokens/block, 4 waves) ---------
__global__ __launch_bounds__(256) void kan_ln_v3_kernel(
    const float* __restrict__ hin, const float* __restrict__ grid,
    const unsigned short* __restrict__ wb,
    const float* __restrict__ g, const float* __restrict__ bta,
    int l, int gstride, float* __restrict__ hout)
{
    __shared__ __align__(16) unsigned short act_lds[TM][1032];  // row pad -> 2-way bank (free)
    __shared__ float so[TM][D];
    int tid = threadIdx.x;
    int t0 = blockIdx.x * TM;

    // ---- basis phase: 1792 (token,i) pairs, 7 per thread ----
    for (int e = tid; e < TM * D; e += 256) {
        int t = e / D, i = e % D;
        float xv = hin[(size_t)(t0 + t) * D + i];
        float si = xv / (1.f + __expf(-xv));
        const float* grp = grid + i * gstride;
        float gr[NKNOT];
        #pragma unroll
        for (int ii = 0; ii < NKNOT; ++ii) gr[ii] = grp[ii];
        float bs[11];
        #pragma unroll
        for (int ii = 0; ii < 11; ++ii) bs[ii] = (xv >= gr[ii] && xv < gr[ii+1]) ? 1.f : 0.f;
        #pragma unroll
        for (int kk = 1; kk <= 3; ++kk) {
            #pragma unroll
            for (int ii = 0; ii + kk <= 10; ++ii) {
                float left  = (xv - gr[ii]) / (gr[ii+kk] - gr[ii]) * bs[ii];
                float right = (gr[ii+kk+1] - xv) / (gr[ii+kk+1] - gr[ii+1]) * bs[ii+1];
                bs[ii] = left + right;
            }
        }
        unsigned short* arow = &act_lds[t][i * 9];
        #pragma unroll
        for (int b = 0; b < 8; ++b) arow[b] = f2bf(bs[b]);
        arow[8] = f2bf(si);
    }
    // zero-pad k = 1008..1031
    for (int e = tid; e < TM * 24; e += 256)
        act_lds[e / 24][KTOT + e % 24] = 0;
    __syncthreads();

    // ---- MFMA GEMM phase: wave w owns j-tiles 2w, 2w+1 (7 tiles total) ----
    int w = tid >> 6, lane = tid & 63;
    int m = lane & 15, g4 = lane >> 4;
    int jt0 = 2 * w, jt1 = 2 * w + 1;
    f32x4 acc0 = {0.f,0.f,0.f,0.f}, acc1 = {0.f,0.f,0.f,0.f};
    const bf16x8* wbl = (const bf16x8*)wb + (size_t)l * NKT * D * 4;
    #pragma unroll 4
    for (int kt = 0; kt < NKT; ++kt) {
        bf16x8 a = *(const bf16x8*)&act_lds[m][kt * 32 + g4 * 8];
        bf16x8 b0 = wbl[((size_t)kt * D + jt0 * 16 + m) * 4 + g4];
        acc0 = __builtin_amdgcn_mfma_f32_16x16x32_bf16(a, b0, acc0, 0, 0, 0);
        if (jt1 < 7) {
            bf16x8 b1 = wbl[((size_t)kt * D + jt1 * 16 + m) * 4 + g4];
            acc1 = __builtin_amdgcn_mfma_f32_16x16x32_bf16(a, b1, acc1, 0, 0, 0);
        }
    }

    // ---- epilogue: D + residual -> so ----
    #pragma unroll
    for (int r = 0; r < 4; ++r) {
        int t = g4 * 4 + r;
        int j0 = jt0 * 16 + m;
        so[t][j0] = acc0[r] + hin[(size_t)(t0 + t) * D + j0];
        if (jt1 < 7) {
            int j1 = jt1 * 16 + m;
            so[t][j1] = acc1[r] + hin[(size_t)(t0 + t) * D + j1];
        }
    }
    __syncthreads();

    // ---- LN phase: 4 waves x 4 tokens ----
    for (int tt = 0; tt < 4; ++tt) {
        int t = w * 4 + tt;
        float x0 = so[t][lane];
        float x1 = (lane + 64 < D) ? so[t][lane + 64] : 0.f;
        float s1 = x0 + x1, s2 = x0*x0 + x1*x1;
        #pragma unroll
        for (int off = 32; off; off >>= 1) { s1 += __shfl_xor(s1, off, 64); s2 += __shfl_xor(s2, off, 64); }
        float mu = s1 * (1.f/112.f);
        float var = s2 * (1.f/112.f) - mu*mu;
        float rs = rsqrtf(var + 1e-5f);
        for (int ii = lane; ii < D; ii += 64)
            hout[(size_t)(t0 + t) * D + ii] = (so[t][ii] - mu) * rs * g[l*D + ii] + bta[l*D + ii];
    }
}

// ---------------- classifier: f32 output ----------------
__global__ __launch_bounds__(64) void cls_kernel(
    const float* __restrict__ h, const float* __restrict__ cw, const float* __restrict__ cb,
    float* __restrict__ out)
{
    int tid = threadIdx.x;
    if (tid < BATCH*2) {
        int b = tid >> 1, c = tid & 1;
        const float* hr = h + (size_t)b*SEQ*D;   // token s=0
        const float* wr = cw + c*D;
        float a = 0.f;
        for (int i = 0; i < D; ++i) a += hr[i]*wr[i];
        out[b*2 + c] = a + cb[c];
    }
}

// ---------------- ws-too-small sentinel (diagnostic) ----------------
__global__ void sentinel_kernel(float* __restrict__ out, int nel)
{
    int i = threadIdx.x;
    if (i < nel) out[i] = 1e30f;
}

extern "C" void kernel_launch(void* const* d_in, const int* in_sizes, int n_in,
                              void* d_out, int out_size, void* d_ws, size_t ws_size,
                              hipStream_t stream)
{
    const float* x      = (const float*)d_in[0];
    const int*   mask   = (const int*)  d_in[1];
    const float* grid   = (const float*)d_in[2];
    const float* qw     = (const float*)d_in[3];
    const float* qb     = (const float*)d_in[4];
    const float* kw     = (const float*)d_in[5];
    const float* kb     = (const float*)d_in[6];
    const float* vw     = (const float*)d_in[7];
    const float* vb     = (const float*)d_in[8];
    const float* ow     = (const float*)d_in[9];
    const float* ob     = (const float*)d_in[10];
    const float* ln1g   = (const float*)d_in[11];
    const float* ln1b   = (const float*)d_in[12];
    const float* ln2g   = (const float*)d_in[13];
    const float* ln2b   = (const float*)d_in[14];
    const float* base_w = (const float*)d_in[15];
    const float* spline_w = (const float*)d_in[16];
    const float* scaler = (const float*)d_in[17];
    const float* cls_w  = (const float*)d_in[18];
    const float* cls_b  = (const float*)d_in[19];

    size_t SZ = (size_t)NTOK * D;              // 917504 floats per buffer
    size_t WBN = (size_t)2 * NKT * D * 32;     // 229376 bf16 elements
    size_t need = 6 * SZ * sizeof(float) + WBN * sizeof(unsigned short);  // ~22.5 MB
    if (ws_size < need) {
        sentinel_kernel<<<1, 64, 0, stream>>>((float*)d_out, out_size);
        return;
    }
    float* ws = (float*)d_ws;
    float* q   = ws;
    float* k   = q + SZ;
    float* v   = k + SZ;
    float* ctx = v + SZ;
    float* hA  = ctx + SZ;
    float* hB  = hA + SZ;
    unsigned short* wbuf = (unsigned short*)(hB + SZ);

    int gstride = (in_sizes[2] == NKNOT) ? 0 : NKNOT;

    wb_prep_kernel<<<(int)((WBN + 255)/256), 256, 0, stream>>>(
        base_w, spline_w, scaler, wbuf);

    const float* hin = x;
    for (int l = 0; l < 2; ++l) {
        qkv_kernel<<<NTOK/8, 256, 0, stream>>>(hin, qw,qb,kw,kb,vw,vb, l, q,k,v);
        attn_kernel<<<BATCH*HEADS, 256, 0, stream>>>(q,k,v,mask,ctx);
        oproj_ln_kernel<<<NTOK/4, 256, 0, stream>>>(ctx, hin, ow, ob, ln1g, ln1b, l, hA);
        kan_ln_v3_kernel<<<NTOK/TM, 256, 0, stream>>>(hA, grid, wbuf, ln2g, ln2b, l, gstride, hB);
        hin = hB;
    }
    cls_kernel<<<1, 64, 0, stream>>>(hB, cls_w, cls_b, (float*)d_out);
}

// Round 14
// 320.320 us; speedup vs baseline: 1.0097x; 1.0097x over previous
//
#include <hip/hip_runtime.h>
#include <hip/hip_bf16.h>

#define D 112
#define HEADS 28
#define HDIM 4
#define SEQ 512
#define BATCH 16
#define NTOK (BATCH*SEQ)
#define NBASES 8
#define NKNOT 12
#define KTOT (D*9)          // 1008 real K; padded to 1024 for MFMA
#define KPAD 1024
#define NKT (KPAD/32)       // 32 K-steps
#define TM 16               // tokens per block in kan GEMM
#define LOG2E 1.44269504088896f
#define ATTN_BIAS (-23.0831169f)   // -16*log2(e)

typedef __attribute__((ext_vector_type(8))) __bf16 bf16x8;
typedef __attribute__((ext_vector_type(4))) float f32x4;

__device__ __forceinline__ float dot4(float4 a, float4 b) {
    return a.x*b.x + a.y*b.y + a.z*b.z + a.w*b.w;
}

__device__ __forceinline__ unsigned short f2bf(float f) {
    unsigned u = __float_as_uint(f);
    unsigned r = u + 0x7FFFu + ((u >> 16) & 1u);   // RNE
    return (unsigned short)(r >> 16);
}

__device__ __forceinline__ unsigned cvt_pk_bf16(float lo, float hi) {
    unsigned r;
    asm("v_cvt_pk_bf16_f32 %0, %1, %2" : "=v"(r) : "v"(lo), "v"(hi));
    return r;
}

// ---------------- QKV projection (8 tokens/block) ----------------
// q is scaled by 0.5*log2(e) so attention scores are in log2 units.
__global__ __launch_bounds__(256) void qkv_kernel(
    const float* __restrict__ hin,
    const float* __restrict__ qw, const float* __restrict__ qb,
    const float* __restrict__ kw, const float* __restrict__ kb,
    const float* __restrict__ vw, const float* __restrict__ vb,
    int l, float* __restrict__ q, float* __restrict__ k, float* __restrict__ v)
{
    __shared__ float4 xs[8][28];
    int tid = threadIdx.x;
    int t0 = blockIdx.x * 8;
    const float4* src = (const float4*)(hin + (size_t)t0 * D);
    for (int e = tid; e < 8*28; e += 256) xs[e/28][e%28] = src[e];
    __syncthreads();
    for (int o = tid; o < 3*D; o += 256) {
        int m = o / D, j = o % D;
        const float* wbase = (m==0) ? qw : (m==1) ? kw : vw;
        const float* bbase = (m==0) ? qb : (m==1) ? kb : vb;
        const float4* wrow = (const float4*)(wbase + (size_t)(l*D + j) * D);
        float acc[8];
        #pragma unroll
        for (int t=0;t<8;++t) acc[t]=0.f;
        for (int c = 0; c < 28; ++c) {
            float4 wc = wrow[c];
            #pragma unroll
            for (int t = 0; t < 8; ++t) acc[t] += dot4(wc, xs[t][c]);
        }
        float bias = bbase[l*D + j];
        float scl = (m==0) ? 0.5f * LOG2E : 1.0f;  // q/sqrt(4) * log2(e)
        float* dst = (m==0) ? q : (m==1) ? k : v;
        int h = j >> 2, hd = j & 3;
        #pragma unroll
        for (int t = 0; t < 8; ++t) {
            int n = t0 + t; int b = n >> 9; int s = n & 511;
            dst[((size_t)(b*HEADS + h) * SEQ + s) * HDIM + hd] = (acc[t] + bias) * scl;
        }
    }
}

// ---------------- per-batch mask flag: 1 if no key is masked ----------------
__global__ void mask_flags_kernel(const int* __restrict__ mask, int* __restrict__ flags)
{
    __shared__ int ok;
    if (threadIdx.x == 0) ok = 1;
    __syncthreads();
    int bad = 0;
    for (int i = threadIdx.x; i < SEQ; i += 256)
        if (mask[blockIdx.x*SEQ + i] == 0) bad = 1;
    if (bad) atomicAnd(&ok, 0);
    __syncthreads();
    if (threadIdx.x == 0) flags[blockIdx.x] = ok;
}

// ---------------- attention: bf16-packed K/V, 1 LDS read/key, fixed-bias softmax --------
// 2 queries/thread, 896 blocks x 128 threads. K4+V4 packed bf16 in one uint4 ->
// single broadcast ds_read_b128 per key; unpack is shift/and (free bit-ops).
// All-ones-mask fast path folds the constant bias into the score FMA chain.
__global__ __launch_bounds__(128) void attn_kernel(
    const float* __restrict__ q, const float* __restrict__ k, const float* __restrict__ v,
    const int* __restrict__ mask, const int* __restrict__ flags, float* __restrict__ ctx)
{
    __shared__ uint4 skv[SEQ];     // 8 KB
    __shared__ float smf[SEQ];     // fallback mask bias
    int tid = threadIdx.x;
    int bh = blockIdx.x >> 1, qt = blockIdx.x & 1;
    int b = bh / HEADS, h = bh % HEADS;
    const float4* kk = (const float4*)k + (size_t)bh*SEQ;
    const float4* vv = (const float4*)v + (size_t)bh*SEQ;
    int allones = flags[b];
    for (int i = tid; i < SEQ; i += 128) {
        float4 kf = kk[i];
        float4 vf = vv[i];
        uint4 pk;
        pk.x = cvt_pk_bf16(kf.x, kf.y);
        pk.y = cvt_pk_bf16(kf.z, kf.w);
        pk.z = cvt_pk_bf16(vf.x, vf.y);
        pk.w = cvt_pk_bf16(vf.z, vf.w);
        skv[i] = pk;
        if (!allones) smf[i] = mask[b*SEQ + i] ? ATTN_BIAS : -1e9f;
    }
    __syncthreads();

    int s0 = qt*256 + tid;           // query 0
    int s1 = s0 + 128;               // query 1
    const float4* qp = (const float4*)q + (size_t)bh*SEQ;
    float4 qv0 = qp[s0], qv1 = qp[s1];
    float sum0 = 0.f, sum1 = 0.f;
    float a00=0.f, a01=0.f, a02=0.f, a03=0.f;
    float a10=0.f, a11=0.f, a12=0.f, a13=0.f;

    if (allones) {
        #pragma unroll 8
        for (int kp = 0; kp < SEQ; ++kp) {
            uint4 u = skv[kp];
            float kx = __uint_as_float(u.x << 16);
            float ky = __uint_as_float(u.x & 0xffff0000u);
            float kz = __uint_as_float(u.y << 16);
            float kw_ = __uint_as_float(u.y & 0xffff0000u);
            float vx = __uint_as_float(u.z << 16);
            float vy = __uint_as_float(u.z & 0xffff0000u);
            float vz = __uint_as_float(u.w << 16);
            float vw_ = __uint_as_float(u.w & 0xffff0000u);
            float sc0 = fmaf(qv0.x,kx, fmaf(qv0.y,ky, fmaf(qv0.z,kz, fmaf(qv0.w,kw_, ATTN_BIAS))));
            float sc1 = fmaf(qv1.x,kx, fmaf(qv1.y,ky, fmaf(qv1.z,kz, fmaf(qv1.w,kw_, ATTN_BIAS))));
            float p0 = __builtin_exp2f(sc0);
            float p1 = __builtin_exp2f(sc1);
            sum0 += p0; sum1 += p1;
            a00 = fmaf(p0,vx,a00); a01 = fmaf(p0,vy,a01);
            a02 = fmaf(p0,vz,a02); a03 = fmaf(p0,vw_,a03);
            a10 = fmaf(p1,vx,a10); a11 = fmaf(p1,vy,a11);
            a12 = fmaf(p1,vz,a12); a13 = fmaf(p1,vw_,a13);
        }
    } else {
        #pragma unroll 8
        for (int kp = 0; kp < SEQ; ++kp) {
            uint4 u = skv[kp];
            float mf = smf[kp];
            float kx = __uint_as_float(u.x << 16);
            float ky = __uint_as_float(u.x & 0xffff0000u);
            float kz = __uint_as_float(u.y << 16);
            float kw_ = __uint_as_float(u.y & 0xffff0000u);
            float vx = __uint_as_float(u.z << 16);
            float vy = __uint_as_float(u.z & 0xffff0000u);
            float vz = __uint_as_float(u.w << 16);
            float vw_ = __uint_as_float(u.w & 0xffff0000u);
            float sc0 = fmaf(qv0.x,kx, fmaf(qv0.y,ky, fmaf(qv0.z,kz, fmaf(qv0.w,kw_, mf))));
            float sc1 = fmaf(qv1.x,kx, fmaf(qv1.y,ky, fmaf(qv1.z,kz, fmaf(qv1.w,kw_, mf))));
            float p0 = __builtin_exp2f(sc0);
            float p1 = __builtin_exp2f(sc1);
            sum0 += p0; sum1 += p1;
            a00 = fmaf(p0,vx,a00); a01 = fmaf(p0,vy,a01);
            a02 = fmaf(p0,vz,a02); a03 = fmaf(p0,vw_,a03);
            a10 = fmaf(p1,vx,a10); a11 = fmaf(p1,vy,a11);
            a12 = fmaf(p1,vz,a12); a13 = fmaf(p1,vw_,a13);
        }
    }
    float inv0 = 1.f / sum0, inv1 = 1.f / sum1;
    float4 o0 = {a00*inv0, a01*inv0, a02*inv0, a03*inv0};
    float4 o1 = {a10*inv1, a11*inv1, a12*inv1, a13*inv1};
    ((float4*)ctx)[(size_t)(b*SEQ + s0)*HEADS + h] = o0;   // ctx in (B,S,D) layout
    ((float4*)ctx)[(size_t)(b*SEQ + s1)*HEADS + h] = o1;
}

// ---------------- O-projection + residual + LN1 (4 tokens/block) ----------------
__global__ __launch_bounds__(256) void oproj_ln_kernel(
    const float* __restrict__ ctx, const float* __restrict__ hin,
    const float* __restrict__ ow, const float* __restrict__ ob,
    const float* __restrict__ g, const float* __restrict__ bta,
    int l, float* __restrict__ hout)
{
    __shared__ float4 sc[4][28];
    __shared__ float so[4][112];
    int tid = threadIdx.x;
    int t0 = blockIdx.x * 4;
    const float4* src = (const float4*)(ctx + (size_t)t0*D);
    if (tid < 112) sc[tid/28][tid%28] = src[tid];
    __syncthreads();
    if (tid < 224) {
        int j = tid % D, tg = tid / D;
        const float4* wrow = (const float4*)(ow + (size_t)(l*D + j)*D);
        float a0=0.f, a1=0.f;
        for (int c = 0; c < 28; ++c) {
            float4 wc = wrow[c];
            a0 += dot4(wc, sc[2*tg][c]);
            a1 += dot4(wc, sc[2*tg+1][c]);
        }
        float bias = ob[l*D + j];
        so[2*tg][j]   = a0 + bias + hin[(size_t)(t0+2*tg)*D + j];
        so[2*tg+1][j] = a1 + bias + hin[(size_t)(t0+2*tg+1)*D + j];
    }
    __syncthreads();
    int w = tid >> 6, lane = tid & 63;
    float x0 = so[w][lane];
    float x1 = (lane + 64 < D) ? so[w][lane+64] : 0.f;
    float s1 = x0 + x1, s2 = x0*x0 + x1*x1;
    #pragma unroll
    for (int off = 32; off; off >>= 1) { s1 += __shfl_xor(s1, off, 64); s2 += __shfl_xor(s2, off, 64); }
    float mu = s1 * (1.f/112.f);
    float var = s2 * (1.f/112.f) - mu*mu;
    float rs = rsqrtf(var + 1e-5f);
    for (int i = lane; i < D; i += 64)
        hout[(size_t)(t0+w)*D + i] = (so[w][i] - mu) * rs * g[l*D+i] + bta[l*D+i];
}

// ---------------- Wb prep: fold (spline_w*scaler, base_w) into bf16 B-fragment layout ----
__global__ void wb_prep_kernel(
    const float* __restrict__ base_w, const float* __restrict__ spline_w,
    const float* __restrict__ scaler, unsigned short* __restrict__ wb)
{
    int idx = blockIdx.x * 256 + threadIdx.x;
    if (idx >= 2 * NKT * D * 32) return;
    int kk = idx & 31;
    int j  = (idx >> 5) % D;
    int kt = ((idx >> 5) / D) % NKT;
    int l  = idx / (32 * D * NKT);
    int k = kt * 32 + kk;
    float val = 0.f;
    if (k < KTOT) {
        int i = k / 9, b = k % 9;
        size_t ji = ((size_t)l * D + j) * D + i;
        val = (b == 8) ? base_w[ji] : spline_w[ji * NBASES + b] * scaler[ji];
    }
    wb[idx] = f2bf(val);
}

// ---------------- KAN via bf16 MFMA + residual + LN2 (16 tokens/block, 4 waves) ---------
__global__ __launch_bounds__(256) void kan_ln_v3_kernel(
    const float* __restrict__ hin, const float* __restrict__ grid,
    const unsigned short* __restrict__ wb,
    const float* __restrict__ g, const float* __restrict__ bta,
    int l, int gstride, float* __restrict__ hout)
{
    __shared__ __align__(16) unsigned short act_lds[TM][1032];  // row pad -> 2-way bank (free)
    __shared__ float so[TM][D];
    int tid = threadIdx.x;
    int t0 = blockIdx.x * TM;

    // ---- basis phase: 1792 (token,i) pairs, 7 per thread ----
    for (int e = tid; e < TM * D; e += 256) {
        int t = e / D, i = e % D;
        float xv = hin[(size_t)(t0 + t) * D + i];
        float si = xv / (1.f + __expf(-xv));
        const float* grp = grid + i * gstride;
        float gr[NKNOT];
        #pragma unroll
        for (int ii = 0; ii < NKNOT; ++ii) gr[ii] = grp[ii];
        float bs[11];
        #pragma unroll
        for (int ii = 0; ii < 11; ++ii) bs[ii] = (xv >= gr[ii] && xv < gr[ii+1]) ? 1.f : 0.f;
        #pragma unroll
        for (int kk = 1; kk <= 3; ++kk) {
            #pragma unroll
            for (int ii = 0; ii + kk <= 10; ++ii) {
                float left  = (xv - gr[ii]) / (gr[ii+kk] - gr[ii]) * bs[ii];
                float right = (gr[ii+kk+1] - xv) / (gr[ii+kk+1] - gr[ii+1]) * bs[ii+1];
                bs[ii] = left + right;
            }
        }
        unsigned short* arow = &act_lds[t][i * 9];
        #pragma unroll
        for (int b = 0; b < 8; ++b) arow[b] = f2bf(bs[b]);
        arow[8] = f2bf(si);
    }
    // zero-pad k = 1008..1031
    for (int e = tid; e < TM * 24; e += 256)
        act_lds[e / 24][KTOT + e % 24] = 0;
    __syncthreads();

    // ---- MFMA GEMM phase: wave w owns j-tiles 2w, 2w+1 (7 tiles total) ----
    int w = tid >> 6, lane = tid & 63;
    int m = lane & 15, g4 = lane >> 4;
    int jt0 = 2 * w, jt1 = 2 * w + 1;
    f32x4 acc0 = {0.f,0.f,0.f,0.f}, acc1 = {0.f,0.f,0.f,0.f};
    const bf16x8* wbl = (const bf16x8*)wb + (size_t)l * NKT * D * 4;
    #pragma unroll 4
    for (int kt = 0; kt < NKT; ++kt) {
        bf16x8 a = *(const bf16x8*)&act_lds[m][kt * 32 + g4 * 8];
        bf16x8 b0 = wbl[((size_t)kt * D + jt0 * 16 + m) * 4 + g4];
        acc0 = __builtin_amdgcn_mfma_f32_16x16x32_bf16(a, b0, acc0, 0, 0, 0);
        if (jt1 < 7) {
            bf16x8 b1 = wbl[((size_t)kt * D + jt1 * 16 + m) * 4 + g4];
            acc1 = __builtin_amdgcn_mfma_f32_16x16x32_bf16(a, b1, acc1, 0, 0, 0);
        }
    }

    // ---- epilogue: D + residual -> so ----
    #pragma unroll
    for (int r = 0; r < 4; ++r) {
        int t = g4 * 4 + r;
        int j0 = jt0 * 16 + m;
        so[t][j0] = acc0[r] + hin[(size_t)(t0 + t) * D + j0];
        if (jt1 < 7) {
            int j1 = jt1 * 16 + m;
            so[t][j1] = acc1[r] + hin[(size_t)(t0 + t) * D + j1];
        }
    }
    __syncthreads();

    // ---- LN phase: 4 waves x 4 tokens ----
    for (int tt = 0; tt < 4; ++tt) {
        int t = w * 4 + tt;
        float x0 = so[t][lane];
        float x1 = (lane + 64 < D) ? so[t][lane + 64] : 0.f;
        float s1 = x0 + x1, s2 = x0*x0 + x1*x1;
        #pragma unroll
        for (int off = 32; off; off >>= 1) { s1 += __shfl_xor(s1, off, 64); s2 += __shfl_xor(s2, off, 64); }
        float mu = s1 * (1.f/112.f);
        float var = s2 * (1.f/112.f) - mu*mu;
        float rs = rsqrtf(var + 1e-5f);
        for (int ii = lane; ii < D; ii += 64)
            hout[(size_t)(t0 + t) * D + ii] = (so[t][ii] - mu) * rs * g[l*D + ii] + bta[l*D + ii];
    }
}

// ---------------- classifier: f32 output ----------------
__global__ __launch_bounds__(64) void cls_kernel(
    const float* __restrict__ h, const float* __restrict__ cw, const float* __restrict__ cb,
    float* __restrict__ out)
{
    int tid = threadIdx.x;
    if (tid < BATCH*2) {
        int b = tid >> 1, c = tid & 1;
        const float* hr = h + (size_t)b*SEQ*D;   // token s=0
        const float* wr = cw + c*D;
        float a = 0.f;
        for (int i = 0; i < D; ++i) a += hr[i]*wr[i];
        out[b*2 + c] = a + cb[c];
    }
}

// ---------------- ws-too-small sentinel (diagnostic) ----------------
__global__ void sentinel_kernel(float* __restrict__ out, int nel)
{
    int i = threadIdx.x;
    if (i < nel) out[i] = 1e30f;
}

extern "C" void kernel_launch(void* const* d_in, const int* in_sizes, int n_in,
                              void* d_out, int out_size, void* d_ws, size_t ws_size,
                              hipStream_t stream)
{
    const float* x      = (const float*)d_in[0];
    const int*   mask   = (const int*)  d_in[1];
    const float* grid   = (const float*)d_in[2];
    const float* qw     = (const float*)d_in[3];
    const float* qb     = (const float*)d_in[4];
    const float* kw     = (const float*)d_in[5];
    const float* kb     = (const float*)d_in[6];
    const float* vw     = (const float*)d_in[7];
    const float* vb     = (const float*)d_in[8];
    const float* ow     = (const float*)d_in[9];
    const float* ob     = (const float*)d_in[10];
    const float* ln1g   = (const float*)d_in[11];
    const float* ln1b   = (const float*)d_in[12];
    const float* ln2g   = (const float*)d_in[13];
    const float* ln2b   = (const float*)d_in[14];
    const float* base_w = (const float*)d_in[15];
    const float* spline_w = (const float*)d_in[16];
    const float* scaler = (const float*)d_in[17];
    const float* cls_w  = (const float*)d_in[18];
    const float* cls_b  = (const float*)d_in[19];

    size_t SZ = (size_t)NTOK * D;              // 917504 floats per buffer
    size_t WBN = (size_t)2 * NKT * D * 32;     // 229376 bf16 elements
    size_t need = 6 * SZ * sizeof(float) + WBN * sizeof(unsigned short) + 64*sizeof(int);
    if (ws_size < need) {
        sentinel_kernel<<<1, 64, 0, stream>>>((float*)d_out, out_size);
        return;
    }
    float* ws = (float*)d_ws;
    float* q   = ws;
    float* k   = q + SZ;
    float* v   = k + SZ;
    float* ctx = v + SZ;
    float* hA  = ctx + SZ;
    float* hB  = hA + SZ;
    unsigned short* wbuf = (unsigned short*)(hB + SZ);
    int* flags = (int*)(wbuf + WBN);

    int gstride = (in_sizes[2] == NKNOT) ? 0 : NKNOT;

    wb_prep_kernel<<<(int)((WBN + 255)/256), 256, 0, stream>>>(
        base_w, spline_w, scaler, wbuf);
    mask_flags_kernel<<<BATCH, 256, 0, stream>>>(mask, flags);

    const float* hin = x;
    for (int l = 0; l < 2; ++l) {
        qkv_kernel<<<NTOK/8, 256, 0, stream>>>(hin, qw,qb,kw,kb,vw,vb, l, q,k,v);
        attn_kernel<<<BATCH*HEADS*2, 128, 0, stream>>>(q,k,v,mask,flags,ctx);
        oproj_ln_kernel<<<NTOK/4, 256, 0, stream>>>(ctx, hin, ow, ob, ln1g, ln1b, l, hA);
        kan_ln_v3_kernel<<<NTOK/TM, 256, 0, stream>>>(hA, grid, wbuf, ln2g, ln2b, l, gstride, hB);
        hin = hB;
    }
    cls_kernel<<<1, 64, 0, stream>>>(hB, cls_w, cls_b, (float*)d_out);
}

// Round 15
// 278.630 us; speedup vs baseline: 1.1608x; 1.1496x over previous
//
#include <hip/hip_runtime.h>
#include <hip/hip_bf16.h>

#define D 112
#define HEADS 28
#define HDIM 4
#define SEQ 512
#define BATCH 16
#define NTOK (BATCH*SEQ)
#define NBASES 8
#define NKNOT 12
#define KTOT (D*9)          // 1008 real K for KAN; padded to 1024
#define KPAD 1024
#define NKT (KPAD/32)       // 32 K-steps (KAN)
#define TM 16               // tokens per block in GEMM kernels
#define QJT 21              // 336/16 j-tiles in fused qkv GEMM
#define LOG2E 1.44269504088896f
#define ATTN_BIAS (-23.0831169f)   // -16*log2(e)

typedef __attribute__((ext_vector_type(8))) __bf16 bf16x8;
typedef __attribute__((ext_vector_type(4))) float f32x4;

__device__ __forceinline__ unsigned short f2bf(float f) {
    unsigned u = __float_as_uint(f);
    unsigned r = u + 0x7FFFu + ((u >> 16) & 1u);   // RNE
    return (unsigned short)(r >> 16);
}

__device__ __forceinline__ unsigned cvt_pk_bf16(float lo, float hi) {
    unsigned r;
    asm("v_cvt_pk_bf16_f32 %0, %1, %2" : "=v"(r) : "v"(lo), "v"(hi));
    return r;
}

// ---------------- weight prep: qkv concat -> bf16 B-fragment layout ----------------
// wq[l][kt(4)][j(336)][kk(32)] = Wcat[j][i=kt*32+kk]; j<112: qw row j; 112-223: kw; 224-335: vw.
__global__ void wqkv_prep_kernel(
    const float* __restrict__ qw, const float* __restrict__ kw, const float* __restrict__ vw,
    unsigned short* __restrict__ wq)
{
    int idx = blockIdx.x * 256 + threadIdx.x;
    if (idx >= 2*4*336*32) return;
    int kk = idx & 31;
    int j  = (idx >> 5) % 336;
    int kt = ((idx >> 5) / 336) & 3;
    int l  = idx / (32*336*4);
    int i = kt*32 + kk;
    float val = 0.f;
    if (i < D) {
        int mo = j / D, jj = j % D;
        const float* src = (mo==0) ? qw : (mo==1) ? kw : vw;
        val = src[((size_t)l*D + jj)*D + i];
    }
    wq[idx] = f2bf(val);
}

// ---------------- weight prep: oproj -> bf16 B-fragment layout ----------------
// wo[l][kt(4)][j(112)][kk(32)] = ow[l][j][i=kt*32+kk], 0 for i>=112.
__global__ void wo_prep_kernel(const float* __restrict__ ow, unsigned short* __restrict__ wo)
{
    int idx = blockIdx.x * 256 + threadIdx.x;
    if (idx >= 2*4*D*32) return;
    int kk = idx & 31;
    int j  = (idx >> 5) % D;
    int kt = ((idx >> 5) / D) & 3;
    int l  = idx / (32*D*4);
    int i = kt*32 + kk;
    float val = (i < D) ? ow[((size_t)l*D + j)*D + i] : 0.f;
    wo[idx] = f2bf(val);
}

// ---------------- per-batch mask flag: 1 if no key is masked ----------------
__global__ void mask_flags_kernel(const int* __restrict__ mask, int* __restrict__ flags)
{
    __shared__ int ok;
    if (threadIdx.x == 0) ok = 1;
    __syncthreads();
    int bad = 0;
    for (int i = threadIdx.x; i < SEQ; i += 256)
        if (mask[blockIdx.x*SEQ + i] == 0) bad = 1;
    if (bad) atomicAnd(&ok, 0);
    __syncthreads();
    if (threadIdx.x == 0) flags[blockIdx.x] = ok;
}

// ---------------- fused QKV via MFMA (16 tokens/block, 4 waves, 21 j-tiles) ----------------
__global__ __launch_bounds__(256) void qkv_mfma_kernel(
    const float* __restrict__ hin, const unsigned short* __restrict__ wq,
    const float* __restrict__ qb, const float* __restrict__ kb, const float* __restrict__ vb,
    int l, float* __restrict__ q, float* __restrict__ k, float* __restrict__ v)
{
    __shared__ __align__(16) unsigned short act[TM][136];   // 16 x (128+8 pad)
    int tid = threadIdx.x;
    int t0 = blockIdx.x * TM;
    for (int e = tid; e < TM*D; e += 256) {
        int t = e / D, i = e % D;
        act[t][i] = f2bf(hin[(size_t)(t0 + t)*D + i]);
    }
    for (int e = tid; e < TM*16; e += 256) act[e/16][D + (e%16)] = 0;
    __syncthreads();

    int w = tid >> 6, lane = tid & 63, m = lane & 15, g4 = lane >> 4;
    f32x4 acc[6];
    #pragma unroll
    for (int qq = 0; qq < 6; ++qq) acc[qq] = (f32x4){0.f,0.f,0.f,0.f};
    const bf16x8* wql = (const bf16x8*)wq + (size_t)l*4*336*4;
    #pragma unroll
    for (int kt = 0; kt < 4; ++kt) {
        bf16x8 a = *(const bf16x8*)&act[m][kt*32 + g4*8];
        #pragma unroll
        for (int qq = 0; qq < 6; ++qq) {
            int jt = w + 4*qq;
            if (jt < QJT) {
                bf16x8 bf = wql[((size_t)kt*336 + jt*16 + m)*4 + g4];
                acc[qq] = __builtin_amdgcn_mfma_f32_16x16x32_bf16(a, bf, acc[qq], 0, 0, 0);
            }
        }
    }
    #pragma unroll
    for (int qq = 0; qq < 6; ++qq) {
        int jt = w + 4*qq;
        if (jt >= QJT) continue;
        int j = jt*16 + m;
        int mo = j / D, jj = j % D;
        const float* bb = (mo==0) ? qb : (mo==1) ? kb : vb;
        float bias = bb[l*D + jj];
        float scl = (mo==0) ? 0.5f*LOG2E : 1.0f;
        float* dst = (mo==0) ? q : (mo==1) ? k : v;
        int h = jj >> 2, hd = jj & 3;
        #pragma unroll
        for (int r = 0; r < 4; ++r) {
            int n = t0 + g4*4 + r;
            int bi = n >> 9, s = n & 511;
            dst[((size_t)(bi*HEADS + h)*SEQ + s)*HDIM + hd] = (acc[qq][r] + bias)*scl;
        }
    }
}

// ---------------- attention: split-K x2, packed bf16 K/V, fixed-bias softmax ----------------
// 2 blocks per (b,h), 256 threads: lq=tid&127 -> queries s0,s1; half=tid>>7 -> key range.
// One ds_read_b128 per key; partials combined through LDS (sums add under shared bias).
__global__ __launch_bounds__(256) void attn_kernel(
    const float* __restrict__ q, const float* __restrict__ k, const float* __restrict__ v,
    const int* __restrict__ mask, const int* __restrict__ flags, float* __restrict__ ctx)
{
    __shared__ uint4 skv[SEQ];          // 8 KB packed bf16 K|V
    __shared__ float smf[SEQ];          // fallback mask bias
    __shared__ float pcomb[128][11];    // upper-half partials
    int tid = threadIdx.x;
    int bh = blockIdx.x >> 1, qt = blockIdx.x & 1;
    int b = bh / HEADS, h = bh % HEADS;
    int allones = flags[b];
    const float4* kk = (const float4*)k + (size_t)bh*SEQ;
    const float4* vv = (const float4*)v + (size_t)bh*SEQ;
    for (int i = tid; i < SEQ; i += 256) {
        float4 kf = kk[i];
        float4 vf = vv[i];
        uint4 pk;
        pk.x = cvt_pk_bf16(kf.x, kf.y);
        pk.y = cvt_pk_bf16(kf.z, kf.w);
        pk.z = cvt_pk_bf16(vf.x, vf.y);
        pk.w = cvt_pk_bf16(vf.z, vf.w);
        skv[i] = pk;
        if (!allones) smf[i] = mask[b*SEQ + i] ? ATTN_BIAS : -1e9f;
    }
    __syncthreads();

    int half = tid >> 7;            // key half
    int lq   = tid & 127;           // local query
    int s0 = qt*256 + lq;
    int s1 = s0 + 128;
    const float4* qp = (const float4*)q + (size_t)bh*SEQ;
    float4 qv0 = qp[s0], qv1 = qp[s1];
    float sum0 = 0.f, sum1 = 0.f;
    float a00=0.f, a01=0.f, a02=0.f, a03=0.f;
    float a10=0.f, a11=0.f, a12=0.f, a13=0.f;
    int kbase = half * 256;

    if (allones) {
        #pragma unroll 8
        for (int kp = 0; kp < 256; ++kp) {
            uint4 u = skv[kbase + kp];
            float kx = __uint_as_float(u.x << 16);
            float ky = __uint_as_float(u.x & 0xffff0000u);
            float kz = __uint_as_float(u.y << 16);
            float kw_ = __uint_as_float(u.y & 0xffff0000u);
            float vx = __uint_as_float(u.z << 16);
            float vy = __uint_as_float(u.z & 0xffff0000u);
            float vz = __uint_as_float(u.w << 16);
            float vw_ = __uint_as_float(u.w & 0xffff0000u);
            float sc0 = fmaf(qv0.x,kx, fmaf(qv0.y,ky, fmaf(qv0.z,kz, fmaf(qv0.w,kw_, ATTN_BIAS))));
            float sc1 = fmaf(qv1.x,kx, fmaf(qv1.y,ky, fmaf(qv1.z,kz, fmaf(qv1.w,kw_, ATTN_BIAS))));
            float p0 = __builtin_exp2f(sc0);
            float p1 = __builtin_exp2f(sc1);
            sum0 += p0; sum1 += p1;
            a00 = fmaf(p0,vx,a00); a01 = fmaf(p0,vy,a01);
            a02 = fmaf(p0,vz,a02); a03 = fmaf(p0,vw_,a03);
            a10 = fmaf(p1,vx,a10); a11 = fmaf(p1,vy,a11);
            a12 = fmaf(p1,vz,a12); a13 = fmaf(p1,vw_,a13);
        }
    } else {
        #pragma unroll 8
        for (int kp = 0; kp < 256; ++kp) {
            uint4 u = skv[kbase + kp];
            float mf = smf[kbase + kp];
            float kx = __uint_as_float(u.x << 16);
            float ky = __uint_as_float(u.x & 0xffff0000u);
            float kz = __uint_as_float(u.y << 16);
            float kw_ = __uint_as_float(u.y & 0xffff0000u);
            float vx = __uint_as_float(u.z << 16);
            float vy = __uint_as_float(u.z & 0xffff0000u);
            float vz = __uint_as_float(u.w << 16);
            float vw_ = __uint_as_float(u.w & 0xffff0000u);
            float sc0 = fmaf(qv0.x,kx, fmaf(qv0.y,ky, fmaf(qv0.z,kz, fmaf(qv0.w,kw_, mf))));
            float sc1 = fmaf(qv1.x,kx, fmaf(qv1.y,ky, fmaf(qv1.z,kz, fmaf(qv1.w,kw_, mf))));
            float p0 = __builtin_exp2f(sc0);
            float p1 = __builtin_exp2f(sc1);
            sum0 += p0; sum1 += p1;
            a00 = fmaf(p0,vx,a00); a01 = fmaf(p0,vy,a01);
            a02 = fmaf(p0,vz,a02); a03 = fmaf(p0,vw_,a03);
            a10 = fmaf(p1,vx,a10); a11 = fmaf(p1,vy,a11);
            a12 = fmaf(p1,vz,a12); a13 = fmaf(p1,vw_,a13);
        }
    }

    if (half == 1) {
        pcomb[lq][0] = sum0;
        pcomb[lq][1] = a00; pcomb[lq][2] = a01; pcomb[lq][3] = a02; pcomb[lq][4] = a03;
        pcomb[lq][5] = sum1;
        pcomb[lq][6] = a10; pcomb[lq][7] = a11; pcomb[lq][8] = a12; pcomb[lq][9] = a13;
    }
    __syncthreads();
    if (half == 0) {
        sum0 += pcomb[lq][0];
        a00 += pcomb[lq][1]; a01 += pcomb[lq][2]; a02 += pcomb[lq][3]; a03 += pcomb[lq][4];
        sum1 += pcomb[lq][5];
        a10 += pcomb[lq][6]; a11 += pcomb[lq][7]; a12 += pcomb[lq][8]; a13 += pcomb[lq][9];
        float inv0 = 1.f / sum0, inv1 = 1.f / sum1;
        float4 o0 = {a00*inv0, a01*inv0, a02*inv0, a03*inv0};
        float4 o1 = {a10*inv1, a11*inv1, a12*inv1, a13*inv1};
        ((float4*)ctx)[(size_t)(b*SEQ + s0)*HEADS + h] = o0;   // ctx in (B,S,D) layout
        ((float4*)ctx)[(size_t)(b*SEQ + s1)*HEADS + h] = o1;
    }
}

// ---------------- O-projection via MFMA + residual + LN1 (16 tokens/block) ----------------
__global__ __launch_bounds__(256) void oproj_ln_v2_kernel(
    const float* __restrict__ ctx, const float* __restrict__ hin,
    const unsigned short* __restrict__ wo, const float* __restrict__ ob,
    const float* __restrict__ g, const float* __restrict__ bta,
    int l, float* __restrict__ hout)
{
    __shared__ __align__(16) unsigned short act[TM][136];
    __shared__ float so[TM][D];
    int tid = threadIdx.x;
    int t0 = blockIdx.x * TM;
    for (int e = tid; e < TM*D; e += 256) {
        int t = e / D, i = e % D;
        act[t][i] = f2bf(ctx[(size_t)(t0 + t)*D + i]);
    }
    for (int e = tid; e < TM*16; e += 256) act[e/16][D + (e%16)] = 0;
    __syncthreads();

    int w = tid >> 6, lane = tid & 63, m = lane & 15, g4 = lane >> 4;
    int jt0 = 2*w, jt1 = 2*w + 1;
    f32x4 acc0 = {0.f,0.f,0.f,0.f}, acc1 = {0.f,0.f,0.f,0.f};
    const bf16x8* wol = (const bf16x8*)wo + (size_t)l*4*D*4;
    #pragma unroll
    for (int kt = 0; kt < 4; ++kt) {
        bf16x8 a = *(const bf16x8*)&act[m][kt*32 + g4*8];
        bf16x8 b0 = wol[((size_t)kt*D + jt0*16 + m)*4 + g4];
        acc0 = __builtin_amdgcn_mfma_f32_16x16x32_bf16(a, b0, acc0, 0, 0, 0);
        if (jt1 < 7) {
            bf16x8 b1 = wol[((size_t)kt*D + jt1*16 + m)*4 + g4];
            acc1 = __builtin_amdgcn_mfma_f32_16x16x32_bf16(a, b1, acc1, 0, 0, 0);
        }
    }
    #pragma unroll
    for (int r = 0; r < 4; ++r) {
        int t = g4*4 + r;
        int j0 = jt0*16 + m;
        so[t][j0] = acc0[r] + ob[l*D + j0] + hin[(size_t)(t0 + t)*D + j0];
        if (jt1 < 7) {
            int j1 = jt1*16 + m;
            so[t][j1] = acc1[r] + ob[l*D + j1] + hin[(size_t)(t0 + t)*D + j1];
        }
    }
    __syncthreads();

    for (int tt = 0; tt < 4; ++tt) {
        int t = w*4 + tt;
        float x0 = so[t][lane];
        float x1 = (lane + 64 < D) ? so[t][lane + 64] : 0.f;
        float s1 = x0 + x1, s2 = x0*x0 + x1*x1;
        #pragma unroll
        for (int off = 32; off; off >>= 1) { s1 += __shfl_xor(s1, off, 64); s2 += __shfl_xor(s2, off, 64); }
        float mu = s1 * (1.f/112.f);
        float var = s2 * (1.f/112.f) - mu*mu;
        float rs = rsqrtf(var + 1e-5f);
        for (int ii = lane; ii < D; ii += 64)
            hout[(size_t)(t0 + t)*D + ii] = (so[t][ii] - mu)*rs*g[l*D + ii] + bta[l*D + ii];
    }
}

// ---------------- Wb prep: fold (spline_w*scaler, base_w) into bf16 B-fragment layout ----
__global__ void wb_prep_kernel(
    const float* __restrict__ base_w, const float* __restrict__ spline_w,
    const float* __restrict__ scaler, unsigned short* __restrict__ wb)
{
    int idx = blockIdx.x * 256 + threadIdx.x;
    if (idx >= 2 * NKT * D * 32) return;
    int kk = idx & 31;
    int j  = (idx >> 5) % D;
    int kt = ((idx >> 5) / D) % NKT;
    int l  = idx / (32 * D * NKT);
    int k = kt * 32 + kk;
    float val = 0.f;
    if (k < KTOT) {
        int i = k / 9, b = k % 9;
        size_t ji = ((size_t)l * D + j) * D + i;
        val = (b == 8) ? base_w[ji] : spline_w[ji * NBASES + b] * scaler[ji];
    }
    wb[idx] = f2bf(val);
}

// ---------------- KAN via bf16 MFMA + residual + LN2 (16 tokens/block, 4 waves) ---------
__global__ __launch_bounds__(256) void kan_ln_v3_kernel(
    const float* __restrict__ hin, const float* __restrict__ grid,
    const unsigned short* __restrict__ wb,
    const float* __restrict__ g, const float* __restrict__ bta,
    int l, int gstride, float* __restrict__ hout)
{
    __shared__ __align__(16) unsigned short act_lds[TM][1032];  // row pad -> 2-way bank (free)
    __shared__ float so[TM][D];
    int tid = threadIdx.x;
    int t0 = blockIdx.x * TM;

    for (int e = tid; e < TM * D; e += 256) {
        int t = e / D, i = e % D;
        float xv = hin[(size_t)(t0 + t) * D + i];
        float si = xv / (1.f + __expf(-xv));
        const float* grp = grid + i * gstride;
        float gr[NKNOT];
        #pragma unroll
        for (int ii = 0; ii < NKNOT; ++ii) gr[ii] = grp[ii];
        float bs[11];
        #pragma unroll
        for (int ii = 0; ii < 11; ++ii) bs[ii] = (xv >= gr[ii] && xv < gr[ii+1]) ? 1.f : 0.f;
        #pragma unroll
        for (int kk = 1; kk <= 3; ++kk) {
            #pragma unroll
            for (int ii = 0; ii + kk <= 10; ++ii) {
                float left  = (xv - gr[ii]) / (gr[ii+kk] - gr[ii]) * bs[ii];
                float right = (gr[ii+kk+1] - xv) / (gr[ii+kk+1] - gr[ii+1]) * bs[ii+1];
                bs[ii] = left + right;
            }
        }
        unsigned short* arow = &act_lds[t][i * 9];
        #pragma unroll
        for (int b = 0; b < 8; ++b) arow[b] = f2bf(bs[b]);
        arow[8] = f2bf(si);
    }
    for (int e = tid; e < TM * 24; e += 256)
        act_lds[e / 24][KTOT + e % 24] = 0;
    __syncthreads();

    int w = tid >> 6, lane = tid & 63;
    int m = lane & 15, g4 = lane >> 4;
    int jt0 = 2 * w, jt1 = 2 * w + 1;
    f32x4 acc0 = {0.f,0.f,0.f,0.f}, acc1 = {0.f,0.f,0.f,0.f};
    const bf16x8* wbl = (const bf16x8*)wb + (size_t)l * NKT * D * 4;
    #pragma unroll 4
    for (int kt = 0; kt < NKT; ++kt) {
        bf16x8 a = *(const bf16x8*)&act_lds[m][kt * 32 + g4 * 8];
        bf16x8 b0 = wbl[((size_t)kt * D + jt0 * 16 + m) * 4 + g4];
        acc0 = __builtin_amdgcn_mfma_f32_16x16x32_bf16(a, b0, acc0, 0, 0, 0);
        if (jt1 < 7) {
            bf16x8 b1 = wbl[((size_t)kt * D + jt1 * 16 + m) * 4 + g4];
            acc1 = __builtin_amdgcn_mfma_f32_16x16x32_bf16(a, b1, acc1, 0, 0, 0);
        }
    }

    #pragma unroll
    for (int r = 0; r < 4; ++r) {
        int t = g4 * 4 + r;
        int j0 = jt0 * 16 + m;
        so[t][j0] = acc0[r] + hin[(size_t)(t0 + t) * D + j0];
        if (jt1 < 7) {
            int j1 = jt1 * 16 + m;
            so[t][j1] = acc1[r] + hin[(size_t)(t0 + t) * D + j1];
        }
    }
    __syncthreads();

    for (int tt = 0; tt < 4; ++tt) {
        int t = w * 4 + tt;
        float x0 = so[t][lane];
        float x1 = (lane + 64 < D) ? so[t][lane + 64] : 0.f;
        float s1 = x0 + x1, s2 = x0*x0 + x1*x1;
        #pragma unroll
        for (int off = 32; off; off >>= 1) { s1 += __shfl_xor(s1, off, 64); s2 += __shfl_xor(s2, off, 64); }
        float mu = s1 * (1.f/112.f);
        float var = s2 * (1.f/112.f) - mu*mu;
        float rs = rsqrtf(var + 1e-5f);
        for (int ii = lane; ii < D; ii += 64)
            hout[(size_t)(t0 + t) * D + ii] = (so[t][ii] - mu) * rs * g[l*D + ii] + bta[l*D + ii];
    }
}

// ---------------- classifier: f32 output ----------------
__global__ __launch_bounds__(64) void cls_kernel(
    const float* __restrict__ h, const float* __restrict__ cw, const float* __restrict__ cb,
    float* __restrict__ out)
{
    int tid = threadIdx.x;
    if (tid < BATCH*2) {
        int b = tid >> 1, c = tid & 1;
        const float* hr = h + (size_t)b*SEQ*D;   // token s=0
        const float* wr = cw + c*D;
        float a = 0.f;
        for (int i = 0; i < D; ++i) a += hr[i]*wr[i];
        out[b*2 + c] = a + cb[c];
    }
}

// ---------------- ws-too-small sentinel (diagnostic) ----------------
__global__ void sentinel_kernel(float* __restrict__ out, int nel)
{
    int i = threadIdx.x;
    if (i < nel) out[i] = 1e30f;
}

extern "C" void kernel_launch(void* const* d_in, const int* in_sizes, int n_in,
                              void* d_out, int out_size, void* d_ws, size_t ws_size,
                              hipStream_t stream)
{
    const float* x      = (const float*)d_in[0];
    const int*   mask   = (const int*)  d_in[1];
    const float* grid   = (const float*)d_in[2];
    const float* qw     = (const float*)d_in[3];
    const float* qb     = (const float*)d_in[4];
    const float* kw     = (const float*)d_in[5];
    const float* kb     = (const float*)d_in[6];
    const float* vw     = (const float*)d_in[7];
    const float* vb     = (const float*)d_in[8];
    const float* ow     = (const float*)d_in[9];
    const float* ob     = (const float*)d_in[10];
    const float* ln1g   = (const float*)d_in[11];
    const float* ln1b   = (const float*)d_in[12];
    const float* ln2g   = (const float*)d_in[13];
    const float* ln2b   = (const float*)d_in[14];
    const float* base_w = (const float*)d_in[15];
    const float* spline_w = (const float*)d_in[16];
    const float* scaler = (const float*)d_in[17];
    const float* cls_w  = (const float*)d_in[18];
    const float* cls_b  = (const float*)d_in[19];

    size_t SZ   = (size_t)NTOK * D;            // 917504 floats per buffer
    size_t WBN  = (size_t)2 * NKT * D * 32;    // 229376 bf16 (kan weights)
    size_t WQN  = (size_t)2 * 4 * 336 * 32;    // 86016 bf16 (qkv weights)
    size_t WON  = (size_t)2 * 4 * D * 32;      // 28672 bf16 (oproj weights)
    size_t need = 6*SZ*sizeof(float) + (WBN + WQN + WON)*sizeof(unsigned short) + 256;
    if (ws_size < need) {
        sentinel_kernel<<<1, 64, 0, stream>>>((float*)d_out, out_size);
        return;
    }
    float* ws = (float*)d_ws;
    float* q   = ws;
    float* k   = q + SZ;
    float* v   = k + SZ;
    float* ctx = v + SZ;
    float* hA  = ctx + SZ;
    float* hB  = hA + SZ;
    unsigned short* wbuf  = (unsigned short*)(hB + SZ);
    unsigned short* wqkv  = wbuf + WBN;
    unsigned short* wobuf = wqkv + WQN;
    int* flags = (int*)(wobuf + WON);

    int gstride = (in_sizes[2] == NKNOT) ? 0 : NKNOT;

    wb_prep_kernel<<<(int)((WBN + 255)/256), 256, 0, stream>>>(base_w, spline_w, scaler, wbuf);
    wqkv_prep_kernel<<<(int)((WQN + 255)/256), 256, 0, stream>>>(qw, kw, vw, wqkv);
    wo_prep_kernel<<<(int)((WON + 255)/256), 256, 0, stream>>>(ow, wobuf);
    mask_flags_kernel<<<BATCH, 256, 0, stream>>>(mask, flags);

    const float* hin = x;
    for (int l = 0; l < 2; ++l) {
        qkv_mfma_kernel<<<NTOK/TM, 256, 0, stream>>>(hin, wqkv, qb, kb, vb, l, q, k, v);
        attn_kernel<<<BATCH*HEADS*2, 256, 0, stream>>>(q, k, v, mask, flags, ctx);
        oproj_ln_v2_kernel<<<NTOK/TM, 256, 0, stream>>>(ctx, hin, wobuf, ob, ln1g, ln1b, l, hA);
        kan_ln_v3_kernel<<<NTOK/TM, 256, 0, stream>>>(hA, grid, wbuf, ln2g, ln2b, l, gstride, hB);
        hin = hB;
    }
    cls_kernel<<<1, 64, 0, stream>>>(hB, cls_w, cls_b, (float*)d_out);
}

// Round 16
// 254.823 us; speedup vs baseline: 1.2692x; 1.0934x over previous
//
#include <hip/hip_runtime.h>
#include <hip/hip_bf16.h>

#define D 112
#define HEADS 28
#define HDIM 4
#define SEQ 512
#define BATCH 16
#define NTOK (BATCH*SEQ)
#define NBASES 8
#define NKNOT 12
#define KTOT (D*9)          // 1008 real K for KAN; padded to 1024
#define KPAD 1024
#define NKT (KPAD/32)       // 32 K-steps (KAN)
#define TM 16               // tokens per block in GEMM kernels
#define QJT 21              // 336/16 j-tiles in fused qkv GEMM
#define LOG2E 1.44269504088896f
#define ATTN_BIAS (-23.0831169f)   // -16*log2(e)

typedef __attribute__((ext_vector_type(8))) __bf16 bf16x8;
typedef __attribute__((ext_vector_type(4))) float f32x4;

__device__ __forceinline__ unsigned short f2bf(float f) {
    unsigned u = __float_as_uint(f);
    unsigned r = u + 0x7FFFu + ((u >> 16) & 1u);   // RNE
    return (unsigned short)(r >> 16);
}

__device__ __forceinline__ unsigned cvt_pk_bf16(float lo, float hi) {
    unsigned r;
    asm("v_cvt_pk_bf16_f32 %0, %1, %2" : "=v"(r) : "v"(lo), "v"(hi));
    return r;
}

// ---------------- weight prep: qkv concat -> bf16 B-fragment layout ----------------
__global__ void wqkv_prep_kernel(
    const float* __restrict__ qw, const float* __restrict__ kw, const float* __restrict__ vw,
    unsigned short* __restrict__ wq)
{
    int idx = blockIdx.x * 256 + threadIdx.x;
    if (idx >= 2*4*336*32) return;
    int kk = idx & 31;
    int j  = (idx >> 5) % 336;
    int kt = ((idx >> 5) / 336) & 3;
    int l  = idx / (32*336*4);
    int i = kt*32 + kk;
    float val = 0.f;
    if (i < D) {
        int mo = j / D, jj = j % D;
        const float* src = (mo==0) ? qw : (mo==1) ? kw : vw;
        val = src[((size_t)l*D + jj)*D + i];
    }
    wq[idx] = f2bf(val);
}

// ---------------- weight prep: oproj -> bf16 B-fragment layout ----------------
__global__ void wo_prep_kernel(const float* __restrict__ ow, unsigned short* __restrict__ wo)
{
    int idx = blockIdx.x * 256 + threadIdx.x;
    if (idx >= 2*4*D*32) return;
    int kk = idx & 31;
    int j  = (idx >> 5) % D;
    int kt = ((idx >> 5) / D) & 3;
    int l  = idx / (32*D*4);
    int i = kt*32 + kk;
    float val = (i < D) ? ow[((size_t)l*D + j)*D + i] : 0.f;
    wo[idx] = f2bf(val);
}

// ---------------- fused QKV via MFMA (16 tokens/block, 4 waves, 21 j-tiles) ----------------
__global__ __launch_bounds__(256) void qkv_mfma_kernel(
    const float* __restrict__ hin, const unsigned short* __restrict__ wq,
    const float* __restrict__ qb, const float* __restrict__ kb, const float* __restrict__ vb,
    int l, float* __restrict__ q, float* __restrict__ k, float* __restrict__ v)
{
    __shared__ __align__(16) unsigned short act[TM][136];   // 16 x (128+8 pad)
    int tid = threadIdx.x;
    int t0 = blockIdx.x * TM;
    for (int e = tid; e < TM*D; e += 256) {
        int t = e / D, i = e % D;
        act[t][i] = f2bf(hin[(size_t)(t0 + t)*D + i]);
    }
    for (int e = tid; e < TM*16; e += 256) act[e/16][D + (e%16)] = 0;
    __syncthreads();

    int w = tid >> 6, lane = tid & 63, m = lane & 15, g4 = lane >> 4;
    f32x4 acc[6];
    #pragma unroll
    for (int qq = 0; qq < 6; ++qq) acc[qq] = (f32x4){0.f,0.f,0.f,0.f};
    const bf16x8* wql = (const bf16x8*)wq + (size_t)l*4*336*4;
    #pragma unroll
    for (int kt = 0; kt < 4; ++kt) {
        bf16x8 a = *(const bf16x8*)&act[m][kt*32 + g4*8];
        #pragma unroll
        for (int qq = 0; qq < 6; ++qq) {
            int jt = w + 4*qq;
            if (jt < QJT) {
                bf16x8 bf = wql[((size_t)kt*336 + jt*16 + m)*4 + g4];
                acc[qq] = __builtin_amdgcn_mfma_f32_16x16x32_bf16(a, bf, acc[qq], 0, 0, 0);
            }
        }
    }
    #pragma unroll
    for (int qq = 0; qq < 6; ++qq) {
        int jt = w + 4*qq;
        if (jt >= QJT) continue;
        int j = jt*16 + m;
        int mo = j / D, jj = j % D;
        const float* bb = (mo==0) ? qb : (mo==1) ? kb : vb;
        float bias = bb[l*D + jj];
        float scl = (mo==0) ? 0.5f*LOG2E : 1.0f;
        float* dst = (mo==0) ? q : (mo==1) ? k : v;
        int h = jj >> 2, hd = jj & 3;
        #pragma unroll
        for (int r = 0; r < 4; ++r) {
            int n = t0 + g4*4 + r;
            int bi = n >> 9, s = n & 511;
            dst[((size_t)(bi*HEADS + h)*SEQ + s)*HDIM + hd] = (acc[qq][r] + bias)*scl;
        }
    }
}

// ---------------- attention via MFMA (flash-style, mask folded into GEMM) ----------------
// Block = half a (b,h): 256 queries, 4 waves x 4 q-tiles. Scores: S^T = K.Q^T with
// K slot4 = mask-bias, Q slot4 = 1.0 (bias comes out of the MFMA). Softmax rows are
// keys -> in-lane sum. PV: P packed bf16 through per-wave LDS tile (72B stride).
__global__ __launch_bounds__(256) void attn_mfma_kernel(
    const float* __restrict__ q, const float* __restrict__ k, const float* __restrict__ v,
    const int* __restrict__ mask, float* __restrict__ ctx)
{
    __shared__ __align__(16) unsigned short kpack[SEQ][8];   // k0..3, mf, 0,0,0   (8KB)
    __shared__ __align__(16) unsigned short qpack[256][8];   // q0..3, 1.0, 0,0,0  (4KB)
    __shared__ __align__(16) unsigned short vT[4][SEQ];      // V^T                (4KB)
    __shared__ __align__(16) uint4 zfrag;                    // 16B zeros
    __shared__ __align__(16) unsigned int plds[4][16*18];    // per-wave P, 72B row stride (4.5KB)

    int tid = threadIdx.x;
    int bh = blockIdx.x >> 1, qh = blockIdx.x & 1;
    int b = bh / HEADS, h = bh % HEADS;

    if (tid == 0) zfrag = (uint4){0,0,0,0};
    const float4* kk = (const float4*)k + (size_t)bh*SEQ;
    const float4* vv = (const float4*)v + (size_t)bh*SEQ;
    for (int s = tid; s < SEQ; s += 256) {
        float4 kf = kk[s];
        float mf = mask[b*SEQ + s] ? ATTN_BIAS : -1e9f;
        uint4 pk;
        pk.x = cvt_pk_bf16(kf.x, kf.y);
        pk.y = cvt_pk_bf16(kf.z, kf.w);
        pk.z = cvt_pk_bf16(mf, 0.f);
        pk.w = 0;
        *(uint4*)&kpack[s][0] = pk;
        float4 vf = vv[s];
        vT[0][s] = f2bf(vf.x); vT[1][s] = f2bf(vf.y);
        vT[2][s] = f2bf(vf.z); vT[3][s] = f2bf(vf.w);
    }
    {
        int s = qh*256 + tid;
        float4 qf = ((const float4*)q)[(size_t)bh*SEQ + s];
        uint4 pk;
        pk.x = cvt_pk_bf16(qf.x, qf.y);
        pk.y = cvt_pk_bf16(qf.z, qf.w);
        pk.z = cvt_pk_bf16(1.0f, 0.f);
        pk.w = 0;
        *(uint4*)&qpack[tid][0] = pk;
    }
    __syncthreads();

    int w = tid >> 6, lane = tid & 63, ln = lane & 15, g4 = lane >> 4;
    unsigned int* pw = &plds[w][0];
    const bf16x8* zf = (const bf16x8*)&zfrag;

    for (int qt = 0; qt < 4; ++qt) {
        int q0 = w*64 + qt*16;    // block-local query base
        bf16x8 qfrag = (g4 == 0) ? *(const bf16x8*)&qpack[q0 + ln][0] : *zf;
        f32x4 oacc = {0.f,0.f,0.f,0.f};
        float sum = 0.f;
        for (int kb = 0; kb < SEQ; kb += 32) {
            bf16x8 ka0 = (g4 == 0) ? *(const bf16x8*)&kpack[kb + ln][0]      : *zf;
            bf16x8 ka1 = (g4 == 0) ? *(const bf16x8*)&kpack[kb + 16 + ln][0] : *zf;
            f32x4 s0 = __builtin_amdgcn_mfma_f32_16x16x32_bf16(ka0, qfrag, (f32x4){0.f,0.f,0.f,0.f}, 0, 0, 0);
            f32x4 s1 = __builtin_amdgcn_mfma_f32_16x16x32_bf16(ka1, qfrag, (f32x4){0.f,0.f,0.f,0.f}, 0, 0, 0);
            // lane holds: col=ln (query), rows = keys kb + g4*4 + r (s0) / +16 (s1)
            float p00 = __builtin_exp2f(s0[0]), p01 = __builtin_exp2f(s0[1]);
            float p02 = __builtin_exp2f(s0[2]), p03 = __builtin_exp2f(s0[3]);
            float p10 = __builtin_exp2f(s1[0]), p11 = __builtin_exp2f(s1[1]);
            float p12 = __builtin_exp2f(s1[2]), p13 = __builtin_exp2f(s1[3]);
            sum += ((p00 + p01) + (p02 + p03)) + ((p10 + p11) + (p12 + p13));
            uint2 w0 = {cvt_pk_bf16(p00, p01), cvt_pk_bf16(p02, p03)};
            uint2 w1 = {cvt_pk_bf16(p10, p11), cvt_pk_bf16(p12, p13)};
            *(uint2*)&pw[ln*18 + g4*2]     = w0;   // keys kb+g4*4..+3   -> u32 slots g4*2,+1
            *(uint2*)&pw[ln*18 + 8 + g4*2] = w1;   // keys kb+16+g4*4..+3
            // PV: A = P (lane m=ln query, keys g4*8..+7), B = V^T
            bf16x8 pa = *(const bf16x8*)&pw[ln*18 + g4*4];
            bf16x8 vb = (ln < 4) ? *(const bf16x8*)&vT[ln][kb + g4*8] : *zf;
            oacc = __builtin_amdgcn_mfma_f32_16x16x32_bf16(pa, vb, oacc, 0, 0, 0);
        }
        // sum reduce across the 4 g4 groups (same query col ln)
        sum += __shfl_xor(sum, 16, 64);
        sum += __shfl_xor(sum, 32, 64);
        float inv = 1.f / sum;                  // lane: total for query ln
        // oacc: rows = queries g4*4+r, col = ln = d (<4)
        float i0 = __shfl(inv, g4*4 + 0, 64);
        float i1 = __shfl(inv, g4*4 + 1, 64);
        float i2 = __shfl(inv, g4*4 + 2, 64);
        float i3 = __shfl(inv, g4*4 + 3, 64);
        if (ln < 4) {
            size_t base = (size_t)(b*SEQ + qh*256 + q0 + g4*4);
            ctx[(base + 0)*D + h*4 + ln] = oacc[0] * i0;
            ctx[(base + 1)*D + h*4 + ln] = oacc[1] * i1;
            ctx[(base + 2)*D + h*4 + ln] = oacc[2] * i2;
            ctx[(base + 3)*D + h*4 + ln] = oacc[3] * i3;
        }
    }
}

// ---------------- O-projection via MFMA + residual + LN1 (16 tokens/block) ----------------
__global__ __launch_bounds__(256) void oproj_ln_v2_kernel(
    const float* __restrict__ ctx, const float* __restrict__ hin,
    const unsigned short* __restrict__ wo, const float* __restrict__ ob,
    const float* __restrict__ g, const float* __restrict__ bta,
    int l, float* __restrict__ hout)
{
    __shared__ __align__(16) unsigned short act[TM][136];
    __shared__ float so[TM][D];
    int tid = threadIdx.x;
    int t0 = blockIdx.x * TM;
    for (int e = tid; e < TM*D; e += 256) {
        int t = e / D, i = e % D;
        act[t][i] = f2bf(ctx[(size_t)(t0 + t)*D + i]);
    }
    for (int e = tid; e < TM*16; e += 256) act[e/16][D + (e%16)] = 0;
    __syncthreads();

    int w = tid >> 6, lane = tid & 63, m = lane & 15, g4 = lane >> 4;
    int jt0 = 2*w, jt1 = 2*w + 1;
    f32x4 acc0 = {0.f,0.f,0.f,0.f}, acc1 = {0.f,0.f,0.f,0.f};
    const bf16x8* wol = (const bf16x8*)wo + (size_t)l*4*D*4;
    #pragma unroll
    for (int kt = 0; kt < 4; ++kt) {
        bf16x8 a = *(const bf16x8*)&act[m][kt*32 + g4*8];
        bf16x8 b0 = wol[((size_t)kt*D + jt0*16 + m)*4 + g4];
        acc0 = __builtin_amdgcn_mfma_f32_16x16x32_bf16(a, b0, acc0, 0, 0, 0);
        if (jt1 < 7) {
            bf16x8 b1 = wol[((size_t)kt*D + jt1*16 + m)*4 + g4];
            acc1 = __builtin_amdgcn_mfma_f32_16x16x32_bf16(a, b1, acc1, 0, 0, 0);
        }
    }
    #pragma unroll
    for (int r = 0; r < 4; ++r) {
        int t = g4*4 + r;
        int j0 = jt0*16 + m;
        so[t][j0] = acc0[r] + ob[l*D + j0] + hin[(size_t)(t0 + t)*D + j0];
        if (jt1 < 7) {
            int j1 = jt1*16 + m;
            so[t][j1] = acc1[r] + ob[l*D + j1] + hin[(size_t)(t0 + t)*D + j1];
        }
    }
    __syncthreads();

    for (int tt = 0; tt < 4; ++tt) {
        int t = w*4 + tt;
        float x0 = so[t][lane];
        float x1 = (lane + 64 < D) ? so[t][lane + 64] : 0.f;
        float s1 = x0 + x1, s2 = x0*x0 + x1*x1;
        #pragma unroll
        for (int off = 32; off; off >>= 1) { s1 += __shfl_xor(s1, off, 64); s2 += __shfl_xor(s2, off, 64); }
        float mu = s1 * (1.f/112.f);
        float var = s2 * (1.f/112.f) - mu*mu;
        float rs = rsqrtf(var + 1e-5f);
        for (int ii = lane; ii < D; ii += 64)
            hout[(size_t)(t0 + t)*D + ii] = (so[t][ii] - mu)*rs*g[l*D + ii] + bta[l*D + ii];
    }
}

// ---------------- Wb prep: fold (spline_w*scaler, base_w) into bf16 B-fragment layout ----
__global__ void wb_prep_kernel(
    const float* __restrict__ base_w, const float* __restrict__ spline_w,
    const float* __restrict__ scaler, unsigned short* __restrict__ wb)
{
    int idx = blockIdx.x * 256 + threadIdx.x;
    if (idx >= 2 * NKT * D * 32) return;
    int kk = idx & 31;
    int j  = (idx >> 5) % D;
    int kt = ((idx >> 5) / D) % NKT;
    int l  = idx / (32 * D * NKT);
    int k = kt * 32 + kk;
    float val = 0.f;
    if (k < KTOT) {
        int i = k / 9, b = k % 9;
        size_t ji = ((size_t)l * D + j) * D + i;
        val = (b == 8) ? base_w[ji] : spline_w[ji * NBASES + b] * scaler[ji];
    }
    wb[idx] = f2bf(val);
}

// ---------------- KAN via bf16 MFMA + residual + LN2 (16 tokens/block, 4 waves) ---------
__global__ __launch_bounds__(256) void kan_ln_v3_kernel(
    const float* __restrict__ hin, const float* __restrict__ grid,
    const unsigned short* __restrict__ wb,
    const float* __restrict__ g, const float* __restrict__ bta,
    int l, int gstride, float* __restrict__ hout)
{
    __shared__ __align__(16) unsigned short act_lds[TM][1032];  // row pad -> 2-way bank (free)
    __shared__ float so[TM][D];
    int tid = threadIdx.x;
    int t0 = blockIdx.x * TM;

    for (int e = tid; e < TM * D; e += 256) {
        int t = e / D, i = e % D;
        float xv = hin[(size_t)(t0 + t) * D + i];
        float si = xv / (1.f + __expf(-xv));
        const float* grp = grid + i * gstride;
        float gr[NKNOT];
        #pragma unroll
        for (int ii = 0; ii < NKNOT; ++ii) gr[ii] = grp[ii];
        float bs[11];
        #pragma unroll
        for (int ii = 0; ii < 11; ++ii) bs[ii] = (xv >= gr[ii] && xv < gr[ii+1]) ? 1.f : 0.f;
        #pragma unroll
        for (int kk = 1; kk <= 3; ++kk) {
            #pragma unroll
            for (int ii = 0; ii + kk <= 10; ++ii) {
                float left  = (xv - gr[ii]) / (gr[ii+kk] - gr[ii]) * bs[ii];
                float right = (gr[ii+kk+1] - xv) / (gr[ii+kk+1] - gr[ii+1]) * bs[ii+1];
                bs[ii] = left + right;
            }
        }
        unsigned short* arow = &act_lds[t][i * 9];
        #pragma unroll
        for (int b = 0; b < 8; ++b) arow[b] = f2bf(bs[b]);
        arow[8] = f2bf(si);
    }
    for (int e = tid; e < TM * 24; e += 256)
        act_lds[e / 24][KTOT + e % 24] = 0;
    __syncthreads();

    int w = tid >> 6, lane = tid & 63;
    int m = lane & 15, g4 = lane >> 4;
    int jt0 = 2 * w, jt1 = 2 * w + 1;
    f32x4 acc0 = {0.f,0.f,0.f,0.f}, acc1 = {0.f,0.f,0.f,0.f};
    const bf16x8* wbl = (const bf16x8*)wb + (size_t)l * NKT * D * 4;
    #pragma unroll 4
    for (int kt = 0; kt < NKT; ++kt) {
        bf16x8 a = *(const bf16x8*)&act_lds[m][kt * 32 + g4 * 8];
        bf16x8 b0 = wbl[((size_t)kt * D + jt0 * 16 + m) * 4 + g4];
        acc0 = __builtin_amdgcn_mfma_f32_16x16x32_bf16(a, b0, acc0, 0, 0, 0);
        if (jt1 < 7) {
            bf16x8 b1 = wbl[((size_t)kt * D + jt1 * 16 + m) * 4 + g4];
            acc1 = __builtin_amdgcn_mfma_f32_16x16x32_bf16(a, b1, acc1, 0, 0, 0);
        }
    }

    #pragma unroll
    for (int r = 0; r < 4; ++r) {
        int t = g4 * 4 + r;
        int j0 = jt0 * 16 + m;
        so[t][j0] = acc0[r] + hin[(size_t)(t0 + t) * D + j0];
        if (jt1 < 7) {
            int j1 = jt1 * 16 + m;
            so[t][j1] = acc1[r] + hin[(size_t)(t0 + t) * D + j1];
        }
    }
    __syncthreads();

    for (int tt = 0; tt < 4; ++tt) {
        int t = w * 4 + tt;
        float x0 = so[t][lane];
        float x1 = (lane + 64 < D) ? so[t][lane + 64] : 0.f;
        float s1 = x0 + x1, s2 = x0*x0 + x1*x1;
        #pragma unroll
        for (int off = 32; off; off >>= 1) { s1 += __shfl_xor(s1, off, 64); s2 += __shfl_xor(s2, off, 64); }
        float mu = s1 * (1.f/112.f);
        float var = s2 * (1.f/112.f) - mu*mu;
        float rs = rsqrtf(var + 1e-5f);
        for (int ii = lane; ii < D; ii += 64)
            hout[(size_t)(t0 + t) * D + ii] = (so[t][ii] - mu) * rs * g[l*D + ii] + bta[l*D + ii];
    }
}

// ---------------- classifier: f32 output ----------------
__global__ __launch_bounds__(64) void cls_kernel(
    const float* __restrict__ h, const float* __restrict__ cw, const float* __restrict__ cb,
    float* __restrict__ out)
{
    int tid = threadIdx.x;
    if (tid < BATCH*2) {
        int b = tid >> 1, c = tid & 1;
        const float* hr = h + (size_t)b*SEQ*D;   // token s=0
        const float* wr = cw + c*D;
        float a = 0.f;
        for (int i = 0; i < D; ++i) a += hr[i]*wr[i];
        out[b*2 + c] = a + cb[c];
    }
}

// ---------------- ws-too-small sentinel (diagnostic) ----------------
__global__ void sentinel_kernel(float* __restrict__ out, int nel)
{
    int i = threadIdx.x;
    if (i < nel) out[i] = 1e30f;
}

extern "C" void kernel_launch(void* const* d_in, const int* in_sizes, int n_in,
                              void* d_out, int out_size, void* d_ws, size_t ws_size,
                              hipStream_t stream)
{
    const float* x      = (const float*)d_in[0];
    const int*   mask   = (const int*)  d_in[1];
    const float* grid   = (const float*)d_in[2];
    const float* qw     = (const float*)d_in[3];
    const float* qb     = (const float*)d_in[4];
    const float* kw     = (const float*)d_in[5];
    const float* kb     = (const float*)d_in[6];
    const float* vw     = (const float*)d_in[7];
    const float* vb     = (const float*)d_in[8];
    const float* ow     = (const float*)d_in[9];
    const float* ob     = (const float*)d_in[10];
    const float* ln1g   = (const float*)d_in[11];
    const float* ln1b   = (const float*)d_in[12];
    const float* ln2g   = (const float*)d_in[13];
    const float* ln2b   = (const float*)d_in[14];
    const float* base_w = (const float*)d_in[15];
    const float* spline_w = (const float*)d_in[16];
    const float* scaler = (const float*)d_in[17];
    const float* cls_w  = (const float*)d_in[18];
    const float* cls_b  = (const float*)d_in[19];

    size_t SZ   = (size_t)NTOK * D;            // 917504 floats per buffer
    size_t WBN  = (size_t)2 * NKT * D * 32;    // 229376 bf16 (kan weights)
    size_t WQN  = (size_t)2 * 4 * 336 * 32;    // 86016 bf16 (qkv weights)
    size_t WON  = (size_t)2 * 4 * D * 32;      // 28672 bf16 (oproj weights)
    size_t need = 6*SZ*sizeof(float) + (WBN + WQN + WON)*sizeof(unsigned short) + 256;
    if (ws_size < need) {
        sentinel_kernel<<<1, 64, 0, stream>>>((float*)d_out, out_size);
        return;
    }
    float* ws = (float*)d_ws;
    float* q   = ws;
    float* k   = q + SZ;
    float* v   = k + SZ;
    float* ctx = v + SZ;
    float* hA  = ctx + SZ;
    float* hB  = hA + SZ;
    unsigned short* wbuf  = (unsigned short*)(hB + SZ);
    unsigned short* wqkv  = wbuf + WBN;
    unsigned short* wobuf = wqkv + WQN;

    int gstride = (in_sizes[2] == NKNOT) ? 0 : NKNOT;

    wb_prep_kernel<<<(int)((WBN + 255)/256), 256, 0, stream>>>(base_w, spline_w, scaler, wbuf);
    wqkv_prep_kernel<<<(int)((WQN + 255)/256), 256, 0, stream>>>(qw, kw, vw, wqkv);
    wo_prep_kernel<<<(int)((WON + 255)/256), 256, 0, stream>>>(ow, wobuf);

    const float* hin = x;
    for (int l = 0; l < 2; ++l) {
        qkv_mfma_kernel<<<NTOK/TM, 256, 0, stream>>>(hin, wqkv, qb, kb, vb, l, q, k, v);
        attn_mfma_kernel<<<BATCH*HEADS*2, 256, 0, stream>>>(q, k, v, mask, ctx);
        oproj_ln_v2_kernel<<<NTOK/TM, 256, 0, stream>>>(ctx, hin, wobuf, ob, ln1g, ln1b, l, hA);
        kan_ln_v3_kernel<<<NTOK/TM, 256, 0, stream>>>(hA, grid, wbuf, ln2g, ln2b, l, gstride, hB);
        hin = hB;
    }
    cls_kernel<<<1, 64, 0, stream>>>(hB, cls_w, cls_b, (float*)d_out);
}

// Round 17
// 224.797 us; speedup vs baseline: 1.4387x; 1.1336x over previous
//
#include <hip/hip_runtime.h>
#include <hip/hip_bf16.h>

#define D 112
#define HEADS 28
#define HDIM 4
#define SEQ 512
#define BATCH 16
#define NTOK (BATCH*SEQ)
#define NBASES 8
#define NKNOT 12
#define KTOT (D*9)          // 1008 real K for KAN; padded to 1024
#define KPAD 1024
#define NKT (KPAD/32)       // 32 K-steps (KAN)
#define TM 16               // tokens per block in GEMM kernels
#define QJT 21              // 336/16 j-tiles in fused qkv GEMM
#define PST 20              // P-tile row stride (words): aligned b128 reads, uniform banks
#define LOG2E 1.44269504088896f
#define ATTN_BIAS (-23.0831169f)   // -16*log2(e)

typedef __attribute__((ext_vector_type(8))) __bf16 bf16x8;
typedef __attribute__((ext_vector_type(4))) float f32x4;

__device__ __forceinline__ unsigned short f2bf(float f) {
    unsigned u = __float_as_uint(f);
    unsigned r = u + 0x7FFFu + ((u >> 16) & 1u);   // RNE
    return (unsigned short)(r >> 16);
}

__device__ __forceinline__ unsigned cvt_pk_bf16(float lo, float hi) {
    unsigned r;
    asm("v_cvt_pk_bf16_f32 %0, %1, %2" : "=v"(r) : "v"(lo), "v"(hi));
    return r;
}

// ---------------- weight prep: qkv concat -> bf16 B-fragment layout ----------------
__global__ void wqkv_prep_kernel(
    const float* __restrict__ qw, const float* __restrict__ kw, const float* __restrict__ vw,
    unsigned short* __restrict__ wq)
{
    int idx = blockIdx.x * 256 + threadIdx.x;
    if (idx >= 2*4*336*32) return;
    int kk = idx & 31;
    int j  = (idx >> 5) % 336;
    int kt = ((idx >> 5) / 336) & 3;
    int l  = idx / (32*336*4);
    int i = kt*32 + kk;
    float val = 0.f;
    if (i < D) {
        int mo = j / D, jj = j % D;
        const float* src = (mo==0) ? qw : (mo==1) ? kw : vw;
        val = src[((size_t)l*D + jj)*D + i];
    }
    wq[idx] = f2bf(val);
}

// ---------------- weight prep: oproj -> bf16 B-fragment layout ----------------
__global__ void wo_prep_kernel(const float* __restrict__ ow, unsigned short* __restrict__ wo)
{
    int idx = blockIdx.x * 256 + threadIdx.x;
    if (idx >= 2*4*D*32) return;
    int kk = idx & 31;
    int j  = (idx >> 5) % D;
    int kt = ((idx >> 5) / D) & 3;
    int l  = idx / (32*D*4);
    int i = kt*32 + kk;
    float val = (i < D) ? ow[((size_t)l*D + j)*D + i] : 0.f;
    wo[idx] = f2bf(val);
}

// ---------------- fused QKV via MFMA (16 tokens/block, 4 waves, 21 j-tiles) ----------------
__global__ __launch_bounds__(256) void qkv_mfma_kernel(
    const float* __restrict__ hin, const unsigned short* __restrict__ wq,
    const float* __restrict__ qb, const float* __restrict__ kb, const float* __restrict__ vb,
    int l, float* __restrict__ q, float* __restrict__ k, float* __restrict__ v)
{
    __shared__ __align__(16) unsigned short act[TM][136];   // 16 x (128+8 pad)
    int tid = threadIdx.x;
    int t0 = blockIdx.x * TM;
    for (int e = tid; e < TM*D; e += 256) {
        int t = e / D, i = e % D;
        act[t][i] = f2bf(hin[(size_t)(t0 + t)*D + i]);
    }
    for (int e = tid; e < TM*16; e += 256) act[e/16][D + (e%16)] = 0;
    __syncthreads();

    int w = tid >> 6, lane = tid & 63, m = lane & 15, g4 = lane >> 4;
    f32x4 acc[6];
    #pragma unroll
    for (int qq = 0; qq < 6; ++qq) acc[qq] = (f32x4){0.f,0.f,0.f,0.f};
    const bf16x8* wql = (const bf16x8*)wq + (size_t)l*4*336*4;
    #pragma unroll
    for (int kt = 0; kt < 4; ++kt) {
        bf16x8 a = *(const bf16x8*)&act[m][kt*32 + g4*8];
        #pragma unroll
        for (int qq = 0; qq < 6; ++qq) {
            int jt = w + 4*qq;
            if (jt < QJT) {
                bf16x8 bf = wql[((size_t)kt*336 + jt*16 + m)*4 + g4];
                acc[qq] = __builtin_amdgcn_mfma_f32_16x16x32_bf16(a, bf, acc[qq], 0, 0, 0);
            }
        }
    }
    #pragma unroll
    for (int qq = 0; qq < 6; ++qq) {
        int jt = w + 4*qq;
        if (jt >= QJT) continue;
        int j = jt*16 + m;
        int mo = j / D, jj = j % D;
        const float* bb = (mo==0) ? qb : (mo==1) ? kb : vb;
        float bias = bb[l*D + jj];
        float scl = (mo==0) ? 0.5f*LOG2E : 1.0f;
        float* dst = (mo==0) ? q : (mo==1) ? k : v;
        int h = jj >> 2, hd = jj & 3;
        #pragma unroll
        for (int r = 0; r < 4; ++r) {
            int n = t0 + g4*4 + r;
            int bi = n >> 9, s = n & 511;
            dst[((size_t)(bi*HEADS + h)*SEQ + s)*HDIM + hd] = (acc[qq][r] + bias)*scl;
        }
    }
}

// ---------------- attention via MFMA: 4-way q-split + double-buffered pipelined P ---------
// Block = quarter of a (b,h): 128 queries, 4 waves x 2 q-tiles. Two independent 32-key
// chunks in flight per iteration (double-buffered P tiles) for ILP; P stride PST=20 words
// gives 16B-aligned, bank-uniform b128 reads. Mask folded into score MFMA via K slot 4.
__global__ __launch_bounds__(256) void attn_mfma_kernel(
    const float* __restrict__ q, const float* __restrict__ k, const float* __restrict__ v,
    const int* __restrict__ mask, float* __restrict__ ctx)
{
    __shared__ __align__(16) unsigned short kpack[SEQ][8];   // k0..3, mf, 0,0,0   (8KB)
    __shared__ __align__(16) unsigned short qpack[128][8];   // q0..3, 1.0, 0,0,0  (2KB)
    __shared__ __align__(16) unsigned short vT[4][SEQ];      // V^T                (4KB)
    __shared__ __align__(16) uint4 zfrag;                    // 16B zeros
    __shared__ __align__(16) unsigned int plds[4][2][16*PST]; // per-wave 2-buf P (10KB)

    int tid = threadIdx.x;
    int bh = blockIdx.x >> 2, qh = blockIdx.x & 3;
    int b = bh / HEADS, h = bh % HEADS;

    if (tid == 0) zfrag = (uint4){0,0,0,0};
    const float4* kk = (const float4*)k + (size_t)bh*SEQ;
    const float4* vv = (const float4*)v + (size_t)bh*SEQ;
    for (int s = tid; s < SEQ; s += 256) {
        float4 kf = kk[s];
        float mf = mask[b*SEQ + s] ? ATTN_BIAS : -1e9f;
        uint4 pk;
        pk.x = cvt_pk_bf16(kf.x, kf.y);
        pk.y = cvt_pk_bf16(kf.z, kf.w);
        pk.z = cvt_pk_bf16(mf, 0.f);
        pk.w = 0;
        *(uint4*)&kpack[s][0] = pk;
        float4 vf = vv[s];
        vT[0][s] = f2bf(vf.x); vT[1][s] = f2bf(vf.y);
        vT[2][s] = f2bf(vf.z); vT[3][s] = f2bf(vf.w);
    }
    if (tid < 128) {
        int s = qh*128 + tid;
        float4 qf = ((const float4*)q)[(size_t)bh*SEQ + s];
        uint4 pk;
        pk.x = cvt_pk_bf16(qf.x, qf.y);
        pk.y = cvt_pk_bf16(qf.z, qf.w);
        pk.z = cvt_pk_bf16(1.0f, 0.f);
        pk.w = 0;
        *(uint4*)&qpack[tid][0] = pk;
    }
    __syncthreads();

    int w = tid >> 6, lane = tid & 63, ln = lane & 15, g4 = lane >> 4;
    const bf16x8* zf = (const bf16x8*)&zfrag;
    unsigned int* pw0 = &plds[w][0][0];
    unsigned int* pw1 = &plds[w][1][0];

    for (int qt = 0; qt < 2; ++qt) {
        int q0 = w*32 + qt*16;    // block-local query base
        bf16x8 qfrag = (g4 == 0) ? *(const bf16x8*)&qpack[q0 + ln][0] : *zf;
        f32x4 oacc = {0.f,0.f,0.f,0.f};
        float sum = 0.f;
        #pragma unroll 2
        for (int kb = 0; kb < SEQ; kb += 64) {
            int kcA = kb, kcB = kb + 32;
            bf16x8 kaA0 = (g4 == 0) ? *(const bf16x8*)&kpack[kcA + ln][0]      : *zf;
            bf16x8 kaA1 = (g4 == 0) ? *(const bf16x8*)&kpack[kcA + 16 + ln][0] : *zf;
            bf16x8 kaB0 = (g4 == 0) ? *(const bf16x8*)&kpack[kcB + ln][0]      : *zf;
            bf16x8 kaB1 = (g4 == 0) ? *(const bf16x8*)&kpack[kcB + 16 + ln][0] : *zf;
            f32x4 sA0 = __builtin_amdgcn_mfma_f32_16x16x32_bf16(kaA0, qfrag, (f32x4){0.f,0.f,0.f,0.f}, 0, 0, 0);
            f32x4 sA1 = __builtin_amdgcn_mfma_f32_16x16x32_bf16(kaA1, qfrag, (f32x4){0.f,0.f,0.f,0.f}, 0, 0, 0);
            f32x4 sB0 = __builtin_amdgcn_mfma_f32_16x16x32_bf16(kaB0, qfrag, (f32x4){0.f,0.f,0.f,0.f}, 0, 0, 0);
            f32x4 sB1 = __builtin_amdgcn_mfma_f32_16x16x32_bf16(kaB1, qfrag, (f32x4){0.f,0.f,0.f,0.f}, 0, 0, 0);
            // chunk A: exp + pack + stage
            float a00 = __builtin_exp2f(sA0[0]), a01 = __builtin_exp2f(sA0[1]);
            float a02 = __builtin_exp2f(sA0[2]), a03 = __builtin_exp2f(sA0[3]);
            float a10 = __builtin_exp2f(sA1[0]), a11 = __builtin_exp2f(sA1[1]);
            float a12 = __builtin_exp2f(sA1[2]), a13 = __builtin_exp2f(sA1[3]);
            // chunk B: exp + pack + stage (independent chain)
            float b00 = __builtin_exp2f(sB0[0]), b01 = __builtin_exp2f(sB0[1]);
            float b02 = __builtin_exp2f(sB0[2]), b03 = __builtin_exp2f(sB0[3]);
            float b10 = __builtin_exp2f(sB1[0]), b11 = __builtin_exp2f(sB1[1]);
            float b12 = __builtin_exp2f(sB1[2]), b13 = __builtin_exp2f(sB1[3]);
            sum += ((a00 + a01) + (a02 + a03)) + ((a10 + a11) + (a12 + a13))
                 + ((b00 + b01) + (b02 + b03)) + ((b10 + b11) + (b12 + b13));
            uint2 wA0 = {cvt_pk_bf16(a00, a01), cvt_pk_bf16(a02, a03)};
            uint2 wA1 = {cvt_pk_bf16(a10, a11), cvt_pk_bf16(a12, a13)};
            uint2 wB0 = {cvt_pk_bf16(b00, b01), cvt_pk_bf16(b02, b03)};
            uint2 wB1 = {cvt_pk_bf16(b10, b11), cvt_pk_bf16(b12, b13)};
            *(uint2*)&pw0[ln*PST + g4*2]     = wA0;
            *(uint2*)&pw0[ln*PST + 8 + g4*2] = wA1;
            *(uint2*)&pw1[ln*PST + g4*2]     = wB0;
            *(uint2*)&pw1[ln*PST + 8 + g4*2] = wB1;
            // PV for both chunks
            bf16x8 paA = *(const bf16x8*)&pw0[ln*PST + g4*4];
            bf16x8 vbA = (ln < 4) ? *(const bf16x8*)&vT[ln][kcA + g4*8] : *zf;
            oacc = __builtin_amdgcn_mfma_f32_16x16x32_bf16(paA, vbA, oacc, 0, 0, 0);
            bf16x8 paB = *(const bf16x8*)&pw1[ln*PST + g4*4];
            bf16x8 vbB = (ln < 4) ? *(const bf16x8*)&vT[ln][kcB + g4*8] : *zf;
            oacc = __builtin_amdgcn_mfma_f32_16x16x32_bf16(paB, vbB, oacc, 0, 0, 0);
        }
        // sum reduce across the 4 g4 groups (same query col ln)
        sum += __shfl_xor(sum, 16, 64);
        sum += __shfl_xor(sum, 32, 64);
        float inv = 1.f / sum;                  // lane: total for query ln
        float i0 = __shfl(inv, g4*4 + 0, 64);
        float i1 = __shfl(inv, g4*4 + 1, 64);
        float i2 = __shfl(inv, g4*4 + 2, 64);
        float i3 = __shfl(inv, g4*4 + 3, 64);
        if (ln < 4) {
            size_t base = (size_t)(b*SEQ + qh*128 + q0 + g4*4);
            ctx[(base + 0)*D + h*4 + ln] = oacc[0] * i0;
            ctx[(base + 1)*D + h*4 + ln] = oacc[1] * i1;
            ctx[(base + 2)*D + h*4 + ln] = oacc[2] * i2;
            ctx[(base + 3)*D + h*4 + ln] = oacc[3] * i3;
        }
    }
}

// ---------------- O-projection via MFMA + residual + LN1 (16 tokens/block) ----------------
__global__ __launch_bounds__(256) void oproj_ln_v2_kernel(
    const float* __restrict__ ctx, const float* __restrict__ hin,
    const unsigned short* __restrict__ wo, const float* __restrict__ ob,
    const float* __restrict__ g, const float* __restrict__ bta,
    int l, float* __restrict__ hout)
{
    __shared__ __align__(16) unsigned short act[TM][136];
    __shared__ float so[TM][D];
    int tid = threadIdx.x;
    int t0 = blockIdx.x * TM;
    for (int e = tid; e < TM*D; e += 256) {
        int t = e / D, i = e % D;
        act[t][i] = f2bf(ctx[(size_t)(t0 + t)*D + i]);
    }
    for (int e = tid; e < TM*16; e += 256) act[e/16][D + (e%16)] = 0;
    __syncthreads();

    int w = tid >> 6, lane = tid & 63, m = lane & 15, g4 = lane >> 4;
    int jt0 = 2*w, jt1 = 2*w + 1;
    f32x4 acc0 = {0.f,0.f,0.f,0.f}, acc1 = {0.f,0.f,0.f,0.f};
    const bf16x8* wol = (const bf16x8*)wo + (size_t)l*4*D*4;
    #pragma unroll
    for (int kt = 0; kt < 4; ++kt) {
        bf16x8 a = *(const bf16x8*)&act[m][kt*32 + g4*8];
        bf16x8 b0 = wol[((size_t)kt*D + jt0*16 + m)*4 + g4];
        acc0 = __builtin_amdgcn_mfma_f32_16x16x32_bf16(a, b0, acc0, 0, 0, 0);
        if (jt1 < 7) {
            bf16x8 b1 = wol[((size_t)kt*D + jt1*16 + m)*4 + g4];
            acc1 = __builtin_amdgcn_mfma_f32_16x16x32_bf16(a, b1, acc1, 0, 0, 0);
        }
    }
    #pragma unroll
    for (int r = 0; r < 4; ++r) {
        int t = g4*4 + r;
        int j0 = jt0*16 + m;
        so[t][j0] = acc0[r] + ob[l*D + j0] + hin[(size_t)(t0 + t)*D + j0];
        if (jt1 < 7) {
            int j1 = jt1*16 + m;
            so[t][j1] = acc1[r] + ob[l*D + j1] + hin[(size_t)(t0 + t)*D + j1];
        }
    }
    __syncthreads();

    for (int tt = 0; tt < 4; ++tt) {
        int t = w*4 + tt;
        float x0 = so[t][lane];
        float x1 = (lane + 64 < D) ? so[t][lane + 64] : 0.f;
        float s1 = x0 + x1, s2 = x0*x0 + x1*x1;
        #pragma unroll
        for (int off = 32; off; off >>= 1) { s1 += __shfl_xor(s1, off, 64); s2 += __shfl_xor(s2, off, 64); }
        float mu = s1 * (1.f/112.f);
        float var = s2 * (1.f/112.f) - mu*mu;
        float rs = rsqrtf(var + 1e-5f);
        for (int ii = lane; ii < D; ii += 64)
            hout[(size_t)(t0 + t)*D + ii] = (so[t][ii] - mu)*rs*g[l*D + ii] + bta[l*D + ii];
    }
}

// ---------------- Wb prep: fold (spline_w*scaler, base_w) into bf16 B-fragment layout ----
__global__ void wb_prep_kernel(
    const float* __restrict__ base_w, const float* __restrict__ spline_w,
    const float* __restrict__ scaler, unsigned short* __restrict__ wb)
{
    int idx = blockIdx.x * 256 + threadIdx.x;
    if (idx >= 2 * NKT * D * 32) return;
    int kk = idx & 31;
    int j  = (idx >> 5) % D;
    int kt = ((idx >> 5) / D) % NKT;
    int l  = idx / (32 * D * NKT);
    int k = kt * 32 + kk;
    float val = 0.f;
    if (k < KTOT) {
        int i = k / 9, b = k % 9;
        size_t ji = ((size_t)l * D + j) * D + i;
        val = (b == 8) ? base_w[ji] : spline_w[ji * NBASES + b] * scaler[ji];
    }
    wb[idx] = f2bf(val);
}

// ---------------- KAN via bf16 MFMA + residual + LN2 (16 tokens/block, 4 waves) ---------
__global__ __launch_bounds__(256) void kan_ln_v3_kernel(
    const float* __restrict__ hin, const float* __restrict__ grid,
    const unsigned short* __restrict__ wb,
    const float* __restrict__ g, const float* __restrict__ bta,
    int l, int gstride, float* __restrict__ hout)
{
    __shared__ __align__(16) unsigned short act_lds[TM][1032];  // row pad -> 2-way bank (free)
    __shared__ float so[TM][D];
    int tid = threadIdx.x;
    int t0 = blockIdx.x * TM;

    for (int e = tid; e < TM * D; e += 256) {
        int t = e / D, i = e % D;
        float xv = hin[(size_t)(t0 + t) * D + i];
        float si = xv / (1.f + __expf(-xv));
        const float* grp = grid + i * gstride;
        float gr[NKNOT];
        #pragma unroll
        for (int ii = 0; ii < NKNOT; ++ii) gr[ii] = grp[ii];
        float bs[11];
        #pragma unroll
        for (int ii = 0; ii < 11; ++ii) bs[ii] = (xv >= gr[ii] && xv < gr[ii+1]) ? 1.f : 0.f;
        #pragma unroll
        for (int kk = 1; kk <= 3; ++kk) {
            #pragma unroll
            for (int ii = 0; ii + kk <= 10; ++ii) {
                float left  = (xv - gr[ii]) / (gr[ii+kk] - gr[ii]) * bs[ii];
                float right = (gr[ii+kk+1] - xv) / (gr[ii+kk+1] - gr[ii+1]) * bs[ii+1];
                bs[ii] = left + right;
            }
        }
        unsigned short* arow = &act_lds[t][i * 9];
        #pragma unroll
        for (int b = 0; b < 8; ++b) arow[b] = f2bf(bs[b]);
        arow[8] = f2bf(si);
    }
    for (int e = tid; e < TM * 24; e += 256)
        act_lds[e / 24][KTOT + e % 24] = 0;
    __syncthreads();

    int w = tid >> 6, lane = tid & 63;
    int m = lane & 15, g4 = lane >> 4;
    int jt0 = 2 * w, jt1 = 2 * w + 1;
    f32x4 acc0 = {0.f,0.f,0.f,0.f}, acc1 = {0.f,0.f,0.f,0.f};
    const bf16x8* wbl = (const bf16x8*)wb + (size_t)l * NKT * D * 4;
    #pragma unroll 4
    for (int kt = 0; kt < NKT; ++kt) {
        bf16x8 a = *(const bf16x8*)&act_lds[m][kt * 32 + g4 * 8];
        bf16x8 b0 = wbl[((size_t)kt * D + jt0 * 16 + m) * 4 + g4];
        acc0 = __builtin_amdgcn_mfma_f32_16x16x32_bf16(a, b0, acc0, 0, 0, 0);
        if (jt1 < 7) {
            bf16x8 b1 = wbl[((size_t)kt * D + jt1 * 16 + m) * 4 + g4];
            acc1 = __builtin_amdgcn_mfma_f32_16x16x32_bf16(a, b1, acc1, 0, 0, 0);
        }
    }

    #pragma unroll
    for (int r = 0; r < 4; ++r) {
        int t = g4 * 4 + r;
        int j0 = jt0 * 16 + m;
        so[t][j0] = acc0[r] + hin[(size_t)(t0 + t) * D + j0];
        if (jt1 < 7) {
            int j1 = jt1 * 16 + m;
            so[t][j1] = acc1[r] + hin[(size_t)(t0 + t) * D + j1];
        }
    }
    __syncthreads();

    for (int tt = 0; tt < 4; ++tt) {
        int t = w * 4 + tt;
        float x0 = so[t][lane];
        float x1 = (lane + 64 < D) ? so[t][lane + 64] : 0.f;
        float s1 = x0 + x1, s2 = x0*x0 + x1*x1;
        #pragma unroll
        for (int off = 32; off; off >>= 1) { s1 += __shfl_xor(s1, off, 64); s2 += __shfl_xor(s2, off, 64); }
        float mu = s1 * (1.f/112.f);
        float var = s2 * (1.f/112.f) - mu*mu;
        float rs = rsqrtf(var + 1e-5f);
        for (int ii = lane; ii < D; ii += 64)
            hout[(size_t)(t0 + t) * D + ii] = (so[t][ii] - mu) * rs * g[l*D + ii] + bta[l*D + ii];
    }
}

// ---------------- classifier: f32 output ----------------
__global__ __launch_bounds__(64) void cls_kernel(
    const float* __restrict__ h, const float* __restrict__ cw, const float* __restrict__ cb,
    float* __restrict__ out)
{
    int tid = threadIdx.x;
    if (tid < BATCH*2) {
        int b = tid >> 1, c = tid & 1;
        const float* hr = h + (size_t)b*SEQ*D;   // token s=0
        const float* wr = cw + c*D;
        float a = 0.f;
        for (int i = 0; i < D; ++i) a += hr[i]*wr[i];
        out[b*2 + c] = a + cb[c];
    }
}

// ---------------- ws-too-small sentinel (diagnostic) ----------------
__global__ void sentinel_kernel(float* __restrict__ out, int nel)
{
    int i = threadIdx.x;
    if (i < nel) out[i] = 1e30f;
}

extern "C" void kernel_launch(void* const* d_in, const int* in_sizes, int n_in,
                              void* d_out, int out_size, void* d_ws, size_t ws_size,
                              hipStream_t stream)
{
    const float* x      = (const float*)d_in[0];
    const int*   mask   = (const int*)  d_in[1];
    const float* grid   = (const float*)d_in[2];
    const float* qw     = (const float*)d_in[3];
    const float* qb     = (const float*)d_in[4];
    const float* kw     = (const float*)d_in[5];
    const float* kb     = (const float*)d_in[6];
    const float* vw     = (const float*)d_in[7];
    const float* vb     = (const float*)d_in[8];
    const float* ow     = (const float*)d_in[9];
    const float* ob     = (const float*)d_in[10];
    const float* ln1g   = (const float*)d_in[11];
    const float* ln1b   = (const float*)d_in[12];
    const float* ln2g   = (const float*)d_in[13];
    const float* ln2b   = (const float*)d_in[14];
    const float* base_w = (const float*)d_in[15];
    const float* spline_w = (const float*)d_in[16];
    const float* scaler = (const float*)d_in[17];
    const float* cls_w  = (const float*)d_in[18];
    const float* cls_b  = (const float*)d_in[19];

    size_t SZ   = (size_t)NTOK * D;            // 917504 floats per buffer
    size_t WBN  = (size_t)2 * NKT * D * 32;    // 229376 bf16 (kan weights)
    size_t WQN  = (size_t)2 * 4 * 336 * 32;    // 86016 bf16 (qkv weights)
    size_t WON  = (size_t)2 * 4 * D * 32;      // 28672 bf16 (oproj weights)
    size_t need = 6*SZ*sizeof(float) + (WBN + WQN + WON)*sizeof(unsigned short) + 256;
    if (ws_size < need) {
        sentinel_kernel<<<1, 64, 0, stream>>>((float*)d_out, out_size);
        return;
    }
    float* ws = (float*)d_ws;
    float* q   = ws;
    float* k   = q + SZ;
    float* v   = k + SZ;
    float* ctx = v + SZ;
    float* hA  = ctx + SZ;
    float* hB  = hA + SZ;
    unsigned short* wbuf  = (unsigned short*)(hB + SZ);
    unsigned short* wqkv  = wbuf + WBN;
    unsigned short* wobuf = wqkv + WQN;

    int gstride = (in_sizes[2] == NKNOT) ? 0 : NKNOT;

    wb_prep_kernel<<<(int)((WBN + 255)/256), 256, 0, stream>>>(base_w, spline_w, scaler, wbuf);
    wqkv_prep_kernel<<<(int)((WQN + 255)/256), 256, 0, stream>>>(qw, kw, vw, wqkv);
    wo_prep_kernel<<<(int)((WON + 255)/256), 256, 0, stream>>>(ow, wobuf);

    const float* hin = x;
    for (int l = 0; l < 2; ++l) {
        qkv_mfma_kernel<<<NTOK/TM, 256, 0, stream>>>(hin, wqkv, qb, kb, vb, l, q, k, v);
        attn_mfma_kernel<<<BATCH*HEADS*4, 256, 0, stream>>>(q, k, v, mask, ctx);
        oproj_ln_v2_kernel<<<NTOK/TM, 256, 0, stream>>>(ctx, hin, wobuf, ob, ln1g, ln1b, l, hA);
        kan_ln_v3_kernel<<<NTOK/TM, 256, 0, stream>>>(hA, grid, wbuf, ln2g, ln2b, l, gstride, hB);
        hin = hB;
    }
    cls_kernel<<<1, 64, 0, stream>>>(hB, cls_w, cls_b, (float*)d_out);
}

// Round 18
// 218.419 us; speedup vs baseline: 1.4807x; 1.0292x over previous
//
#include <hip/hip_runtime.h>
#include <hip/hip_bf16.h>

#define D 112
#define HEADS 28
#define HDIM 4
#define SEQ 512
#define BATCH 16
#define NTOK (BATCH*SEQ)
#define NBASES 8
#define NKNOT 12
#define KTOT (D*9)          // 1008 real K for KAN; padded to 1024
#define KPAD 1024
#define NKT (KPAD/32)       // 32 K-steps (KAN)
#define TM 16               // tokens per block in GEMM kernels
#define QJT 21              // 336/16 j-tiles in fused qkv GEMM
#define PST 20              // P-tile row stride (words)
#define VST 520             // vT row stride (bf16): breaks mod-32 bank alignment
#define LOG2E 1.44269504088896f
#define ATTN_BIAS (-23.0831169f)   // -16*log2(e)

typedef __attribute__((ext_vector_type(8))) __bf16 bf16x8;
typedef __attribute__((ext_vector_type(4))) float f32x4;

__device__ __forceinline__ unsigned short f2bf(float f) {
    unsigned u = __float_as_uint(f);
    unsigned r = u + 0x7FFFu + ((u >> 16) & 1u);   // RNE
    return (unsigned short)(r >> 16);
}

__device__ __forceinline__ unsigned cvt_pk_bf16(float lo, float hi) {
    unsigned r;
    asm("v_cvt_pk_bf16_f32 %0, %1, %2" : "=v"(r) : "v"(lo), "v"(hi));
    return r;
}

// ---------------- weight prep: qkv concat -> bf16 B-fragment layout ----------------
__global__ void wqkv_prep_kernel(
    const float* __restrict__ qw, const float* __restrict__ kw, const float* __restrict__ vw,
    unsigned short* __restrict__ wq)
{
    int idx = blockIdx.x * 256 + threadIdx.x;
    if (idx >= 2*4*336*32) return;
    int kk = idx & 31;
    int j  = (idx >> 5) % 336;
    int kt = ((idx >> 5) / 336) & 3;
    int l  = idx / (32*336*4);
    int i = kt*32 + kk;
    float val = 0.f;
    if (i < D) {
        int mo = j / D, jj = j % D;
        const float* src = (mo==0) ? qw : (mo==1) ? kw : vw;
        val = src[((size_t)l*D + jj)*D + i];
    }
    wq[idx] = f2bf(val);
}

// ---------------- weight prep: oproj -> bf16 B-fragment layout ----------------
__global__ void wo_prep_kernel(const float* __restrict__ ow, unsigned short* __restrict__ wo)
{
    int idx = blockIdx.x * 256 + threadIdx.x;
    if (idx >= 2*4*D*32) return;
    int kk = idx & 31;
    int j  = (idx >> 5) % D;
    int kt = ((idx >> 5) / D) & 3;
    int l  = idx / (32*D*4);
    int i = kt*32 + kk;
    float val = (i < D) ? ow[((size_t)l*D + j)*D + i] : 0.f;
    wo[idx] = f2bf(val);
}

// ---------------- fused QKV via MFMA (16 tokens/block, 4 waves, 21 j-tiles) ----------------
__global__ __launch_bounds__(256) void qkv_mfma_kernel(
    const float* __restrict__ hin, const unsigned short* __restrict__ wq,
    const float* __restrict__ qb, const float* __restrict__ kb, const float* __restrict__ vb,
    int l, float* __restrict__ q, float* __restrict__ k, float* __restrict__ v)
{
    __shared__ __align__(16) unsigned short act[TM][136];   // 16 x (128+8 pad)
    int tid = threadIdx.x;
    int t0 = blockIdx.x * TM;
    for (int e = tid; e < TM*D; e += 256) {
        int t = e / D, i = e % D;
        act[t][i] = f2bf(hin[(size_t)(t0 + t)*D + i]);
    }
    for (int e = tid; e < TM*16; e += 256) act[e/16][D + (e%16)] = 0;
    __syncthreads();

    int w = tid >> 6, lane = tid & 63, m = lane & 15, g4 = lane >> 4;
    f32x4 acc[6];
    #pragma unroll
    for (int qq = 0; qq < 6; ++qq) acc[qq] = (f32x4){0.f,0.f,0.f,0.f};
    const bf16x8* wql = (const bf16x8*)wq + (size_t)l*4*336*4;
    #pragma unroll
    for (int kt = 0; kt < 4; ++kt) {
        bf16x8 a = *(const bf16x8*)&act[m][kt*32 + g4*8];
        #pragma unroll
        for (int qq = 0; qq < 6; ++qq) {
            int jt = w + 4*qq;
            if (jt < QJT) {
                bf16x8 bf = wql[((size_t)kt*336 + jt*16 + m)*4 + g4];
                acc[qq] = __builtin_amdgcn_mfma_f32_16x16x32_bf16(a, bf, acc[qq], 0, 0, 0);
            }
        }
    }
    #pragma unroll
    for (int qq = 0; qq < 6; ++qq) {
        int jt = w + 4*qq;
        if (jt >= QJT) continue;
        int j = jt*16 + m;
        int mo = j / D, jj = j % D;
        const float* bb = (mo==0) ? qb : (mo==1) ? kb : vb;
        float bias = bb[l*D + jj];
        float scl = (mo==0) ? 0.5f*LOG2E : 1.0f;
        float* dst = (mo==0) ? q : (mo==1) ? k : v;
        int h = jj >> 2, hd = jj & 3;
        #pragma unroll
        for (int r = 0; r < 4; ++r) {
            int n = t0 + g4*4 + r;
            int bi = n >> 9, s = n & 511;
            dst[((size_t)(bi*HEADS + h)*SEQ + s)*HDIM + hd] = (acc[qq][r] + bias)*scl;
        }
    }
}

// ---------------- attention via MFMA: ones-column softmax sums on the matrix pipe ---------
// Block = quarter (b,h): 128 queries. Score: S^T = K.Q^T (mask bias in K slot 4).
// PV B-operand = V^T with a 5th row of ones -> output col 4 = softmax denominators.
__global__ __launch_bounds__(256) void attn_mfma_kernel(
    const float* __restrict__ q, const float* __restrict__ k, const float* __restrict__ v,
    const int* __restrict__ mask, float* __restrict__ ctx)
{
    __shared__ __align__(16) unsigned short kpack[SEQ][8];    // k0..3, mf, 0,0,0   (8KB)
    __shared__ __align__(16) unsigned short qpack[128][8];    // q0..3, 1.0, 0,0,0  (2KB)
    __shared__ __align__(16) unsigned short vT[5][VST];       // V^T + ones row     (5.1KB)
    __shared__ __align__(16) uint4 zfrag;
    __shared__ __align__(16) unsigned int plds[4][2][16*PST]; // per-wave 2-buf P   (10KB)

    int tid = threadIdx.x;
    int bh = blockIdx.x >> 2, qh = blockIdx.x & 3;
    int b = bh / HEADS, h = bh % HEADS;

    if (tid == 0) zfrag = (uint4){0,0,0,0};
    const float4* kk = (const float4*)k + (size_t)bh*SEQ;
    const float4* vv = (const float4*)v + (size_t)bh*SEQ;
    for (int s = tid; s < SEQ; s += 256) {
        float4 kf = kk[s];
        float mf = mask[b*SEQ + s] ? ATTN_BIAS : -1e9f;
        uint4 pk;
        pk.x = cvt_pk_bf16(kf.x, kf.y);
        pk.y = cvt_pk_bf16(kf.z, kf.w);
        pk.z = cvt_pk_bf16(mf, 0.f);
        pk.w = 0;
        *(uint4*)&kpack[s][0] = pk;
        float4 vf = vv[s];
        vT[0][s] = f2bf(vf.x); vT[1][s] = f2bf(vf.y);
        vT[2][s] = f2bf(vf.z); vT[3][s] = f2bf(vf.w);
        vT[4][s] = 0x3F80;   // bf16 1.0 -> denominator column
    }
    if (tid < 128) {
        int s = qh*128 + tid;
        float4 qf = ((const float4*)q)[(size_t)bh*SEQ + s];
        uint4 pk;
        pk.x = cvt_pk_bf16(qf.x, qf.y);
        pk.y = cvt_pk_bf16(qf.z, qf.w);
        pk.z = cvt_pk_bf16(1.0f, 0.f);
        pk.w = 0;
        *(uint4*)&qpack[tid][0] = pk;
    }
    __syncthreads();

    int w = tid >> 6, lane = tid & 63, ln = lane & 15, g4 = lane >> 4;
    const bf16x8* zf = (const bf16x8*)&zfrag;
    unsigned int* pw0 = &plds[w][0][0];
    unsigned int* pw1 = &plds[w][1][0];

    for (int qt = 0; qt < 2; ++qt) {
        int q0 = w*32 + qt*16;    // block-local query base
        bf16x8 qfrag = (g4 == 0) ? *(const bf16x8*)&qpack[q0 + ln][0] : *zf;
        f32x4 oacc = {0.f,0.f,0.f,0.f};
        #pragma unroll 2
        for (int kb = 0; kb < SEQ; kb += 64) {
            int kcA = kb, kcB = kb + 32;
            bf16x8 kaA0 = (g4 == 0) ? *(const bf16x8*)&kpack[kcA + ln][0]      : *zf;
            bf16x8 kaA1 = (g4 == 0) ? *(const bf16x8*)&kpack[kcA + 16 + ln][0] : *zf;
            bf16x8 kaB0 = (g4 == 0) ? *(const bf16x8*)&kpack[kcB + ln][0]      : *zf;
            bf16x8 kaB1 = (g4 == 0) ? *(const bf16x8*)&kpack[kcB + 16 + ln][0] : *zf;
            f32x4 sA0 = __builtin_amdgcn_mfma_f32_16x16x32_bf16(kaA0, qfrag, (f32x4){0.f,0.f,0.f,0.f}, 0, 0, 0);
            f32x4 sA1 = __builtin_amdgcn_mfma_f32_16x16x32_bf16(kaA1, qfrag, (f32x4){0.f,0.f,0.f,0.f}, 0, 0, 0);
            f32x4 sB0 = __builtin_amdgcn_mfma_f32_16x16x32_bf16(kaB0, qfrag, (f32x4){0.f,0.f,0.f,0.f}, 0, 0, 0);
            f32x4 sB1 = __builtin_amdgcn_mfma_f32_16x16x32_bf16(kaB1, qfrag, (f32x4){0.f,0.f,0.f,0.f}, 0, 0, 0);
            float a00 = __builtin_exp2f(sA0[0]), a01 = __builtin_exp2f(sA0[1]);
            float a02 = __builtin_exp2f(sA0[2]), a03 = __builtin_exp2f(sA0[3]);
            float a10 = __builtin_exp2f(sA1[0]), a11 = __builtin_exp2f(sA1[1]);
            float a12 = __builtin_exp2f(sA1[2]), a13 = __builtin_exp2f(sA1[3]);
            float b00 = __builtin_exp2f(sB0[0]), b01 = __builtin_exp2f(sB0[1]);
            float b02 = __builtin_exp2f(sB0[2]), b03 = __builtin_exp2f(sB0[3]);
            float b10 = __builtin_exp2f(sB1[0]), b11 = __builtin_exp2f(sB1[1]);
            float b12 = __builtin_exp2f(sB1[2]), b13 = __builtin_exp2f(sB1[3]);
            uint2 wA0 = {cvt_pk_bf16(a00, a01), cvt_pk_bf16(a02, a03)};
            uint2 wA1 = {cvt_pk_bf16(a10, a11), cvt_pk_bf16(a12, a13)};
            uint2 wB0 = {cvt_pk_bf16(b00, b01), cvt_pk_bf16(b02, b03)};
            uint2 wB1 = {cvt_pk_bf16(b10, b11), cvt_pk_bf16(b12, b13)};
            *(uint2*)&pw0[ln*PST + g4*2]     = wA0;
            *(uint2*)&pw0[ln*PST + 8 + g4*2] = wA1;
            *(uint2*)&pw1[ln*PST + g4*2]     = wB0;
            *(uint2*)&pw1[ln*PST + 8 + g4*2] = wB1;
            bf16x8 paA = *(const bf16x8*)&pw0[ln*PST + g4*4];
            bf16x8 vbA = (ln < 5) ? *(const bf16x8*)&vT[ln][kcA + g4*8] : *zf;
            oacc = __builtin_amdgcn_mfma_f32_16x16x32_bf16(paA, vbA, oacc, 0, 0, 0);
            bf16x8 paB = *(const bf16x8*)&pw1[ln*PST + g4*4];
            bf16x8 vbB = (ln < 5) ? *(const bf16x8*)&vT[ln][kcB + g4*8] : *zf;
            oacc = __builtin_amdgcn_mfma_f32_16x16x32_bf16(paB, vbB, oacc, 0, 0, 0);
        }
        // denominators live at lanes ln==4 (col 4), row r = query g4*4+r
        int src = g4*16 + 4;
        float s0 = __shfl(oacc[0], src, 64);
        float s1 = __shfl(oacc[1], src, 64);
        float s2 = __shfl(oacc[2], src, 64);
        float s3 = __shfl(oacc[3], src, 64);
        float i0 = __builtin_amdgcn_rcpf(s0);
        float i1 = __builtin_amdgcn_rcpf(s1);
        float i2 = __builtin_amdgcn_rcpf(s2);
        float i3 = __builtin_amdgcn_rcpf(s3);
        if (ln < 4) {
            size_t base = (size_t)(b*SEQ + qh*128 + q0 + g4*4);
            ctx[(base + 0)*D + h*4 + ln] = oacc[0] * i0;
            ctx[(base + 1)*D + h*4 + ln] = oacc[1] * i1;
            ctx[(base + 2)*D + h*4 + ln] = oacc[2] * i2;
            ctx[(base + 3)*D + h*4 + ln] = oacc[3] * i3;
        }
    }
}

// ---------------- Wb prep: fold (spline_w*scaler, base_w) into bf16 B-fragment layout ----
__global__ void wb_prep_kernel(
    const float* __restrict__ base_w, const float* __restrict__ spline_w,
    const float* __restrict__ scaler, unsigned short* __restrict__ wb)
{
    int idx = blockIdx.x * 256 + threadIdx.x;
    if (idx >= 2 * NKT * D * 32) return;
    int kk = idx & 31;
    int j  = (idx >> 5) % D;
    int kt = ((idx >> 5) / D) % NKT;
    int l  = idx / (32 * D * NKT);
    int k = kt * 32 + kk;
    float val = 0.f;
    if (k < KTOT) {
        int i = k / 9, b = k % 9;
        size_t ji = ((size_t)l * D + j) * D + i;
        val = (b == 8) ? base_w[ji] : spline_w[ji * NBASES + b] * scaler[ji];
    }
    wb[idx] = f2bf(val);
}

// ---------------- FUSED: oproj MFMA + res + LN1 + KAN MFMA + res + LN2 (16 tok/block) ----
__global__ __launch_bounds__(256) void oproj_kan_ln_kernel(
    const float* __restrict__ ctx, const float* __restrict__ hin,
    const unsigned short* __restrict__ wo, const float* __restrict__ ob,
    const float* __restrict__ g1, const float* __restrict__ b1,
    const float* __restrict__ grid, const unsigned short* __restrict__ wb,
    const float* __restrict__ g2, const float* __restrict__ b2,
    int l, int gstride, float* __restrict__ hout)
{
    __shared__ __align__(16) unsigned short abuf[TM*1032];  // union: oproj stride 136 / kan stride 1032
    __shared__ float so[TM][D];
    int tid = threadIdx.x;
    int t0 = blockIdx.x * TM;
    int w = tid >> 6, lane = tid & 63, m = lane & 15, g4 = lane >> 4;

    // ---- 1. stage ctx (bf16, stride 136, zero-padded cols) ----
    for (int e = tid; e < TM*136; e += 256) {
        int t = e / 136, i = e % 136;
        abuf[e] = (i < D) ? f2bf(ctx[(size_t)(t0 + t)*D + i]) : 0;
    }
    __syncthreads();

    // ---- 2. oproj MFMA + bias + residual -> so ----
    {
        int jt0 = 2*w, jt1 = 2*w + 1;
        f32x4 acc0 = {0.f,0.f,0.f,0.f}, acc1 = {0.f,0.f,0.f,0.f};
        const bf16x8* wol = (const bf16x8*)wo + (size_t)l*4*D*4;
        #pragma unroll
        for (int kt = 0; kt < 4; ++kt) {
            bf16x8 a = *(const bf16x8*)&abuf[m*136 + kt*32 + g4*8];
            bf16x8 b0 = wol[((size_t)kt*D + jt0*16 + m)*4 + g4];
            acc0 = __builtin_amdgcn_mfma_f32_16x16x32_bf16(a, b0, acc0, 0, 0, 0);
            if (jt1 < 7) {
                bf16x8 b1f = wol[((size_t)kt*D + jt1*16 + m)*4 + g4];
                acc1 = __builtin_amdgcn_mfma_f32_16x16x32_bf16(a, b1f, acc1, 0, 0, 0);
            }
        }
        #pragma unroll
        for (int r = 0; r < 4; ++r) {
            int t = g4*4 + r;
            int j0 = jt0*16 + m;
            so[t][j0] = acc0[r] + ob[l*D + j0] + hin[(size_t)(t0 + t)*D + j0];
            if (jt1 < 7) {
                int j1 = jt1*16 + m;
                so[t][j1] = acc1[r] + ob[l*D + j1] + hin[(size_t)(t0 + t)*D + j1];
            }
        }
    }
    __syncthreads();

    // ---- 3. LN1 in place on so ----
    for (int tt = 0; tt < 4; ++tt) {
        int t = w*4 + tt;
        float x0 = so[t][lane];
        float x1 = (lane + 64 < D) ? so[t][lane + 64] : 0.f;
        float s1 = x0 + x1, s2 = x0*x0 + x1*x1;
        #pragma unroll
        for (int off = 32; off; off >>= 1) { s1 += __shfl_xor(s1, off, 64); s2 += __shfl_xor(s2, off, 64); }
        float mu = s1 * (1.f/112.f);
        float var = s2 * (1.f/112.f) - mu*mu;
        float rs = rsqrtf(var + 1e-5f);
        so[t][lane] = (x0 - mu)*rs*g1[l*D + lane] + b1[l*D + lane];
        if (lane + 64 < D)
            so[t][lane+64] = (x1 - mu)*rs*g1[l*D + lane+64] + b1[l*D + lane+64];
    }
    __syncthreads();

    // ---- 4. spline basis + silu from so -> abuf (stride 1032) ----
    for (int e = tid; e < TM * D; e += 256) {
        int t = e / D, i = e % D;
        float xv = so[t][i];
        float si = xv / (1.f + __expf(-xv));
        const float* grp = grid + i * gstride;
        float gr[NKNOT];
        #pragma unroll
        for (int ii = 0; ii < NKNOT; ++ii) gr[ii] = grp[ii];
        float bs[11];
        #pragma unroll
        for (int ii = 0; ii < 11; ++ii) bs[ii] = (xv >= gr[ii] && xv < gr[ii+1]) ? 1.f : 0.f;
        #pragma unroll
        for (int kk = 1; kk <= 3; ++kk) {
            #pragma unroll
            for (int ii = 0; ii + kk <= 10; ++ii) {
                float left  = (xv - gr[ii]) / (gr[ii+kk] - gr[ii]) * bs[ii];
                float right = (gr[ii+kk+1] - xv) / (gr[ii+kk+1] - gr[ii+1]) * bs[ii+1];
                bs[ii] = left + right;
            }
        }
        unsigned short* arow = &abuf[t*1032 + i*9];
        #pragma unroll
        for (int b = 0; b < 8; ++b) arow[b] = f2bf(bs[b]);
        arow[8] = f2bf(si);
    }
    for (int e = tid; e < TM * 24; e += 256)
        abuf[(e/24)*1032 + KTOT + (e%24)] = 0;
    __syncthreads();

    // ---- 5. KAN MFMA + residual (LN1 output) -> so ----
    {
        int jt0 = 2*w, jt1 = 2*w + 1;
        f32x4 acc0 = {0.f,0.f,0.f,0.f}, acc1 = {0.f,0.f,0.f,0.f};
        const bf16x8* wbl = (const bf16x8*)wb + (size_t)l * NKT * D * 4;
        #pragma unroll 4
        for (int kt = 0; kt < NKT; ++kt) {
            bf16x8 a = *(const bf16x8*)&abuf[m*1032 + kt*32 + g4*8];
            bf16x8 b0 = wbl[((size_t)kt*D + jt0*16 + m)*4 + g4];
            acc0 = __builtin_amdgcn_mfma_f32_16x16x32_bf16(a, b0, acc0, 0, 0, 0);
            if (jt1 < 7) {
                bf16x8 b1f = wbl[((size_t)kt*D + jt1*16 + m)*4 + g4];
                acc1 = __builtin_amdgcn_mfma_f32_16x16x32_bf16(a, b1f, acc1, 0, 0, 0);
            }
        }
        #pragma unroll
        for (int r = 0; r < 4; ++r) {
            int t = g4*4 + r;
            int j0 = jt0*16 + m;
            so[t][j0] = acc0[r] + so[t][j0];
            if (jt1 < 7) {
                int j1 = jt1*16 + m;
                so[t][j1] = acc1[r] + so[t][j1];
            }
        }
    }
    __syncthreads();

    // ---- 6. LN2 -> hout ----
    for (int tt = 0; tt < 4; ++tt) {
        int t = w*4 + tt;
        float x0 = so[t][lane];
        float x1 = (lane + 64 < D) ? so[t][lane + 64] : 0.f;
        float s1 = x0 + x1, s2 = x0*x0 + x1*x1;
        #pragma unroll
        for (int off = 32; off; off >>= 1) { s1 += __shfl_xor(s1, off, 64); s2 += __shfl_xor(s2, off, 64); }
        float mu = s1 * (1.f/112.f);
        float var = s2 * (1.f/112.f) - mu*mu;
        float rs = rsqrtf(var + 1e-5f);
        for (int ii = lane; ii < D; ii += 64)
            hout[(size_t)(t0 + t)*D + ii] = (so[t][ii] - mu)*rs*g2[l*D + ii] + b2[l*D + ii];
    }
}

// ---------------- classifier: f32 output ----------------
__global__ __launch_bounds__(64) void cls_kernel(
    const float* __restrict__ h, const float* __restrict__ cw, const float* __restrict__ cb,
    float* __restrict__ out)
{
    int tid = threadIdx.x;
    if (tid < BATCH*2) {
        int b = tid >> 1, c = tid & 1;
        const float* hr = h + (size_t)b*SEQ*D;   // token s=0
        const float* wr = cw + c*D;
        float a = 0.f;
        for (int i = 0; i < D; ++i) a += hr[i]*wr[i];
        out[b*2 + c] = a + cb[c];
    }
}

// ---------------- ws-too-small sentinel (diagnostic) ----------------
__global__ void sentinel_kernel(float* __restrict__ out, int nel)
{
    int i = threadIdx.x;
    if (i < nel) out[i] = 1e30f;
}

extern "C" void kernel_launch(void* const* d_in, const int* in_sizes, int n_in,
                              void* d_out, int out_size, void* d_ws, size_t ws_size,
                              hipStream_t stream)
{
    const float* x      = (const float*)d_in[0];
    const int*   mask   = (const int*)  d_in[1];
    const float* grid   = (const float*)d_in[2];
    const float* qw     = (const float*)d_in[3];
    const float* qb     = (const float*)d_in[4];
    const float* kw     = (const float*)d_in[5];
    const float* kb     = (const float*)d_in[6];
    const float* vw     = (const float*)d_in[7];
    const float* vb     = (const float*)d_in[8];
    const float* ow     = (const float*)d_in[9];
    const float* ob     = (const float*)d_in[10];
    const float* ln1g   = (const float*)d_in[11];
    const float* ln1b   = (const float*)d_in[12];
    const float* ln2g   = (const float*)d_in[13];
    const float* ln2b   = (const float*)d_in[14];
    const float* base_w = (const float*)d_in[15];
    const float* spline_w = (const float*)d_in[16];
    const float* scaler = (const float*)d_in[17];
    const float* cls_w  = (const float*)d_in[18];
    const float* cls_b  = (const float*)d_in[19];

    size_t SZ   = (size_t)NTOK * D;            // 917504 floats per buffer
    size_t WBN  = (size_t)2 * NKT * D * 32;    // 229376 bf16 (kan weights)
    size_t WQN  = (size_t)2 * 4 * 336 * 32;    // 86016 bf16 (qkv weights)
    size_t WON  = (size_t)2 * 4 * D * 32;      // 28672 bf16 (oproj weights)
    size_t need = 6*SZ*sizeof(float) + (WBN + WQN + WON)*sizeof(unsigned short) + 256;
    if (ws_size < need) {
        sentinel_kernel<<<1, 64, 0, stream>>>((float*)d_out, out_size);
        return;
    }
    float* ws = (float*)d_ws;
    float* q   = ws;
    float* k   = q + SZ;
    float* v   = k + SZ;
    float* ctx = v + SZ;
    float* hA  = ctx + SZ;
    float* hB  = hA + SZ;
    unsigned short* wbuf  = (unsigned short*)(hB + SZ);
    unsigned short* wqkv  = wbuf + WBN;
    unsigned short* wobuf = wqkv + WQN;

    int gstride = (in_sizes[2] == NKNOT) ? 0 : NKNOT;

    wb_prep_kernel<<<(int)((WBN + 255)/256), 256, 0, stream>>>(base_w, spline_w, scaler, wbuf);
    wqkv_prep_kernel<<<(int)((WQN + 255)/256), 256, 0, stream>>>(qw, kw, vw, wqkv);
    wo_prep_kernel<<<(int)((WON + 255)/256), 256, 0, stream>>>(ow, wobuf);

    const float* hin = x;
    float* houts[2] = {hA, hB};
    for (int l = 0; l < 2; ++l) {
        qkv_mfma_kernel<<<NTOK/TM, 256, 0, stream>>>(hin, wqkv, qb, kb, vb, l, q, k, v);
        attn_mfma_kernel<<<BATCH*HEADS*4, 256, 0, stream>>>(q, k, v, mask, ctx);
        oproj_kan_ln_kernel<<<NTOK/TM, 256, 0, stream>>>(ctx, hin, wobuf, ob, ln1g, ln1b,
                                                         grid, wbuf, ln2g, ln2b, l, gstride, houts[l]);
        hin = houts[l];
    }
    cls_kernel<<<1, 64, 0, stream>>>(hB, cls_w, cls_b, (float*)d_out);
}

// Round 19
// 153.958 us; speedup vs baseline: 2.1007x; 1.4187x over previous
//
#include <hip/hip_runtime.h>
#include <hip/hip_bf16.h>

#define D 112
#define HEADS 28
#define HDIM 4
#define SEQ 512
#define BATCH 16
#define NTOK (BATCH*SEQ)
#define NBASES 8
#define NKNOT 12
#define KTOT (D*9)          // 1008 real K for KAN; padded to 1024
#define KPAD 1024
#define NKT (KPAD/32)       // 32 K-steps (KAN)
#define TM 16               // tokens per block in GEMM kernels
#define QJT 21              // 336/16 j-tiles in fused qkv GEMM
#define PST 20              // P-tile row stride (words)
#define VST 520             // vT row stride (bf16): breaks mod-32 bank alignment
#define LOG2E 1.44269504088896f
#define ATTN_BIAS (-23.0831169f)   // -16*log2(e)

typedef __attribute__((ext_vector_type(8))) __bf16 bf16x8;
typedef __attribute__((ext_vector_type(4))) float f32x4;

__device__ __forceinline__ unsigned short f2bf(float f) {
    unsigned u = __float_as_uint(f);
    unsigned r = u + 0x7FFFu + ((u >> 16) & 1u);   // RNE
    return (unsigned short)(r >> 16);
}

__device__ __forceinline__ unsigned cvt_pk_bf16(float lo, float hi) {
    unsigned r;
    asm("v_cvt_pk_bf16_f32 %0, %1, %2" : "=v"(r) : "v"(lo), "v"(hi));
    return r;
}

// ---------------- weight prep: qkv concat -> bf16 B-fragment layout ----------------
__global__ void wqkv_prep_kernel(
    const float* __restrict__ qw, const float* __restrict__ kw, const float* __restrict__ vw,
    unsigned short* __restrict__ wq)
{
    int idx = blockIdx.x * 256 + threadIdx.x;
    if (idx >= 2*4*336*32) return;
    int kk = idx & 31;
    int j  = (idx >> 5) % 336;
    int kt = ((idx >> 5) / 336) & 3;
    int l  = idx / (32*336*4);
    int i = kt*32 + kk;
    float val = 0.f;
    if (i < D) {
        int mo = j / D, jj = j % D;
        const float* src = (mo==0) ? qw : (mo==1) ? kw : vw;
        val = src[((size_t)l*D + jj)*D + i];
    }
    wq[idx] = f2bf(val);
}

// ---------------- weight prep: oproj -> bf16 B-fragment layout ----------------
__global__ void wo_prep_kernel(const float* __restrict__ ow, unsigned short* __restrict__ wo)
{
    int idx = blockIdx.x * 256 + threadIdx.x;
    if (idx >= 2*4*D*32) return;
    int kk = idx & 31;
    int j  = (idx >> 5) % D;
    int kt = ((idx >> 5) / D) & 3;
    int l  = idx / (32*D*4);
    int i = kt*32 + kk;
    float val = (i < D) ? ow[((size_t)l*D + j)*D + i] : 0.f;
    wo[idx] = f2bf(val);
}

// ---------------- fused QKV via MFMA (16 tokens/block, 8 waves, 21 j-tiles) ----------------
__global__ __launch_bounds__(512) void qkv_mfma_kernel(
    const float* __restrict__ hin, const unsigned short* __restrict__ wq,
    const float* __restrict__ qb, const float* __restrict__ kb, const float* __restrict__ vb,
    int l, float* __restrict__ q, float* __restrict__ k, float* __restrict__ v)
{
    __shared__ __align__(16) unsigned short act[TM][136];   // 16 x (128+8 pad)
    int tid = threadIdx.x;
    int t0 = blockIdx.x * TM;
    for (int e = tid; e < TM*D; e += 512) {
        int t = e / D, i = e % D;
        act[t][i] = f2bf(hin[(size_t)(t0 + t)*D + i]);
    }
    for (int e = tid; e < TM*16; e += 512) act[e/16][D + (e%16)] = 0;
    __syncthreads();

    int w = tid >> 6, lane = tid & 63, m = lane & 15, g4 = lane >> 4;
    f32x4 acc[3];
    #pragma unroll
    for (int qq = 0; qq < 3; ++qq) acc[qq] = (f32x4){0.f,0.f,0.f,0.f};
    const bf16x8* wql = (const bf16x8*)wq + (size_t)l*4*336*4;
    #pragma unroll
    for (int kt = 0; kt < 4; ++kt) {
        bf16x8 a = *(const bf16x8*)&act[m][kt*32 + g4*8];
        #pragma unroll
        for (int qq = 0; qq < 3; ++qq) {
            int jt = w + 8*qq;
            if (jt < QJT) {
                bf16x8 bf = wql[((size_t)kt*336 + jt*16 + m)*4 + g4];
                acc[qq] = __builtin_amdgcn_mfma_f32_16x16x32_bf16(a, bf, acc[qq], 0, 0, 0);
            }
        }
    }
    #pragma unroll
    for (int qq = 0; qq < 3; ++qq) {
        int jt = w + 8*qq;
        if (jt >= QJT) continue;
        int j = jt*16 + m;
        int mo = j / D, jj = j % D;
        const float* bb = (mo==0) ? qb : (mo==1) ? kb : vb;
        float bias = bb[l*D + jj];
        float scl = (mo==0) ? 0.5f*LOG2E : 1.0f;
        float* dst = (mo==0) ? q : (mo==1) ? k : v;
        int h = jj >> 2, hd = jj & 3;
        #pragma unroll
        for (int r = 0; r < 4; ++r) {
            int n = t0 + g4*4 + r;
            int bi = n >> 9, s = n & 511;
            dst[((size_t)(bi*HEADS + h)*SEQ + s)*HDIM + hd] = (acc[qq][r] + bias)*scl;
        }
    }
}

// ---------------- attention via MFMA: ones-column softmax sums on the matrix pipe ---------
__global__ __launch_bounds__(256) void attn_mfma_kernel(
    const float* __restrict__ q, const float* __restrict__ k, const float* __restrict__ v,
    const int* __restrict__ mask, float* __restrict__ ctx)
{
    __shared__ __align__(16) unsigned short kpack[SEQ][8];    // k0..3, mf, 0,0,0   (8KB)
    __shared__ __align__(16) unsigned short qpack[128][8];    // q0..3, 1.0, 0,0,0  (2KB)
    __shared__ __align__(16) unsigned short vT[5][VST];       // V^T + ones row     (5.1KB)
    __shared__ __align__(16) uint4 zfrag;
    __shared__ __align__(16) unsigned int plds[4][2][16*PST]; // per-wave 2-buf P   (10KB)

    int tid = threadIdx.x;
    int bh = blockIdx.x >> 2, qh = blockIdx.x & 3;
    int b = bh / HEADS, h = bh % HEADS;

    if (tid == 0) zfrag = (uint4){0,0,0,0};
    const float4* kk = (const float4*)k + (size_t)bh*SEQ;
    const float4* vv = (const float4*)v + (size_t)bh*SEQ;
    for (int s = tid; s < SEQ; s += 256) {
        float4 kf = kk[s];
        float mf = mask[b*SEQ + s] ? ATTN_BIAS : -1e9f;
        uint4 pk;
        pk.x = cvt_pk_bf16(kf.x, kf.y);
        pk.y = cvt_pk_bf16(kf.z, kf.w);
        pk.z = cvt_pk_bf16(mf, 0.f);
        pk.w = 0;
        *(uint4*)&kpack[s][0] = pk;
        float4 vf = vv[s];
        vT[0][s] = f2bf(vf.x); vT[1][s] = f2bf(vf.y);
        vT[2][s] = f2bf(vf.z); vT[3][s] = f2bf(vf.w);
        vT[4][s] = 0x3F80;   // bf16 1.0 -> denominator column
    }
    if (tid < 128) {
        int s = qh*128 + tid;
        float4 qf = ((const float4*)q)[(size_t)bh*SEQ + s];
        uint4 pk;
        pk.x = cvt_pk_bf16(qf.x, qf.y);
        pk.y = cvt_pk_bf16(qf.z, qf.w);
        pk.z = cvt_pk_bf16(1.0f, 0.f);
        pk.w = 0;
        *(uint4*)&qpack[tid][0] = pk;
    }
    __syncthreads();

    int w = tid >> 6, lane = tid & 63, ln = lane & 15, g4 = lane >> 4;
    const bf16x8* zf = (const bf16x8*)&zfrag;
    unsigned int* pw0 = &plds[w][0][0];
    unsigned int* pw1 = &plds[w][1][0];

    for (int qt = 0; qt < 2; ++qt) {
        int q0 = w*32 + qt*16;    // block-local query base
        bf16x8 qfrag = (g4 == 0) ? *(const bf16x8*)&qpack[q0 + ln][0] : *zf;
        f32x4 oacc = {0.f,0.f,0.f,0.f};
        #pragma unroll 2
        for (int kb = 0; kb < SEQ; kb += 64) {
            int kcA = kb, kcB = kb + 32;
            bf16x8 kaA0 = (g4 == 0) ? *(const bf16x8*)&kpack[kcA + ln][0]      : *zf;
            bf16x8 kaA1 = (g4 == 0) ? *(const bf16x8*)&kpack[kcA + 16 + ln][0] : *zf;
            bf16x8 kaB0 = (g4 == 0) ? *(const bf16x8*)&kpack[kcB + ln][0]      : *zf;
            bf16x8 kaB1 = (g4 == 0) ? *(const bf16x8*)&kpack[kcB + 16 + ln][0] : *zf;
            f32x4 sA0 = __builtin_amdgcn_mfma_f32_16x16x32_bf16(kaA0, qfrag, (f32x4){0.f,0.f,0.f,0.f}, 0, 0, 0);
            f32x4 sA1 = __builtin_amdgcn_mfma_f32_16x16x32_bf16(kaA1, qfrag, (f32x4){0.f,0.f,0.f,0.f}, 0, 0, 0);
            f32x4 sB0 = __builtin_amdgcn_mfma_f32_16x16x32_bf16(kaB0, qfrag, (f32x4){0.f,0.f,0.f,0.f}, 0, 0, 0);
            f32x4 sB1 = __builtin_amdgcn_mfma_f32_16x16x32_bf16(kaB1, qfrag, (f32x4){0.f,0.f,0.f,0.f}, 0, 0, 0);
            float a00 = __builtin_exp2f(sA0[0]), a01 = __builtin_exp2f(sA0[1]);
            float a02 = __builtin_exp2f(sA0[2]), a03 = __builtin_exp2f(sA0[3]);
            float a10 = __builtin_exp2f(sA1[0]), a11 = __builtin_exp2f(sA1[1]);
            float a12 = __builtin_exp2f(sA1[2]), a13 = __builtin_exp2f(sA1[3]);
            float b00 = __builtin_exp2f(sB0[0]), b01 = __builtin_exp2f(sB0[1]);
            float b02 = __builtin_exp2f(sB0[2]), b03 = __builtin_exp2f(sB0[3]);
            float b10 = __builtin_exp2f(sB1[0]), b11 = __builtin_exp2f(sB1[1]);
            float b12 = __builtin_exp2f(sB1[2]), b13 = __builtin_exp2f(sB1[3]);
            uint2 wA0 = {cvt_pk_bf16(a00, a01), cvt_pk_bf16(a02, a03)};
            uint2 wA1 = {cvt_pk_bf16(a10, a11), cvt_pk_bf16(a12, a13)};
            uint2 wB0 = {cvt_pk_bf16(b00, b01), cvt_pk_bf16(b02, b03)};
            uint2 wB1 = {cvt_pk_bf16(b10, b11), cvt_pk_bf16(b12, b13)};
            *(uint2*)&pw0[ln*PST + g4*2]     = wA0;
            *(uint2*)&pw0[ln*PST + 8 + g4*2] = wA1;
            *(uint2*)&pw1[ln*PST + g4*2]     = wB0;
            *(uint2*)&pw1[ln*PST + 8 + g4*2] = wB1;
            bf16x8 paA = *(const bf16x8*)&pw0[ln*PST + g4*4];
            bf16x8 vbA = (ln < 5) ? *(const bf16x8*)&vT[ln][kcA + g4*8] : *zf;
            oacc = __builtin_amdgcn_mfma_f32_16x16x32_bf16(paA, vbA, oacc, 0, 0, 0);
            bf16x8 paB = *(const bf16x8*)&pw1[ln*PST + g4*4];
            bf16x8 vbB = (ln < 5) ? *(const bf16x8*)&vT[ln][kcB + g4*8] : *zf;
            oacc = __builtin_amdgcn_mfma_f32_16x16x32_bf16(paB, vbB, oacc, 0, 0, 0);
        }
        // denominators live at lanes ln==4 (col 4), row r = query g4*4+r
        int src = g4*16 + 4;
        float s0 = __shfl(oacc[0], src, 64);
        float s1 = __shfl(oacc[1], src, 64);
        float s2 = __shfl(oacc[2], src, 64);
        float s3 = __shfl(oacc[3], src, 64);
        float i0 = __builtin_amdgcn_rcpf(s0);
        float i1 = __builtin_amdgcn_rcpf(s1);
        float i2 = __builtin_amdgcn_rcpf(s2);
        float i3 = __builtin_amdgcn_rcpf(s3);
        if (ln < 4) {
            size_t base = (size_t)(b*SEQ + qh*128 + q0 + g4*4);
            ctx[(base + 0)*D + h*4 + ln] = oacc[0] * i0;
            ctx[(base + 1)*D + h*4 + ln] = oacc[1] * i1;
            ctx[(base + 2)*D + h*4 + ln] = oacc[2] * i2;
            ctx[(base + 3)*D + h*4 + ln] = oacc[3] * i3;
        }
    }
}

// ---------------- Wb prep: fold (spline_w*scaler, base_w) into bf16 B-fragment layout ----
__global__ void wb_prep_kernel(
    const float* __restrict__ base_w, const float* __restrict__ spline_w,
    const float* __restrict__ scaler, unsigned short* __restrict__ wb)
{
    int idx = blockIdx.x * 256 + threadIdx.x;
    if (idx >= 2 * NKT * D * 32) return;
    int kk = idx & 31;
    int j  = (idx >> 5) % D;
    int kt = ((idx >> 5) / D) % NKT;
    int l  = idx / (32 * D * NKT);
    int k = kt * 32 + kk;
    float val = 0.f;
    if (k < KTOT) {
        int i = k / 9, b = k % 9;
        size_t ji = ((size_t)l * D + j) * D + i;
        val = (b == 8) ? base_w[ji] : spline_w[ji * NBASES + b] * scaler[ji];
    }
    wb[idx] = f2bf(val);
}

// ---------------- FUSED: oproj + res + LN1 + KAN + res + LN2 (16 tok, 8 waves) ----------
// Direct cardinal B-spline evaluation (uniform grid): only 4 bases non-zero per x,
// pieces {t3, -3t3+3t2+3t+1, 3t3-6t2+4, (1-t)3}/6 at t = frac((x-g0)/h).
__global__ __launch_bounds__(512) void oproj_kan_ln_kernel(
    const float* __restrict__ ctx, const float* __restrict__ hin,
    const unsigned short* __restrict__ wo, const float* __restrict__ ob,
    const float* __restrict__ g1, const float* __restrict__ b1,
    const float* __restrict__ grid, const unsigned short* __restrict__ wb,
    const float* __restrict__ g2, const float* __restrict__ b2,
    int l, int gstride, float* __restrict__ hout)
{
    __shared__ __align__(16) unsigned short abuf[TM*1032];  // union: oproj stride 136 / kan stride 1032
    __shared__ float so[TM][D];
    int tid = threadIdx.x;
    int t0 = blockIdx.x * TM;
    int w = tid >> 6, lane = tid & 63, m = lane & 15, g4 = lane >> 4;
    int jw = w*16 + m;   // this wave's output column (valid when w < 7)

    // ---- 0. prefetch residuals + bias for phase 2 (before any barrier) ----
    float resv[4], obv = 0.f;
    if (w < 7) {
        obv = ob[l*D + jw];
        #pragma unroll
        for (int r = 0; r < 4; ++r)
            resv[r] = hin[(size_t)(t0 + g4*4 + r)*D + jw];
    }

    // ---- 1. stage ctx (bf16, stride 136, zero-padded cols) ----
    for (int e = tid; e < TM*136; e += 512) {
        int t = e / 136, i = e % 136;
        abuf[e] = (i < D) ? f2bf(ctx[(size_t)(t0 + t)*D + i]) : 0;
    }
    __syncthreads();

    // ---- 2. oproj MFMA + bias + residual -> so (wave w owns j-tile w) ----
    if (w < 7) {
        f32x4 acc = {0.f,0.f,0.f,0.f};
        const bf16x8* wol = (const bf16x8*)wo + (size_t)l*4*D*4;
        #pragma unroll
        for (int kt = 0; kt < 4; ++kt) {
            bf16x8 a = *(const bf16x8*)&abuf[m*136 + kt*32 + g4*8];
            bf16x8 b0 = wol[((size_t)kt*D + jw)*4 + g4];
            acc = __builtin_amdgcn_mfma_f32_16x16x32_bf16(a, b0, acc, 0, 0, 0);
        }
        #pragma unroll
        for (int r = 0; r < 4; ++r)
            so[g4*4 + r][jw] = acc[r] + obv + resv[r];
    }
    __syncthreads();

    // ---- 3. LN1 in place on so (8 waves x 2 tokens) ----
    for (int tt = 0; tt < 2; ++tt) {
        int t = w*2 + tt;
        float x0 = so[t][lane];
        float x1 = (lane + 64 < D) ? so[t][lane + 64] : 0.f;
        float s1 = x0 + x1, s2 = x0*x0 + x1*x1;
        #pragma unroll
        for (int off = 32; off; off >>= 1) { s1 += __shfl_xor(s1, off, 64); s2 += __shfl_xor(s2, off, 64); }
        float mu = s1 * (1.f/112.f);
        float var = s2 * (1.f/112.f) - mu*mu;
        float rs = rsqrtf(var + 1e-5f);
        so[t][lane] = (x0 - mu)*rs*g1[l*D + lane] + b1[l*D + lane];
        if (lane + 64 < D)
            so[t][lane+64] = (x1 - mu)*rs*g1[l*D + lane+64] + b1[l*D + lane+64];
    }
    __syncthreads();

    // ---- 4. spline basis (cardinal, direct) + silu from so -> abuf (stride 1032) ----
    for (int e = tid; e < TM * D; e += 512) {
        int tk = e / D, i = e % D;
        float xv = so[tk][i];
        float si = xv * __builtin_amdgcn_rcpf(1.f + __expf(-xv));
        const float* grp = grid + i * gstride;
        float gz = grp[0];
        float hh = grp[1] - gz;
        float u = (xv - gz) / hh;
        float fidx = floorf(u);
        int idx = (int)fidx;
        float t = u - fidx;
        float t2 = t*t, t3 = t2*t;
        const float s6 = 1.f/6.f;
        float p0 = t3 * s6;
        float p1 = (-3.f*t3 + 3.f*t2 + 3.f*t + 1.f) * s6;
        float p2 = (3.f*t3 - 6.f*t2 + 4.f) * s6;
        float om = 1.f - t;
        float p3 = om*om*om * s6;
        unsigned short* arow = &abuf[tk*1032 + i*9];
        #pragma unroll
        for (int b = 0; b < 8; ++b) arow[b] = 0;
        if (u >= 0.f && idx <= 10) {
            if (idx <= 7) arow[idx]   = f2bf(p0);
            if (idx >= 1 && idx <= 8) arow[idx-1] = f2bf(p1);
            if (idx >= 2 && idx <= 9) arow[idx-2] = f2bf(p2);
            if (idx >= 3)             arow[idx-3] = f2bf(p3);
        }
        arow[8] = f2bf(si);
    }
    for (int e = tid; e < TM * 24; e += 512)
        abuf[(e/24)*1032 + KTOT + (e%24)] = 0;
    __syncthreads();

    // ---- 5. KAN MFMA + residual (LN1 output) -> so (wave w owns j-tile w) ----
    if (w < 7) {
        f32x4 acc = {0.f,0.f,0.f,0.f};
        const bf16x8* wbl = (const bf16x8*)wb + (size_t)l * NKT * D * 4;
        #pragma unroll 4
        for (int kt = 0; kt < NKT; ++kt) {
            bf16x8 a = *(const bf16x8*)&abuf[m*1032 + kt*32 + g4*8];
            bf16x8 b0 = wbl[((size_t)kt*D + jw)*4 + g4];
            acc = __builtin_amdgcn_mfma_f32_16x16x32_bf16(a, b0, acc, 0, 0, 0);
        }
        #pragma unroll
        for (int r = 0; r < 4; ++r) {
            int t = g4*4 + r;
            so[t][jw] = acc[r] + so[t][jw];
        }
    }
    __syncthreads();

    // ---- 6. LN2 -> hout (8 waves x 2 tokens) ----
    for (int tt = 0; tt < 2; ++tt) {
        int t = w*2 + tt;
        float x0 = so[t][lane];
        float x1 = (lane + 64 < D) ? so[t][lane + 64] : 0.f;
        float s1 = x0 + x1, s2 = x0*x0 + x1*x1;
        #pragma unroll
        for (int off = 32; off; off >>= 1) { s1 += __shfl_xor(s1, off, 64); s2 += __shfl_xor(s2, off, 64); }
        float mu = s1 * (1.f/112.f);
        float var = s2 * (1.f/112.f) - mu*mu;
        float rs = rsqrtf(var + 1e-5f);
        for (int ii = lane; ii < D; ii += 64)
            hout[(size_t)(t0 + t)*D + ii] = (so[t][ii] - mu)*rs*g2[l*D + ii] + b2[l*D + ii];
    }
}

// ---------------- classifier: f32 output ----------------
__global__ __launch_bounds__(64) void cls_kernel(
    const float* __restrict__ h, const float* __restrict__ cw, const float* __restrict__ cb,
    float* __restrict__ out)
{
    int tid = threadIdx.x;
    if (tid < BATCH*2) {
        int b = tid >> 1, c = tid & 1;
        const float* hr = h + (size_t)b*SEQ*D;   // token s=0
        const float* wr = cw + c*D;
        float a = 0.f;
        for (int i = 0; i < D; ++i) a += hr[i]*wr[i];
        out[b*2 + c] = a + cb[c];
    }
}

// ---------------- ws-too-small sentinel (diagnostic) ----------------
__global__ void sentinel_kernel(float* __restrict__ out, int nel)
{
    int i = threadIdx.x;
    if (i < nel) out[i] = 1e30f;
}

extern "C" void kernel_launch(void* const* d_in, const int* in_sizes, int n_in,
                              void* d_out, int out_size, void* d_ws, size_t ws_size,
                              hipStream_t stream)
{
    const float* x      = (const float*)d_in[0];
    const int*   mask   = (const int*)  d_in[1];
    const float* grid   = (const float*)d_in[2];
    const float* qw     = (const float*)d_in[3];
    const float* qb     = (const float*)d_in[4];
    const float* kw     = (const float*)d_in[5];
    const float* kb     = (const float*)d_in[6];
    const float* vw     = (const float*)d_in[7];
    const float* vb     = (const float*)d_in[8];
    const float* ow     = (const float*)d_in[9];
    const float* ob     = (const float*)d_in[10];
    const float* ln1g   = (const float*)d_in[11];
    const float* ln1b   = (const float*)d_in[12];
    const float* ln2g   = (const float*)d_in[13];
    const float* ln2b   = (const float*)d_in[14];
    const float* base_w = (const float*)d_in[15];
    const float* spline_w = (const float*)d_in[16];
    const float* scaler = (const float*)d_in[17];
    const float* cls_w  = (const float*)d_in[18];
    const float* cls_b  = (const float*)d_in[19];

    size_t SZ   = (size_t)NTOK * D;            // 917504 floats per buffer
    size_t WBN  = (size_t)2 * NKT * D * 32;    // 229376 bf16 (kan weights)
    size_t WQN  = (size_t)2 * 4 * 336 * 32;    // 86016 bf16 (qkv weights)
    size_t WON  = (size_t)2 * 4 * D * 32;      // 28672 bf16 (oproj weights)
    size_t need = 6*SZ*sizeof(float) + (WBN + WQN + WON)*sizeof(unsigned short) + 256;
    if (ws_size < need) {
        sentinel_kernel<<<1, 64, 0, stream>>>((float*)d_out, out_size);
        return;
    }
    float* ws = (float*)d_ws;
    float* q   = ws;
    float* k   = q + SZ;
    float* v   = k + SZ;
    float* ctx = v + SZ;
    float* hA  = ctx + SZ;
    float* hB  = hA + SZ;
    unsigned short* wbuf  = (unsigned short*)(hB + SZ);
    unsigned short* wqkv  = wbuf + WBN;
    unsigned short* wobuf = wqkv + WQN;

    int gstride = (in_sizes[2] == NKNOT) ? 0 : NKNOT;

    wb_prep_kernel<<<(int)((WBN + 255)/256), 256, 0, stream>>>(base_w, spline_w, scaler, wbuf);
    wqkv_prep_kernel<<<(int)((WQN + 255)/256), 256, 0, stream>>>(qw, kw, vw, wqkv);
    wo_prep_kernel<<<(int)((WON + 255)/256), 256, 0, stream>>>(ow, wobuf);

    const float* hin = x;
    float* houts[2] = {hA, hB};
    for (int l = 0; l < 2; ++l) {
        qkv_mfma_kernel<<<NTOK/TM, 512, 0, stream>>>(hin, wqkv, qb, kb, vb, l, q, k, v);
        attn_mfma_kernel<<<BATCH*HEADS*4, 256, 0, stream>>>(q, k, v, mask, ctx);
        oproj_kan_ln_kernel<<<NTOK/TM, 512, 0, stream>>>(ctx, hin, wobuf, ob, ln1g, ln1b,
                                                         grid, wbuf, ln2g, ln2b, l, gstride, houts[l]);
        hin = houts[l];
    }
    cls_kernel<<<1, 64, 0, stream>>>(hB, cls_w, cls_b, (float*)d_out);
}

// Round 20
// 150.710 us; speedup vs baseline: 2.1460x; 1.0216x over previous
//
#include <hip/hip_runtime.h>
#include <hip/hip_bf16.h>

#define D 112
#define HEADS 28
#define HDIM 4
#define SEQ 512
#define BATCH 16
#define NTOK (BATCH*SEQ)
#define NBASES 8
#define NKNOT 12
#define KTOT (D*9)          // 1008 real K for KAN; padded to 1024
#define KPAD 1024
#define NKT (KPAD/32)       // 32 K-steps (KAN)
#define TM 16               // tokens per block in GEMM kernels
#define QJT 21              // 336/16 j-tiles in fused qkv GEMM
#define PST 20              // P-tile row stride (words)
#define VST 522             // vT row stride (bf16): 261 words, mod 32 = 5 -> <=2-way
#define LOG2E 1.44269504088896f
#define ATTN_BIAS (-23.0831169f)   // -16*log2(e)

typedef __attribute__((ext_vector_type(8))) __bf16 bf16x8;
typedef __attribute__((ext_vector_type(4))) float f32x4;

__device__ __forceinline__ unsigned short f2bf(float f) {
    unsigned u = __float_as_uint(f);
    unsigned r = u + 0x7FFFu + ((u >> 16) & 1u);   // RNE
    return (unsigned short)(r >> 16);
}

__device__ __forceinline__ unsigned cvt_pk_bf16(float lo, float hi) {
    unsigned r;
    asm("v_cvt_pk_bf16_f32 %0, %1, %2" : "=v"(r) : "v"(lo), "v"(hi));
    return r;
}

// ---------------- weight prep: qkv concat -> bf16 B-fragment layout ----------------
__global__ void wqkv_prep_kernel(
    const float* __restrict__ qw, const float* __restrict__ kw, const float* __restrict__ vw,
    unsigned short* __restrict__ wq)
{
    int idx = blockIdx.x * 256 + threadIdx.x;
    if (idx >= 2*4*336*32) return;
    int kk = idx & 31;
    int j  = (idx >> 5) % 336;
    int kt = ((idx >> 5) / 336) & 3;
    int l  = idx / (32*336*4);
    int i = kt*32 + kk;
    float val = 0.f;
    if (i < D) {
        int mo = j / D, jj = j % D;
        const float* src = (mo==0) ? qw : (mo==1) ? kw : vw;
        val = src[((size_t)l*D + jj)*D + i];
    }
    wq[idx] = f2bf(val);
}

// ---------------- weight prep: oproj -> bf16 B-fragment layout ----------------
__global__ void wo_prep_kernel(const float* __restrict__ ow, unsigned short* __restrict__ wo)
{
    int idx = blockIdx.x * 256 + threadIdx.x;
    if (idx >= 2*4*D*32) return;
    int kk = idx & 31;
    int j  = (idx >> 5) % D;
    int kt = ((idx >> 5) / D) & 3;
    int l  = idx / (32*D*4);
    int i = kt*32 + kk;
    float val = (i < D) ? ow[((size_t)l*D + j)*D + i] : 0.f;
    wo[idx] = f2bf(val);
}

// ---------------- fused QKV via MFMA (16 tokens/block, 8 waves, 21 j-tiles) ----------------
__global__ __launch_bounds__(512) void qkv_mfma_kernel(
    const float* __restrict__ hin, const unsigned short* __restrict__ wq,
    const float* __restrict__ qb, const float* __restrict__ kb, const float* __restrict__ vb,
    int l, float* __restrict__ q, float* __restrict__ k, float* __restrict__ v)
{
    __shared__ __align__(16) unsigned short act[TM][136];   // 16 x (128+8 pad)
    int tid = threadIdx.x;
    int t0 = blockIdx.x * TM;
    for (int e = tid; e < TM*D; e += 512) {
        int t = e / D, i = e % D;
        act[t][i] = f2bf(hin[(size_t)(t0 + t)*D + i]);
    }
    for (int e = tid; e < TM*16; e += 512) act[e/16][D + (e%16)] = 0;
    __syncthreads();

    int w = tid >> 6, lane = tid & 63, m = lane & 15, g4 = lane >> 4;
    f32x4 acc[3];
    #pragma unroll
    for (int qq = 0; qq < 3; ++qq) acc[qq] = (f32x4){0.f,0.f,0.f,0.f};
    const bf16x8* wql = (const bf16x8*)wq + (size_t)l*4*336*4;
    #pragma unroll
    for (int kt = 0; kt < 4; ++kt) {
        bf16x8 a = *(const bf16x8*)&act[m][kt*32 + g4*8];
        #pragma unroll
        for (int qq = 0; qq < 3; ++qq) {
            int jt = w + 8*qq;
            if (jt < QJT) {
                bf16x8 bf = wql[((size_t)kt*336 + jt*16 + m)*4 + g4];
                acc[qq] = __builtin_amdgcn_mfma_f32_16x16x32_bf16(a, bf, acc[qq], 0, 0, 0);
            }
        }
    }
    #pragma unroll
    for (int qq = 0; qq < 3; ++qq) {
        int jt = w + 8*qq;
        if (jt >= QJT) continue;
        int j = jt*16 + m;
        int mo = j / D, jj = j % D;
        const float* bb = (mo==0) ? qb : (mo==1) ? kb : vb;
        float bias = bb[l*D + jj];
        float scl = (mo==0) ? 0.5f*LOG2E : 1.0f;
        float* dst = (mo==0) ? q : (mo==1) ? k : v;
        int h = jj >> 2, hd = jj & 3;
        #pragma unroll
        for (int r = 0; r < 4; ++r) {
            int n = t0 + g4*4 + r;
            int bi = n >> 9, s = n & 511;
            dst[((size_t)(bi*HEADS + h)*SEQ + s)*HDIM + hd] = (acc[qq][r] + bias)*scl;
        }
    }
}

// ---------------- attention via MFMA: 512 threads (8 waves), 2 blocks per (b,h) ----------
// 8 waves x 32 queries = 256 queries/block -> 4 blocks/CU, up to 8 waves/SIMD for
// latency hiding. Ones-column trick: PV col 4 = softmax denominators (matrix pipe).
__global__ __launch_bounds__(512) void attn_mfma_kernel(
    const float* __restrict__ q, const float* __restrict__ k, const float* __restrict__ v,
    const int* __restrict__ mask, float* __restrict__ ctx)
{
    __shared__ __align__(16) unsigned short kpack[SEQ][8];    // k0..3, mf, 0,0,0   (8KB)
    __shared__ __align__(16) unsigned short qpack[256][8];    // q0..3, 1.0, 0,0,0  (4KB)
    __shared__ __align__(16) unsigned short vT[5][VST];       // V^T + ones row     (5.2KB)
    __shared__ __align__(16) uint4 zfrag;
    __shared__ __align__(16) unsigned int plds[8][2][16*PST]; // per-wave 2-buf P   (20.5KB)

    int tid = threadIdx.x;
    int bh = blockIdx.x >> 1, qh = blockIdx.x & 1;
    int b = bh / HEADS, h = bh % HEADS;

    if (tid == 0) zfrag = (uint4){0,0,0,0};
    const float4* kk = (const float4*)k + (size_t)bh*SEQ;
    const float4* vv = (const float4*)v + (size_t)bh*SEQ;
    for (int s = tid; s < SEQ; s += 512) {
        float4 kf = kk[s];
        float mf = mask[b*SEQ + s] ? ATTN_BIAS : -1e9f;
        uint4 pk;
        pk.x = cvt_pk_bf16(kf.x, kf.y);
        pk.y = cvt_pk_bf16(kf.z, kf.w);
        pk.z = cvt_pk_bf16(mf, 0.f);
        pk.w = 0;
        *(uint4*)&kpack[s][0] = pk;
        float4 vf = vv[s];
        vT[0][s] = f2bf(vf.x); vT[1][s] = f2bf(vf.y);
        vT[2][s] = f2bf(vf.z); vT[3][s] = f2bf(vf.w);
        vT[4][s] = 0x3F80;   // bf16 1.0 -> denominator column
    }
    if (tid < 256) {
        int s = qh*256 + tid;
        float4 qf = ((const float4*)q)[(size_t)bh*SEQ + s];
        uint4 pk;
        pk.x = cvt_pk_bf16(qf.x, qf.y);
        pk.y = cvt_pk_bf16(qf.z, qf.w);
        pk.z = cvt_pk_bf16(1.0f, 0.f);
        pk.w = 0;
        *(uint4*)&qpack[tid][0] = pk;
    }
    __syncthreads();

    int w = tid >> 6, lane = tid & 63, ln = lane & 15, g4 = lane >> 4;
    const bf16x8* zf = (const bf16x8*)&zfrag;
    unsigned int* pw0 = &plds[w][0][0];
    unsigned int* pw1 = &plds[w][1][0];

    for (int qt = 0; qt < 2; ++qt) {
        int q0 = w*32 + qt*16;    // block-local query base (0..255)
        bf16x8 qfrag = (g4 == 0) ? *(const bf16x8*)&qpack[q0 + ln][0] : *zf;
        f32x4 oacc = {0.f,0.f,0.f,0.f};
        #pragma unroll 2
        for (int kb = 0; kb < SEQ; kb += 64) {
            int kcA = kb, kcB = kb + 32;
            bf16x8 kaA0 = (g4 == 0) ? *(const bf16x8*)&kpack[kcA + ln][0]      : *zf;
            bf16x8 kaA1 = (g4 == 0) ? *(const bf16x8*)&kpack[kcA + 16 + ln][0] : *zf;
            bf16x8 kaB0 = (g4 == 0) ? *(const bf16x8*)&kpack[kcB + ln][0]      : *zf;
            bf16x8 kaB1 = (g4 == 0) ? *(const bf16x8*)&kpack[kcB + 16 + ln][0] : *zf;
            f32x4 sA0 = __builtin_amdgcn_mfma_f32_16x16x32_bf16(kaA0, qfrag, (f32x4){0.f,0.f,0.f,0.f}, 0, 0, 0);
            f32x4 sA1 = __builtin_amdgcn_mfma_f32_16x16x32_bf16(kaA1, qfrag, (f32x4){0.f,0.f,0.f,0.f}, 0, 0, 0);
            f32x4 sB0 = __builtin_amdgcn_mfma_f32_16x16x32_bf16(kaB0, qfrag, (f32x4){0.f,0.f,0.f,0.f}, 0, 0, 0);
            f32x4 sB1 = __builtin_amdgcn_mfma_f32_16x16x32_bf16(kaB1, qfrag, (f32x4){0.f,0.f,0.f,0.f}, 0, 0, 0);
            float a00 = __builtin_exp2f(sA0[0]), a01 = __builtin_exp2f(sA0[1]);
            float a02 = __builtin_exp2f(sA0[2]), a03 = __builtin_exp2f(sA0[3]);
            float a10 = __builtin_exp2f(sA1[0]), a11 = __builtin_exp2f(sA1[1]);
            float a12 = __builtin_exp2f(sA1[2]), a13 = __builtin_exp2f(sA1[3]);
            float b00 = __builtin_exp2f(sB0[0]), b01 = __builtin_exp2f(sB0[1]);
            float b02 = __builtin_exp2f(sB0[2]), b03 = __builtin_exp2f(sB0[3]);
            float b10 = __builtin_exp2f(sB1[0]), b11 = __builtin_exp2f(sB1[1]);
            float b12 = __builtin_exp2f(sB1[2]), b13 = __builtin_exp2f(sB1[3]);
            uint2 wA0 = {cvt_pk_bf16(a00, a01), cvt_pk_bf16(a02, a03)};
            uint2 wA1 = {cvt_pk_bf16(a10, a11), cvt_pk_bf16(a12, a13)};
            uint2 wB0 = {cvt_pk_bf16(b00, b01), cvt_pk_bf16(b02, b03)};
            uint2 wB1 = {cvt_pk_bf16(b10, b11), cvt_pk_bf16(b12, b13)};
            *(uint2*)&pw0[ln*PST + g4*2]     = wA0;
            *(uint2*)&pw0[ln*PST + 8 + g4*2] = wA1;
            *(uint2*)&pw1[ln*PST + g4*2]     = wB0;
            *(uint2*)&pw1[ln*PST + 8 + g4*2] = wB1;
            bf16x8 paA = *(const bf16x8*)&pw0[ln*PST + g4*4];
            bf16x8 vbA = (ln < 5) ? *(const bf16x8*)&vT[ln][kcA + g4*8] : *zf;
            oacc = __builtin_amdgcn_mfma_f32_16x16x32_bf16(paA, vbA, oacc, 0, 0, 0);
            bf16x8 paB = *(const bf16x8*)&pw1[ln*PST + g4*4];
            bf16x8 vbB = (ln < 5) ? *(const bf16x8*)&vT[ln][kcB + g4*8] : *zf;
            oacc = __builtin_amdgcn_mfma_f32_16x16x32_bf16(paB, vbB, oacc, 0, 0, 0);
        }
        // denominators live at lanes ln==4 (col 4), row r = query g4*4+r
        int src = g4*16 + 4;
        float s0 = __shfl(oacc[0], src, 64);
        float s1 = __shfl(oacc[1], src, 64);
        float s2 = __shfl(oacc[2], src, 64);
        float s3 = __shfl(oacc[3], src, 64);
        float i0 = __builtin_amdgcn_rcpf(s0);
        float i1 = __builtin_amdgcn_rcpf(s1);
        float i2 = __builtin_amdgcn_rcpf(s2);
        float i3 = __builtin_amdgcn_rcpf(s3);
        if (ln < 4) {
            size_t base = (size_t)(b*SEQ + qh*256 + q0 + g4*4);
            ctx[(base + 0)*D + h*4 + ln] = oacc[0] * i0;
            ctx[(base + 1)*D + h*4 + ln] = oacc[1] * i1;
            ctx[(base + 2)*D + h*4 + ln] = oacc[2] * i2;
            ctx[(base + 3)*D + h*4 + ln] = oacc[3] * i3;
        }
    }
}

// ---------------- Wb prep: fold (spline_w*scaler, base_w) into bf16 B-fragment layout ----
__global__ void wb_prep_kernel(
    const float* __restrict__ base_w, const float* __restrict__ spline_w,
    const float* __restrict__ scaler, unsigned short* __restrict__ wb)
{
    int idx = blockIdx.x * 256 + threadIdx.x;
    if (idx >= 2 * NKT * D * 32) return;
    int kk = idx & 31;
    int j  = (idx >> 5) % D;
    int kt = ((idx >> 5) / D) % NKT;
    int l  = idx / (32 * D * NKT);
    int k = kt * 32 + kk;
    float val = 0.f;
    if (k < KTOT) {
        int i = k / 9, b = k % 9;
        size_t ji = ((size_t)l * D + j) * D + i;
        val = (b == 8) ? base_w[ji] : spline_w[ji * NBASES + b] * scaler[ji];
    }
    wb[idx] = f2bf(val);
}

// ---------------- FUSED: oproj + res + LN1 + KAN + res + LN2 (16 tok, 8 waves) ----------
// Direct cardinal B-spline evaluation (uniform grid): only 4 bases non-zero per x,
// pieces {t3, -3t3+3t2+3t+1, 3t3-6t2+4, (1-t)3}/6 at t = frac((x-g0)/h).
__global__ __launch_bounds__(512) void oproj_kan_ln_kernel(
    const float* __restrict__ ctx, const float* __restrict__ hin,
    const unsigned short* __restrict__ wo, const float* __restrict__ ob,
    const float* __restrict__ g1, const float* __restrict__ b1,
    const float* __restrict__ grid, const unsigned short* __restrict__ wb,
    const float* __restrict__ g2, const float* __restrict__ b2,
    int l, int gstride, float* __restrict__ hout)
{
    __shared__ __align__(16) unsigned short abuf[TM*1032];  // union: oproj stride 136 / kan stride 1032
    __shared__ float so[TM][D];
    int tid = threadIdx.x;
    int t0 = blockIdx.x * TM;
    int w = tid >> 6, lane = tid & 63, m = lane & 15, g4 = lane >> 4;
    int jw = w*16 + m;   // this wave's output column (valid when w < 7)

    // ---- 0. prefetch residuals + bias for phase 2 (before any barrier) ----
    float resv[4], obv = 0.f;
    if (w < 7) {
        obv = ob[l*D + jw];
        #pragma unroll
        for (int r = 0; r < 4; ++r)
            resv[r] = hin[(size_t)(t0 + g4*4 + r)*D + jw];
    }

    // ---- 1. stage ctx (bf16, stride 136, zero-padded cols) ----
    for (int e = tid; e < TM*136; e += 512) {
        int t = e / 136, i = e % 136;
        abuf[e] = (i < D) ? f2bf(ctx[(size_t)(t0 + t)*D + i]) : 0;
    }
    __syncthreads();

    // ---- 2. oproj MFMA + bias + residual -> so (wave w owns j-tile w) ----
    if (w < 7) {
        f32x4 acc = {0.f,0.f,0.f,0.f};
        const bf16x8* wol = (const bf16x8*)wo + (size_t)l*4*D*4;
        #pragma unroll
        for (int kt = 0; kt < 4; ++kt) {
            bf16x8 a = *(const bf16x8*)&abuf[m*136 + kt*32 + g4*8];
            bf16x8 b0 = wol[((size_t)kt*D + jw)*4 + g4];
            acc = __builtin_amdgcn_mfma_f32_16x16x32_bf16(a, b0, acc, 0, 0, 0);
        }
        #pragma unroll
        for (int r = 0; r < 4; ++r)
            so[g4*4 + r][jw] = acc[r] + obv + resv[r];
    }
    __syncthreads();

    // ---- 3. LN1 in place on so (8 waves x 2 tokens) ----
    for (int tt = 0; tt < 2; ++tt) {
        int t = w*2 + tt;
        float x0 = so[t][lane];
        float x1 = (lane + 64 < D) ? so[t][lane + 64] : 0.f;
        float s1 = x0 + x1, s2 = x0*x0 + x1*x1;
        #pragma unroll
        for (int off = 32; off; off >>= 1) { s1 += __shfl_xor(s1, off, 64); s2 += __shfl_xor(s2, off, 64); }
        float mu = s1 * (1.f/112.f);
        float var = s2 * (1.f/112.f) - mu*mu;
        float rs = rsqrtf(var + 1e-5f);
        so[t][lane] = (x0 - mu)*rs*g1[l*D + lane] + b1[l*D + lane];
        if (lane + 64 < D)
            so[t][lane+64] = (x1 - mu)*rs*g1[l*D + lane+64] + b1[l*D + lane+64];
    }
    __syncthreads();

    // ---- 4. spline basis (cardinal, direct) + silu from so -> abuf (stride 1032) ----
    for (int e = tid; e < TM * D; e += 512) {
        int tk = e / D, i = e % D;
        float xv = so[tk][i];
        float si = xv * __builtin_amdgcn_rcpf(1.f + __expf(-xv));
        const float* grp = grid + i * gstride;
        float gz = grp[0];
        float hh = grp[1] - gz;
        float u = (xv - gz) / hh;
        float fidx = floorf(u);
        int idx = (int)fidx;
        float t = u - fidx;
        float t2 = t*t, t3 = t2*t;
        const float s6 = 1.f/6.f;
        float p0 = t3 * s6;
        float p1 = (-3.f*t3 + 3.f*t2 + 3.f*t + 1.f) * s6;
        float p2 = (3.f*t3 - 6.f*t2 + 4.f) * s6;
        float om = 1.f - t;
        float p3 = om*om*om * s6;
        unsigned short* arow = &abuf[tk*1032 + i*9];
        #pragma unroll
        for (int b = 0; b < 8; ++b) arow[b] = 0;
        if (u >= 0.f && idx <= 10) {
            if (idx <= 7) arow[idx]   = f2bf(p0);
            if (idx >= 1 && idx <= 8) arow[idx-1] = f2bf(p1);
            if (idx >= 2 && idx <= 9) arow[idx-2] = f2bf(p2);
            if (idx >= 3)             arow[idx-3] = f2bf(p3);
        }
        arow[8] = f2bf(si);
    }
    for (int e = tid; e < TM * 24; e += 512)
        abuf[(e/24)*1032 + KTOT + (e%24)] = 0;
    __syncthreads();

    // ---- 5. KAN MFMA + residual (LN1 output) -> so (wave w owns j-tile w) ----
    if (w < 7) {
        f32x4 acc = {0.f,0.f,0.f,0.f};
        const bf16x8* wbl = (const bf16x8*)wb + (size_t)l * NKT * D * 4;
        #pragma unroll 4
        for (int kt = 0; kt < NKT; ++kt) {
            bf16x8 a = *(const bf16x8*)&abuf[m*1032 + kt*32 + g4*8];
            bf16x8 b0 = wbl[((size_t)kt*D + jw)*4 + g4];
            acc = __builtin_amdgcn_mfma_f32_16x16x32_bf16(a, b0, acc, 0, 0, 0);
        }
        #pragma unroll
        for (int r = 0; r < 4; ++r) {
            int t = g4*4 + r;
            so[t][jw] = acc[r] + so[t][jw];
        }
    }
    __syncthreads();

    // ---- 6. LN2 -> hout (8 waves x 2 tokens) ----
    for (int tt = 0; tt < 2; ++tt) {
        int t = w*2 + tt;
        float x0 = so[t][lane];
        float x1 = (lane + 64 < D) ? so[t][lane + 64] : 0.f;
        float s1 = x0 + x1, s2 = x0*x0 + x1*x1;
        #pragma unroll
        for (int off = 32; off; off >>= 1) { s1 += __shfl_xor(s1, off, 64); s2 += __shfl_xor(s2, off, 64); }
        float mu = s1 * (1.f/112.f);
        float var = s2 * (1.f/112.f) - mu*mu;
        float rs = rsqrtf(var + 1e-5f);
        for (int ii = lane; ii < D; ii += 64)
            hout[(size_t)(t0 + t)*D + ii] = (so[t][ii] - mu)*rs*g2[l*D + ii] + b2[l*D + ii];
    }
}

// ---------------- classifier: f32 output ----------------
__global__ __launch_bounds__(64) void cls_kernel(
    const float* __restrict__ h, const float* __restrict__ cw, const float* __restrict__ cb,
    float* __restrict__ out)
{
    int tid = threadIdx.x;
    if (tid < BATCH*2) {
        int b = tid >> 1, c = tid & 1;
        const float* hr = h + (size_t)b*SEQ*D;   // token s=0
        const float* wr = cw + c*D;
        float a = 0.f;
        for (int i = 0; i < D; ++i) a += hr[i]*wr[i];
        out[b*2 + c] = a + cb[c];
    }
}

// ---------------- ws-too-small sentinel (diagnostic) ----------------
__global__ void sentinel_kernel(float* __restrict__ out, int nel)
{
    int i = threadIdx.x;
    if (i < nel) out[i] = 1e30f;
}

extern "C" void kernel_launch(void* const* d_in, const int* in_sizes, int n_in,
                              void* d_out, int out_size, void* d_ws, size_t ws_size,
                              hipStream_t stream)
{
    const float* x      = (const float*)d_in[0];
    const int*   mask   = (const int*)  d_in[1];
    const float* grid   = (const float*)d_in[2];
    const float* qw     = (const float*)d_in[3];
    const float* qb     = (const float*)d_in[4];
    const float* kw     = (const float*)d_in[5];
    const float* kb     = (const float*)d_in[6];
    const float* vw     = (const float*)d_in[7];
    const float* vb     = (const float*)d_in[8];
    const float* ow     = (const float*)d_in[9];
    const float* ob     = (const float*)d_in[10];
    const float* ln1g   = (const float*)d_in[11];
    const float* ln1b   = (const float*)d_in[12];
    const float* ln2g   = (const float*)d_in[13];
    const float* ln2b   = (const float*)d_in[14];
    const float* base_w = (const float*)d_in[15];
    const float* spline_w = (const float*)d_in[16];
    const float* scaler = (const float*)d_in[17];
    const float* cls_w  = (const float*)d_in[18];
    const float* cls_b  = (const float*)d_in[19];

    size_t SZ   = (size_t)NTOK * D;            // 917504 floats per buffer
    size_t WBN  = (size_t)2 * NKT * D * 32;    // 229376 bf16 (kan weights)
    size_t WQN  = (size_t)2 * 4 * 336 * 32;    // 86016 bf16 (qkv weights)
    size_t WON  = (size_t)2 * 4 * D * 32;      // 28672 bf16 (oproj weights)
    size_t need = 6*SZ*sizeof(float) + (WBN + WQN + WON)*sizeof(unsigned short) + 256;
    if (ws_size < need) {
        sentinel_kernel<<<1, 64, 0, stream>>>((float*)d_out, out_size);
        return;
    }
    float* ws = (float*)d_ws;
    float* q   = ws;
    float* k   = q + SZ;
    float* v   = k + SZ;
    float* ctx = v + SZ;
    float* hA  = ctx + SZ;
    float* hB  = hA + SZ;
    unsigned short* wbuf  = (unsigned short*)(hB + SZ);
    unsigned short* wqkv  = wbuf + WBN;
    unsigned short* wobuf = wqkv + WQN;

    int gstride = (in_sizes[2] == NKNOT) ? 0 : NKNOT;

    wb_prep_kernel<<<(int)((WBN + 255)/256), 256, 0, stream>>>(base_w, spline_w, scaler, wbuf);
    wqkv_prep_kernel<<<(int)((WQN + 255)/256), 256, 0, stream>>>(qw, kw, vw, wqkv);
    wo_prep_kernel<<<(int)((WON + 255)/256), 256, 0, stream>>>(ow, wobuf);

    const float* hin = x;
    float* houts[2] = {hA, hB};
    for (int l = 0; l < 2; ++l) {
        qkv_mfma_kernel<<<NTOK/TM, 512, 0, stream>>>(hin, wqkv, qb, kb, vb, l, q, k, v);
        attn_mfma_kernel<<<BATCH*HEADS*2, 512, 0, stream>>>(q, k, v, mask, ctx);
        oproj_kan_ln_kernel<<<NTOK/TM, 512, 0, stream>>>(ctx, hin, wobuf, ob, ln1g, ln1b,
                                                         grid, wbuf, ln2g, ln2b, l, gstride, houts[l]);
        hin = houts[l];
    }
    cls_kernel<<<1, 64, 0, stream>>>(hB, cls_w, cls_b, (float*)d_out);
}

// Round 21
// 148.945 us; speedup vs baseline: 2.1714x; 1.0119x over previous
//
#include <hip/hip_runtime.h>
#include <hip/hip_bf16.h>

#define D 112
#define HEADS 28
#define HDIM 4
#define SEQ 512
#define BATCH 16
#define NTOK (BATCH*SEQ)
#define NBASES 8
#define NKNOT 12
#define KTOT (D*9)          // 1008 real K for KAN; padded to 1024
#define KPAD 1024
#define NKT (KPAD/32)       // 32 K-steps (KAN)
#define TM 16               // tokens per block in GEMM kernels
#define QJT 21              // 336/16 j-tiles in fused qkv GEMM
#define KST 12              // kpack row stride (shorts): 24B -> 6 words, 2-way banks (free)
#define VST 520             // vT row stride (bf16): 1040B = 65x16 (aligned), rows on distinct banks
#define LOG2E 1.44269504088896f
#define ATTN_BIAS (-23.0831169f)   // -16*log2(e)

typedef __attribute__((ext_vector_type(8))) __bf16 bf16x8;
typedef __attribute__((ext_vector_type(4))) float f32x4;
typedef __attribute__((ext_vector_type(16))) float f32x16;

__device__ __forceinline__ unsigned short f2bf(float f) {
    unsigned u = __float_as_uint(f);
    unsigned r = u + 0x7FFFu + ((u >> 16) & 1u);   // RNE
    return (unsigned short)(r >> 16);
}

__device__ __forceinline__ unsigned cvt_pk_bf16(float lo, float hi) {
    unsigned r;
    asm("v_cvt_pk_bf16_f32 %0, %1, %2" : "=v"(r) : "v"(lo), "v"(hi));
    return r;
}

// ---------------- weight prep: qkv concat -> bf16 B-fragment layout ----------------
__global__ void wqkv_prep_kernel(
    const float* __restrict__ qw, const float* __restrict__ kw, const float* __restrict__ vw,
    unsigned short* __restrict__ wq)
{
    int idx = blockIdx.x * 256 + threadIdx.x;
    if (idx >= 2*4*336*32) return;
    int kk = idx & 31;
    int j  = (idx >> 5) % 336;
    int kt = ((idx >> 5) / 336) & 3;
    int l  = idx / (32*336*4);
    int i = kt*32 + kk;
    float val = 0.f;
    if (i < D) {
        int mo = j / D, jj = j % D;
        const float* src = (mo==0) ? qw : (mo==1) ? kw : vw;
        val = src[((size_t)l*D + jj)*D + i];
    }
    wq[idx] = f2bf(val);
}

// ---------------- weight prep: oproj -> bf16 B-fragment layout ----------------
__global__ void wo_prep_kernel(const float* __restrict__ ow, unsigned short* __restrict__ wo)
{
    int idx = blockIdx.x * 256 + threadIdx.x;
    if (idx >= 2*4*D*32) return;
    int kk = idx & 31;
    int j  = (idx >> 5) % D;
    int kt = ((idx >> 5) / D) & 3;
    int l  = idx / (32*D*4);
    int i = kt*32 + kk;
    float val = (i < D) ? ow[((size_t)l*D + j)*D + i] : 0.f;
    wo[idx] = f2bf(val);
}

// ---------------- fused QKV via MFMA (16 tokens/block, 8 waves, 21 j-tiles) ----------------
__global__ __launch_bounds__(512) void qkv_mfma_kernel(
    const float* __restrict__ hin, const unsigned short* __restrict__ wq,
    const float* __restrict__ qb, const float* __restrict__ kb, const float* __restrict__ vb,
    int l, float* __restrict__ q, float* __restrict__ k, float* __restrict__ v)
{
    __shared__ __align__(16) unsigned short act[TM][136];   // 16 x (128+8 pad)
    int tid = threadIdx.x;
    int t0 = blockIdx.x * TM;
    for (int e = tid; e < TM*D; e += 512) {
        int t = e / D, i = e % D;
        act[t][i] = f2bf(hin[(size_t)(t0 + t)*D + i]);
    }
    for (int e = tid; e < TM*16; e += 512) act[e/16][D + (e%16)] = 0;
    __syncthreads();

    int w = tid >> 6, lane = tid & 63, m = lane & 15, g4 = lane >> 4;
    f32x4 acc[3];
    #pragma unroll
    for (int qq = 0; qq < 3; ++qq) acc[qq] = (f32x4){0.f,0.f,0.f,0.f};
    const bf16x8* wql = (const bf16x8*)wq + (size_t)l*4*336*4;
    #pragma unroll
    for (int kt = 0; kt < 4; ++kt) {
        bf16x8 a = *(const bf16x8*)&act[m][kt*32 + g4*8];
        #pragma unroll
        for (int qq = 0; qq < 3; ++qq) {
            int jt = w + 8*qq;
            if (jt < QJT) {
                bf16x8 bf = wql[((size_t)kt*336 + jt*16 + m)*4 + g4];
                acc[qq] = __builtin_amdgcn_mfma_f32_16x16x32_bf16(a, bf, acc[qq], 0, 0, 0);
            }
        }
    }
    #pragma unroll
    for (int qq = 0; qq < 3; ++qq) {
        int jt = w + 8*qq;
        if (jt >= QJT) continue;
        int j = jt*16 + m;
        int mo = j / D, jj = j % D;
        const float* bb = (mo==0) ? qb : (mo==1) ? kb : vb;
        float bias = bb[l*D + jj];
        float scl = (mo==0) ? 0.5f*LOG2E : 1.0f;
        float* dst = (mo==0) ? q : (mo==1) ? k : v;
        int h = jj >> 2, hd = jj & 3;
        #pragma unroll
        for (int r = 0; r < 4; ++r) {
            int n = t0 + g4*4 + r;
            int bi = n >> 9, s = n & 511;
            dst[((size_t)(bi*HEADS + h)*SEQ + s)*HDIM + hd] = (acc[qq][r] + bias)*scl;
        }
    }
}

// ---------------- attention via 32x32x16 MFMA, register-only P (shfl_xor redistribution) --
// Block = quarter (b,h): 128 queries, 4 waves x 32 queries. Scores: S^T = K.Q^T (K=16,
// mask bias in K slot 4). P stays in registers: the half-swap needed to turn the S^T
// C-layout into the PV B-fragment is __shfl_xor(.,32). PV: O^T = V^T.P with a 5th ones
// row of V^T -> denominators at row 4 (fetched by one more shfl_xor). No P LDS at all.
__global__ __launch_bounds__(256) void attn_mfma_kernel(
    const float* __restrict__ q, const float* __restrict__ k, const float* __restrict__ v,
    const int* __restrict__ mask, float* __restrict__ ctx)
{
    __shared__ __align__(16) unsigned short kpack[SEQ][KST]; // k0..3, mf, 0,0,0 (+pad) 12KB
    __shared__ __align__(16) unsigned short vT[5][VST];      // V^T + ones row          5.2KB
    int tid = threadIdx.x;
    int bh = blockIdx.x >> 2, qh = blockIdx.x & 3;
    int b = bh / HEADS, hd = bh % HEADS;

    const float4* kk = (const float4*)k + (size_t)bh*SEQ;
    const float4* vv = (const float4*)v + (size_t)bh*SEQ;
    for (int s = tid; s < SEQ; s += 256) {
        float4 kf = kk[s];
        float mf = mask[b*SEQ + s] ? ATTN_BIAS : -1e9f;
        *(uint2*)&kpack[s][0] = (uint2){cvt_pk_bf16(kf.x, kf.y), cvt_pk_bf16(kf.z, kf.w)};
        *(uint2*)&kpack[s][4] = (uint2){cvt_pk_bf16(mf, 0.f), 0u};
        float4 vf = vv[s];
        vT[0][s] = f2bf(vf.x); vT[1][s] = f2bf(vf.y);
        vT[2][s] = f2bf(vf.z); vT[3][s] = f2bf(vf.w);
        vT[4][s] = 0x3F80;   // bf16 1.0 -> denominator row
    }
    __syncthreads();

    int w = tid >> 6, lane = tid & 63;
    int m = lane & 31;          // key row (A) / d row (PV A) / query col (outputs)
    int hf = lane >> 5;         // wave half
    int q0 = qh*128 + w*32;     // this wave's query base within (b,h)

    // Q fragment: B[k][n=query m]: k slots 0..4 = q0..3, 1.0 (half 0 only)
    bf16x8 qfrag;
    {
        uint4 uq = {0,0,0,0};
        if (hf == 0) {
            float4 qf = ((const float4*)q)[(size_t)bh*SEQ + q0 + m];
            uq = (uint4){cvt_pk_bf16(qf.x, qf.y), cvt_pk_bf16(qf.z, qf.w), 0x3F80u, 0u};
        }
        qfrag = *(bf16x8*)&uq;
    }

    f32x16 oacc = {};
    #pragma unroll 2
    for (int kb = 0; kb < SEQ; kb += 32) {
        // K fragment: A[m=key][k]: half 0 carries k0..3+mf, half 1 zero
        bf16x8 kfrag;
        {
            uint4 u = {0,0,0,0};
            if (hf == 0) {
                uint2 lo = *(const uint2*)&kpack[kb + m][0];
                uint2 hi = *(const uint2*)&kpack[kb + m][4];
                u = (uint4){lo.x, lo.y, hi.x, hi.y};
            }
            kfrag = *(bf16x8*)&u;
        }
        f32x16 sc = {};
        sc = __builtin_amdgcn_mfma_f32_32x32x16_bf16(kfrag, qfrag, sc, 0, 0, 0);
        // sc reg 4s+r = P(key kb + r + 8s + 4*hf, query q0+m)
        float p0  = __builtin_exp2f(sc[0]),  p1  = __builtin_exp2f(sc[1]);
        float p2  = __builtin_exp2f(sc[2]),  p3  = __builtin_exp2f(sc[3]);
        float p4  = __builtin_exp2f(sc[4]),  p5  = __builtin_exp2f(sc[5]);
        float p6  = __builtin_exp2f(sc[6]),  p7  = __builtin_exp2f(sc[7]);
        float p8  = __builtin_exp2f(sc[8]),  p9  = __builtin_exp2f(sc[9]);
        float p10 = __builtin_exp2f(sc[10]), p11 = __builtin_exp2f(sc[11]);
        float p12 = __builtin_exp2f(sc[12]), p13 = __builtin_exp2f(sc[13]);
        float p14 = __builtin_exp2f(sc[14]), p15 = __builtin_exp2f(sc[15]);
        unsigned c0 = cvt_pk_bf16(p0,  p1),  c1 = cvt_pk_bf16(p2,  p3);
        unsigned c2 = cvt_pk_bf16(p4,  p5),  c3 = cvt_pk_bf16(p6,  p7);
        unsigned c4 = cvt_pk_bf16(p8,  p9),  c5 = cvt_pk_bf16(p10, p11);
        unsigned c6 = cvt_pk_bf16(p12, p13), c7 = cvt_pk_bf16(p14, p15);
        unsigned x0 = __shfl_xor(c0, 32, 64), x1 = __shfl_xor(c1, 32, 64);
        unsigned x2 = __shfl_xor(c2, 32, 64), x3 = __shfl_xor(c3, 32, 64);
        unsigned x4 = __shfl_xor(c4, 32, 64), x5 = __shfl_xor(c5, 32, 64);
        unsigned x6 = __shfl_xor(c6, 32, 64), x7 = __shfl_xor(c7, 32, 64);
        // PV B-frags: B[k=hf*8+j][n=query m]
        uint4 uf1 = { hf ? x2 : c0, hf ? x3 : c1, hf ? c2 : x0, hf ? c3 : x1 };
        uint4 uf2 = { hf ? x6 : c4, hf ? x7 : c5, hf ? c6 : x4, hf ? c7 : x5 };
        bf16x8 pf1 = *(bf16x8*)&uf1;
        bf16x8 pf2 = *(bf16x8*)&uf2;
        // V^T A-frags: A[m=d (rows 0..4)][k]
        uint4 z = {0,0,0,0};
        bf16x8 va1 = (m < 5) ? *(const bf16x8*)&vT[m][kb + hf*8]      : *(bf16x8*)&z;
        bf16x8 va2 = (m < 5) ? *(const bf16x8*)&vT[m][kb + 16 + hf*8] : *(bf16x8*)&z;
        oacc = __builtin_amdgcn_mfma_f32_32x32x16_bf16(va1, pf1, oacc, 0, 0, 0);
        oacc = __builtin_amdgcn_mfma_f32_32x32x16_bf16(va2, pf2, oacc, 0, 0, 0);
    }
    // oacc rows: half0 regs 0..3 = d 0..3; denominator (row 4) = half1 reg 0
    float dn = __shfl_xor(oacc[0], 32, 64);
    float inv = __builtin_amdgcn_rcpf(dn);
    if (hf == 0) {
        int qi = q0 + m;
        float4 o = {oacc[0]*inv, oacc[1]*inv, oacc[2]*inv, oacc[3]*inv};
        ((float4*)ctx)[(size_t)(b*SEQ + qi)*HEADS + hd] = o;   // ctx in (B,S,D)
    }
}

// ---------------- Wb prep: fold (spline_w*scaler, base_w) into bf16 B-fragment layout ----
__global__ void wb_prep_kernel(
    const float* __restrict__ base_w, const float* __restrict__ spline_w,
    const float* __restrict__ scaler, unsigned short* __restrict__ wb)
{
    int idx = blockIdx.x * 256 + threadIdx.x;
    if (idx >= 2 * NKT * D * 32) return;
    int kk = idx & 31;
    int j  = (idx >> 5) % D;
    int kt = ((idx >> 5) / D) % NKT;
    int l  = idx / (32 * D * NKT);
    int k = kt * 32 + kk;
    float val = 0.f;
    if (k < KTOT) {
        int i = k / 9, b = k % 9;
        size_t ji = ((size_t)l * D + j) * D + i;
        val = (b == 8) ? base_w[ji] : spline_w[ji * NBASES + b] * scaler[ji];
    }
    wb[idx] = f2bf(val);
}

// ---------------- FUSED: oproj + res + LN1 + KAN + res + LN2 (16 tok, 8 waves) ----------
__global__ __launch_bounds__(512) void oproj_kan_ln_kernel(
    const float* __restrict__ ctx, const float* __restrict__ hin,
    const unsigned short* __restrict__ wo, const float* __restrict__ ob,
    const float* __restrict__ g1, const float* __restrict__ b1,
    const float* __restrict__ grid, const unsigned short* __restrict__ wb,
    const float* __restrict__ g2, const float* __restrict__ b2,
    int l, int gstride, float* __restrict__ hout)
{
    __shared__ __align__(16) unsigned short abuf[TM*1032];  // union: oproj stride 136 / kan stride 1032
    __shared__ float so[TM][D];
    int tid = threadIdx.x;
    int t0 = blockIdx.x * TM;
    int w = tid >> 6, lane = tid & 63, m = lane & 15, g4 = lane >> 4;
    int jw = w*16 + m;   // this wave's output column (valid when w < 7)

    // ---- 0. prefetch residuals + bias for phase 2 (before any barrier) ----
    float resv[4], obv = 0.f;
    if (w < 7) {
        obv = ob[l*D + jw];
        #pragma unroll
        for (int r = 0; r < 4; ++r)
            resv[r] = hin[(size_t)(t0 + g4*4 + r)*D + jw];
    }

    // ---- 1. stage ctx (bf16, stride 136, zero-padded cols) ----
    for (int e = tid; e < TM*136; e += 512) {
        int t = e / 136, i = e % 136;
        abuf[e] = (i < D) ? f2bf(ctx[(size_t)(t0 + t)*D + i]) : 0;
    }
    __syncthreads();

    // ---- 2. oproj MFMA + bias + residual -> so (wave w owns j-tile w) ----
    if (w < 7) {
        f32x4 acc = {0.f,0.f,0.f,0.f};
        const bf16x8* wol = (const bf16x8*)wo + (size_t)l*4*D*4;
        #pragma unroll
        for (int kt = 0; kt < 4; ++kt) {
            bf16x8 a = *(const bf16x8*)&abuf[m*136 + kt*32 + g4*8];
            bf16x8 b0 = wol[((size_t)kt*D + jw)*4 + g4];
            acc = __builtin_amdgcn_mfma_f32_16x16x32_bf16(a, b0, acc, 0, 0, 0);
        }
        #pragma unroll
        for (int r = 0; r < 4; ++r)
            so[g4*4 + r][jw] = acc[r] + obv + resv[r];
    }
    __syncthreads();

    // ---- 3. LN1 in place on so (8 waves x 2 tokens) ----
    for (int tt = 0; tt < 2; ++tt) {
        int t = w*2 + tt;
        float x0 = so[t][lane];
        float x1 = (lane + 64 < D) ? so[t][lane + 64] : 0.f;
        float s1 = x0 + x1, s2 = x0*x0 + x1*x1;
        #pragma unroll
        for (int off = 32; off; off >>= 1) { s1 += __shfl_xor(s1, off, 64); s2 += __shfl_xor(s2, off, 64); }
        float mu = s1 * (1.f/112.f);
        float var = s2 * (1.f/112.f) - mu*mu;
        float rs = rsqrtf(var + 1e-5f);
        so[t][lane] = (x0 - mu)*rs*g1[l*D + lane] + b1[l*D + lane];
        if (lane + 64 < D)
            so[t][lane+64] = (x1 - mu)*rs*g1[l*D + lane+64] + b1[l*D + lane+64];
    }
    __syncthreads();

    // ---- 4. spline basis (cardinal, direct) + silu from so -> abuf (stride 1032) ----
    for (int e = tid; e < TM * D; e += 512) {
        int tk = e / D, i = e % D;
        float xv = so[tk][i];
        float si = xv * __builtin_amdgcn_rcpf(1.f + __expf(-xv));
        const float* grp = grid + i * gstride;
        float gz = grp[0];
        float hh = grp[1] - gz;
        float u = (xv - gz) / hh;
        float fidx = floorf(u);
        int idx = (int)fidx;
        float t = u - fidx;
        float t2 = t*t, t3 = t2*t;
        const float s6 = 1.f/6.f;
        float p0 = t3 * s6;
        float p1 = (-3.f*t3 + 3.f*t2 + 3.f*t + 1.f) * s6;
        float p2 = (3.f*t3 - 6.f*t2 + 4.f) * s6;
        float om = 1.f - t;
        float p3 = om*om*om * s6;
        unsigned short* arow = &abuf[tk*1032 + i*9];
        #pragma unroll
        for (int b = 0; b < 8; ++b) arow[b] = 0;
        if (u >= 0.f && idx <= 10) {
            if (idx <= 7) arow[idx]   = f2bf(p0);
            if (idx >= 1 && idx <= 8) arow[idx-1] = f2bf(p1);
            if (idx >= 2 && idx <= 9) arow[idx-2] = f2bf(p2);
            if (idx >= 3)             arow[idx-3] = f2bf(p3);
        }
        arow[8] = f2bf(si);
    }
    for (int e = tid; e < TM * 24; e += 512)
        abuf[(e/24)*1032 + KTOT + (e%24)] = 0;
    __syncthreads();

    // ---- 5. KAN MFMA + residual (LN1 output) -> so (wave w owns j-tile w) ----
    if (w < 7) {
        f32x4 acc = {0.f,0.f,0.f,0.f};
        const bf16x8* wbl = (const bf16x8*)wb + (size_t)l * NKT * D * 4;
        #pragma unroll 4
        for (int kt = 0; kt < NKT; ++kt) {
            bf16x8 a = *(const bf16x8*)&abuf[m*1032 + kt*32 + g4*8];
            bf16x8 b0 = wbl[((size_t)kt*D + jw)*4 + g4];
            acc = __builtin_amdgcn_mfma_f32_16x16x32_bf16(a, b0, acc, 0, 0, 0);
        }
        #pragma unroll
        for (int r = 0; r < 4; ++r) {
            int t = g4*4 + r;
            so[t][jw] = acc[r] + so[t][jw];
        }
    }
    __syncthreads();

    // ---- 6. LN2 -> hout (8 waves x 2 tokens) ----
    for (int tt = 0; tt < 2; ++tt) {
        int t = w*2 + tt;
        float x0 = so[t][lane];
        float x1 = (lane + 64 < D) ? so[t][lane + 64] : 0.f;
        float s1 = x0 + x1, s2 = x0*x0 + x1*x1;
        #pragma unroll
        for (int off = 32; off; off >>= 1) { s1 += __shfl_xor(s1, off, 64); s2 += __shfl_xor(s2, off, 64); }
        float mu = s1 * (1.f/112.f);
        float var = s2 * (1.f/112.f) - mu*mu;
        float rs = rsqrtf(var + 1e-5f);
        for (int ii = lane; ii < D; ii += 64)
            hout[(size_t)(t0 + t)*D + ii] = (so[t][ii] - mu)*rs*g2[l*D + ii] + b2[l*D + ii];
    }
}

// ---------------- classifier: f32 output ----------------
__global__ __launch_bounds__(64) void cls_kernel(
    const float* __restrict__ h, const float* __restrict__ cw, const float* __restrict__ cb,
    float* __restrict__ out)
{
    int tid = threadIdx.x;
    if (tid < BATCH*2) {
        int b = tid >> 1, c = tid & 1;
        const float* hr = h + (size_t)b*SEQ*D;   // token s=0
        const float* wr = cw + c*D;
        float a = 0.f;
        for (int i = 0; i < D; ++i) a += hr[i]*wr[i];
        out[b*2 + c] = a + cb[c];
    }
}

// ---------------- ws-too-small sentinel (diagnostic) ----------------
__global__ void sentinel_kernel(float* __restrict__ out, int nel)
{
    int i = threadIdx.x;
    if (i < nel) out[i] = 1e30f;
}

extern "C" void kernel_launch(void* const* d_in, const int* in_sizes, int n_in,
                              void* d_out, int out_size, void* d_ws, size_t ws_size,
                              hipStream_t stream)
{
    const float* x      = (const float*)d_in[0];
    const int*   mask   = (const int*)  d_in[1];
    const float* grid   = (const float*)d_in[2];
    const float* qw     = (const float*)d_in[3];
    const float* qb     = (const float*)d_in[4];
    const float* kw     = (const float*)d_in[5];
    const float* kb     = (const float*)d_in[6];
    const float* vw     = (const float*)d_in[7];
    const float* vb     = (const float*)d_in[8];
    const float* ow     = (const float*)d_in[9];
    const float* ob     = (const float*)d_in[10];
    const float* ln1g   = (const float*)d_in[11];
    const float* ln1b   = (const float*)d_in[12];
    const float* ln2g   = (const float*)d_in[13];
    const float* ln2b   = (const float*)d_in[14];
    const float* base_w = (const float*)d_in[15];
    const float* spline_w = (const float*)d_in[16];
    const float* scaler = (const float*)d_in[17];
    const float* cls_w  = (const float*)d_in[18];
    const float* cls_b  = (const float*)d_in[19];

    size_t SZ   = (size_t)NTOK * D;            // 917504 floats per buffer
    size_t WBN  = (size_t)2 * NKT * D * 32;    // 229376 bf16 (kan weights)
    size_t WQN  = (size_t)2 * 4 * 336 * 32;    // 86016 bf16 (qkv weights)
    size_t WON  = (size_t)2 * 4 * D * 32;      // 28672 bf16 (oproj weights)
    size_t need = 6*SZ*sizeof(float) + (WBN + WQN + WON)*sizeof(unsigned short) + 256;
    if (ws_size < need) {
        sentinel_kernel<<<1, 64, 0, stream>>>((float*)d_out, out_size);
        return;
    }
    float* ws = (float*)d_ws;
    float* q   = ws;
    float* k   = q + SZ;
    float* v   = k + SZ;
    float* ctx = v + SZ;
    float* hA  = ctx + SZ;
    float* hB  = hA + SZ;
    unsigned short* wbuf  = (unsigned short*)(hB + SZ);
    unsigned short* wqkv  = wbuf + WBN;
    unsigned short* wobuf = wqkv + WQN;

    int gstride = (in_sizes[2] == NKNOT) ? 0 : NKNOT;

    wb_prep_kernel<<<(int)((WBN + 255)/256), 256, 0, stream>>>(base_w, spline_w, scaler, wbuf);
    wqkv_prep_kernel<<<(int)((WQN + 255)/256), 256, 0, stream>>>(qw, kw, vw, wqkv);
    wo_prep_kernel<<<(int)((WON + 255)/256), 256, 0, stream>>>(ow, wobuf);

    const float* hin = x;
    float* houts[2] = {hA, hB};
    for (int l = 0; l < 2; ++l) {
        qkv_mfma_kernel<<<NTOK/TM, 512, 0, stream>>>(hin, wqkv, qb, kb, vb, l, q, k, v);
        attn_mfma_kernel<<<BATCH*HEADS*4, 256, 0, stream>>>(q, k, v, mask, ctx);
        oproj_kan_ln_kernel<<<NTOK/TM, 512, 0, stream>>>(ctx, hin, wobuf, ob, ln1g, ln1b,
                                                         grid, wbuf, ln2g, ln2b, l, gstride, houts[l]);
        hin = houts[l];
    }
    cls_kernel<<<1, 64, 0, stream>>>(hB, cls_w, cls_b, (float*)d_out);
}